// Round 7
// baseline (1189.991 us; speedup 1.0000x reference)
//
#include <hip/hip_runtime.h>
#include <stdint.h>

#define N_V   20000
#define M_KP  160000
#define E_N   320000
#define SD    300
#define T_IT  3

typedef unsigned short bf16_t;
typedef __attribute__((ext_vector_type(8))) short short8_t;
typedef __attribute__((ext_vector_type(4))) float float4_t;

__device__ __forceinline__ float bf2f(bf16_t u) {
    return __uint_as_float(((unsigned)u) << 16);
}
__device__ __forceinline__ bf16_t f2bf(float f) {
    unsigned u = __float_as_uint(f);
    unsigned r = (u + 0x7FFFu + ((u >> 16) & 1u)) >> 16;
    return (bf16_t)r;
}

template<bool F32>
__device__ __forceinline__ float LD(const void* p, size_t i) {
    if (F32) return ((const float*)p)[i];
    return bf2f(((const bf16_t*)p)[i]);
}
template<bool F32>
__device__ __forceinline__ void ST(void* p, size_t i, float v) {
    if (F32) ((float*)p)[i] = v;
    else     ((bf16_t*)p)[i] = f2bf(v);
}
__device__ __forceinline__ float LDr(const void* p, long long i, bool f32) {
    return f32 ? ((const float*)p)[i] : bf2f(((const bf16_t*)p)[i]);
}
__device__ __forceinline__ void STr(void* p, size_t i, float v, bool f32) {
    if (f32) ((float*)p)[i] = v;
    else     ((bf16_t*)p)[i] = f2bf(v);
}

// ---------- dtype detect: flag=1 if float inputs are f32, 0 if bf16 ----------
__global__ void k_detect(const unsigned* __restrict__ w, int* __restrict__ flag) {
    __shared__ int cnt_s;
    if (threadIdx.x == 0) cnt_s = 0;
    __syncthreads();
    unsigned u = w[threadIdx.x];          // 128 dwords = 512B, safe for either dtype
    unsigned lo = u & 0xFFFFu;
    int e = (lo >> 7) & 0xFF;
    int plaus = (lo == 0u) || (e >= 96 && e <= 126);
    atomicAdd(&cnt_s, plaus);
    __syncthreads();
    if (threadIdx.x == 0) flag[0] = (cnt_s >= 64) ? 0 : 1;
}

// ---------- CSR build (dst-grouped edges) ----------
__global__ void k_zero(int* p, int n) {
    int i = blockIdx.x * blockDim.x + threadIdx.x;
    if (i < n) p[i] = 0;
}
__global__ void k_hist(const int* __restrict__ dst, int* __restrict__ cnt) {
    int e = blockIdx.x * blockDim.x + threadIdx.x;
    if (e < E_N) atomicAdd(&cnt[dst[e]], 1);
}
__global__ void k_scan(const int* __restrict__ cnt, int* __restrict__ offs,
                       int* __restrict__ cur) {
    __shared__ int buf[1024];
    __shared__ int carry_s;
    int tid = threadIdx.x;
    if (tid == 0) { carry_s = 0; offs[0] = 0; }
    __syncthreads();
    for (int base = 0; base < N_V; base += 1024) {
        int i = base + tid;
        int v = (i < N_V) ? cnt[i] : 0;
        buf[tid] = v;
        __syncthreads();
        for (int off = 1; off < 1024; off <<= 1) {
            int t = (tid >= off) ? buf[tid - off] : 0;
            __syncthreads();
            buf[tid] += t;
            __syncthreads();
        }
        int incl = buf[tid] + carry_s;
        if (i < N_V) { offs[i + 1] = incl; cur[i] = incl - v; }
        __syncthreads();
        if (tid == 1023) carry_s = incl;
        __syncthreads();
    }
}
__global__ void k_scatter(const int* __restrict__ src, const int* __restrict__ dst,
                          int* __restrict__ cur, int* __restrict__ esrc) {
    int e = blockIdx.x * blockDim.x + threadIdx.x;
    if (e < E_N) {
        int p = atomicAdd(&cur[dst[e]], 1);
        esrc[p] = src[e];
    }
}

// ---------- fused init MLP (fallback VALU path) ----------
template<bool F32>
__global__ __launch_bounds__(256) void k_init_fused(
    const void* __restrict__ kp,
    const void* __restrict__ Wi0, const void* __restrict__ bi0,
    const void* __restrict__ Wi1, const void* __restrict__ bi1,
    const void* __restrict__ Wi2, const void* __restrict__ bi2,
    float* __restrict__ kpmax, const int* __restrict__ flag) {
    if ((flag[0] != 0) != F32) return;
    __shared__ float kps[256];
    __shared__ float h1s[64][64];
    __shared__ float h2s[64 * 128];
    int tid = threadIdx.x;
    int row0 = blockIdx.x * 64;
    kps[tid] = LD<F32>(kp, (size_t)row0 * 4 + tid);
    __syncthreads();
    {
        int c = tid & 63;
        float w0 = LD<F32>(Wi0, c), w1 = LD<F32>(Wi0, 64 + c);
        float w2 = LD<F32>(Wi0, 128 + c), w3 = LD<F32>(Wi0, 192 + c);
        float b0 = LD<F32>(bi0, c);
        int rbase = (tid >> 6) * 16;
#pragma unroll
        for (int rr = 0; rr < 16; rr++) {
            int r = rbase + rr;
            float a = b0 + kps[r * 4] * w0 + kps[r * 4 + 1] * w1
                         + kps[r * 4 + 2] * w2 + kps[r * 4 + 3] * w3;
            h1s[r][c] = fmaxf(a, 0.f);
        }
    }
    __syncthreads();
    {
        int c = tid & 127;
        int rbase = (tid >> 7) * 32;
        float b1 = LD<F32>(bi1, c);
        float acc[32];
#pragma unroll
        for (int rr = 0; rr < 32; rr++) acc[rr] = b1;
        for (int k = 0; k < 64; k++) {
            float wv = LD<F32>(Wi1, (size_t)k * 128 + c);
#pragma unroll
            for (int rr = 0; rr < 32; rr++) acc[rr] += h1s[rbase + rr][k] * wv;
        }
#pragma unroll
        for (int rr = 0; rr < 32; rr++)
            h2s[(size_t)(rbase + rr) * 128 + c] = fmaxf(acc[rr], 0.f);
    }
    __syncthreads();
    {
        int cx = tid & 63, rg = tid >> 6;
        float acc[16][5];
#pragma unroll
        for (int r = 0; r < 16; r++)
#pragma unroll
            for (int j = 0; j < 5; j++) acc[r][j] = 0.f;
        bool ok4 = (cx < SD - 256);
        for (int k = 0; k < 128; k++) {
            float w[5];
#pragma unroll
            for (int j = 0; j < 4; j++) w[j] = LD<F32>(Wi2, (size_t)k * SD + cx + 64 * j);
            w[4] = ok4 ? LD<F32>(Wi2, (size_t)k * SD + cx + 256) : 0.f;
#pragma unroll
            for (int r = 0; r < 16; r++) {
                float av = h2s[(rg * 16 + r) * 128 + k];
#pragma unroll
                for (int j = 0; j < 5; j++) acc[r][j] += av * w[j];
            }
        }
        int vbase = (row0 >> 3) + rg * 2;
#pragma unroll
        for (int half = 0; half < 2; half++) {
            int v = vbase + half;
#pragma unroll
            for (int j = 0; j < 5; j++) {
                int c = cx + 64 * j;
                if (c >= SD) continue;
                float m = acc[half * 8][j];
#pragma unroll
                for (int r = 1; r < 8; r++) m = fmaxf(m, acc[half * 8 + r][j]);
                kpmax[(size_t)v * SD + c] = fmaxf(m + LD<F32>(bi2, c), 0.f);
            }
        }
    }
}

// ---------- generic tiled f32 GEMM (fallback path only) ----------
template<bool F32>
__global__ __launch_bounds__(256) void k_gemm(
    const float* __restrict__ A, const void* __restrict__ W,
    const void* __restrict__ bias, const float* res,
    float* C, int Mr, int K, int Nc, int do_relu, const int* __restrict__ flag) {
    if ((flag[0] != 0) != F32) return;
    __shared__ float As[16][65];
    __shared__ float Ws[16][64];
    int tid = threadIdx.x;
    int tx = tid & 15, ty = tid >> 4;
    int row0 = blockIdx.y * 64, col0 = blockIdx.x * 64;
    float acc[4][4] = {{0.f}};
    int lk = tid & 15, lr = tid >> 4;
    int ln = tid & 63, lk4 = tid >> 6;
    for (int k0 = 0; k0 < K; k0 += 16) {
#pragma unroll
        for (int i = 0; i < 4; i++) {
            int r = lr + i * 16;
            int gr = row0 + r, gk = k0 + lk;
            As[lk][r] = (gr < Mr && gk < K) ? A[(size_t)gr * K + gk] : 0.f;
        }
#pragma unroll
        for (int p = 0; p < 4; p++) {
            int kk = lk4 + p * 4;
            int gk = k0 + kk, gn = col0 + ln;
            Ws[kk][ln] = (gk < K && gn < Nc) ? LD<F32>(W, (size_t)gk * Nc + gn) : 0.f;
        }
        __syncthreads();
#pragma unroll
        for (int kk = 0; kk < 16; kk++) {
            float a[4], w[4];
#pragma unroll
            for (int i = 0; i < 4; i++) a[i] = As[kk][ty * 4 + i];
#pragma unroll
            for (int j = 0; j < 4; j++) w[j] = Ws[kk][tx * 4 + j];
#pragma unroll
            for (int i = 0; i < 4; i++)
#pragma unroll
                for (int j = 0; j < 4; j++) acc[i][j] += a[i] * w[j];
        }
        __syncthreads();
    }
#pragma unroll
    for (int i = 0; i < 4; i++) {
        int gr = row0 + ty * 4 + i;
        if (gr >= Mr) continue;
#pragma unroll
        for (int j = 0; j < 4; j++) {
            int gn = col0 + tx * 4 + j;
            if (gn >= Nc) continue;
            float c = acc[i][j] + LD<F32>(bias, gn);
            if (res) c += res[(size_t)gr * Nc + gn];
            if (do_relu) c = fmaxf(c, 0.f);
            C[(size_t)gr * Nc + gn] = c;
        }
    }
}

// ---------- weight prep: split to hi/lo bf16, transposed [Npad][Kpad], zero-padded ----------
// Split matrices (padded elems each):
//   m0:    Wa       320x320 (102400)          cum 0
//   m1-3:  WfS[t]   320x320 (rows 3..302 of Wf[t])
//   m4-6:  Wg[t]    320x320
//   m7:    Wc1      64x320  (20480)           cum 716800
//   m8-11: Wl1[c]   64x320
//   m12-15:Wl2[c]   64x64   (4096)            cum 819200
//   m16:   Wi1      128x64  (8192)            cum 835584
//   m17:   Wi2      304x128 (38912)           cum 843776
// biasF (f32): [0,300) ba | [300,1200) bf | [1200,2100) bg | [2100,2164) bc1
//            | [2164,2420) bl1 | [2420,2676) bl2 | [2676,2804) bi1 | [2804,3104) bi2
// wf3F (f32): 3 x [3][300] rows 0..2 of Wf[t] (for fused-AB GEMM epilogue)
#define PREP_SPLIT 882688
#define PREP_BIAS  3104
#define PREP_WF3   2700
#define PREP_TOT   (PREP_SPLIT + PREP_BIAS + PREP_WF3 + 32)

__global__ __launch_bounds__(256) void k_prep(
    const void* __restrict__ Wa, const void* __restrict__ Wf,
    const void* __restrict__ Wg, const void* __restrict__ Wc1,
    const void* __restrict__ Wl1, const void* __restrict__ Wl2,
    const void* __restrict__ Wi1, const void* __restrict__ Wi2,
    const void* __restrict__ ba, const void* __restrict__ bfb,
    const void* __restrict__ bgb, const void* __restrict__ bc1,
    const void* __restrict__ bl1b, const void* __restrict__ bl2b,
    const void* __restrict__ bi1, const void* __restrict__ bi2,
    unsigned short* __restrict__ SP, float* __restrict__ biasF,
    float* __restrict__ wf3F,
    float* __restrict__ bzero, const int* __restrict__ flag)
{
    int idx = blockIdx.x * 256 + threadIdx.x;
    if (idx >= PREP_TOT) return;
    bool f32 = flag[0] != 0;
    if (idx < PREP_SPLIT) {
        const void* src; long long eoff, cum; int srcN, Nn, Kk, Kpad, pe, local;
        if (idx < 716800) {
            int m = idx / 102400; local = idx - m * 102400;
            pe = 102400; cum = (long long)m * 102400;
            Kpad = 320; Nn = 300; Kk = 300; srcN = 300;
            src = (m == 0) ? Wa : (m <= 3 ? Wf : Wg);
            eoff = (m == 0) ? 0 : (m <= 3 ? (long long)((m - 1) * 303 + 3) * 300
                                          : (long long)(m - 4) * 90000);
        } else if (idx < 819200) {
            int j = (idx - 716800) / 20480; local = (idx - 716800) - j * 20480;
            pe = 20480; cum = 716800 + (long long)j * 20480;
            Kpad = 320; Nn = 64; Kk = 300; srcN = 64;
            src = (j == 0) ? Wc1 : Wl1;
            eoff = (j == 0) ? 0 : (long long)(j - 1) * 19200;
        } else if (idx < 835584) {
            int c = (idx - 819200) / 4096; local = (idx - 819200) - c * 4096;
            pe = 4096; cum = 819200 + (long long)c * 4096;
            Kpad = 64; Nn = 64; Kk = 64; srcN = 64;
            src = Wl2; eoff = (long long)c * 4096;
        } else if (idx < 843776) {
            local = idx - 835584;
            pe = 8192; cum = 835584;
            Kpad = 64; Nn = 128; Kk = 64; srcN = 128;
            src = Wi1; eoff = 0;
        } else {
            local = idx - 843776;
            pe = 38912; cum = 843776;
            Kpad = 128; Nn = 300; Kk = 128; srcN = 300;
            src = Wi2; eoff = 0;
        }
        int n = local / Kpad, k = local - n * Kpad;
        float v = 0.f;
        if (n < Nn && k < Kk) v = LDr(src, eoff + (long long)k * srcN + n, f32);
        bf16_t hi = f2bf(v);                 // RN split
        bf16_t lo = f2bf(v - bf2f(hi));      // bf16 input -> hi exact, lo = 0
        SP[2 * cum + local] = hi;
        SP[2 * cum + pe + local] = lo;
    } else if (idx < PREP_SPLIT + PREP_BIAS) {
        int b = idx - PREP_SPLIT;
        const void* src; int o;
        if (b < 300)       { src = ba;   o = b; }
        else if (b < 1200) { src = bfb;  o = b - 300; }
        else if (b < 2100) { src = bgb;  o = b - 1200; }
        else if (b < 2164) { src = bc1;  o = b - 2100; }
        else if (b < 2420) { src = bl1b; o = b - 2164; }
        else if (b < 2676) { src = bl2b; o = b - 2420; }
        else if (b < 2804) { src = bi1;  o = b - 2676; }
        else               { src = bi2;  o = b - 2804; }
        biasF[b] = LDr(src, o, f32);
    } else if (idx < PREP_SPLIT + PREP_BIAS + PREP_WF3) {
        int b2 = idx - (PREP_SPLIT + PREP_BIAS);
        int t = b2 / 900, rem = b2 - t * 900;     // rem = r*300 + c, r in [0,3)
        wf3F[b2] = LDr(Wf, (long long)t * 303 * SD + rem, f32);
    } else {
        // zero 32 floats after kpmax (== bbag[0..32)) so the K-tail overread of
        // kpmax's last row hits finite zeros on the first MFMA GEMM
        bzero[idx - (PREP_SPLIT + PREP_BIAS + PREP_WF3)] = 0.f;
    }
}

// ---------- MFMA helpers ----------
__device__ __forceinline__ void mfma16(float4_t& c, short8_t a, short8_t b) {
    asm("v_mfma_f32_16x16x32_bf16 %0, %1, %2, %0" : "+v"(c) : "v"(a), "v"(b));
}
__device__ __forceinline__ void split2(float a, float b, unsigned& h, unsigned& l) {
    asm("v_cvt_pk_bf16_f32 %0, %1, %2" : "=v"(h) : "v"(a), "v"(b));
    float la = a - __uint_as_float(h << 16);
    float lb = b - __uint_as_float(h & 0xFFFF0000u);
    asm("v_cvt_pk_bf16_f32 %0, %1, %2" : "=v"(l) : "v"(la), "v"(lb));
}
__device__ __forceinline__ void split8(float4_t x0, float4_t x1,
                                       short8_t* hi, short8_t* lo) {
    union { unsigned u[4]; short8_t v; } H, L;
#pragma unroll
    for (int p = 0; p < 4; p++) {
        float a, b;
        if (p == 0)      { a = x0[0]; b = x0[1]; }
        else if (p == 1) { a = x0[2]; b = x0[3]; }
        else if (p == 2) { a = x1[0]; b = x1[1]; }
        else             { a = x1[2]; b = x1[3]; }
        unsigned ph, pl;
        split2(a, b, ph, pl);
        H.u[p] = ph; L.u[p] = pl;
    }
    *hi = H.v; *lo = L.v;
}

// ---------- MFMA init MLP v3: 4 waves/block, column-split to halve serial chain ----
// Block = 64 kp rows. Wave w: rg=w>>1 (row group of 32), ch=w&1 (column half).
// ch splits layer1's 8 n0 -> 4 each, layer2's 19 n0 -> 10/9 each.
// LDS per row-group: h2h (32x136) + h2l; 2 groups = 34,816 B.
__global__ __launch_bounds__(256) void k_init_mfma(
    const void* __restrict__ kp,
    const void* __restrict__ Wi0, const void* __restrict__ bi0,
    const unsigned short* __restrict__ W1T,   // [128][64], lo at +8192
    const unsigned short* __restrict__ W2T,   // [304][128], lo at +38912
    const float* __restrict__ b1F, const float* __restrict__ b2F,
    float* __restrict__ kpmax, const int* __restrict__ flag)
{
    bool f32 = flag[0] != 0;
    __shared__ __attribute__((aligned(16))) unsigned short lds[2][8704]; // 34,816 B
    int tid = threadIdx.x;
    int w = tid >> 6, lane = tid & 63;
    int rg = w >> 1, ch = w & 1;
    int l15 = lane & 15, g = lane >> 4;
    unsigned short* h2h = lds[rg];
    unsigned short* h2l = lds[rg] + 4352;
    int rw0 = blockIdx.x * 64 + rg * 32;      // row-group's first kp row

    // ---- layer0 (VALU, in-register; duplicated across the ch pair) ----
    float kpr[2][4];
#pragma unroll
    for (int mt = 0; mt < 2; mt++) {
        long long r = rw0 + mt * 16 + l15;
#pragma unroll
        for (int j = 0; j < 4; j++) kpr[mt][j] = LDr(kp, r * 4 + j, f32);
    }
    short8_t a1h[2][2], a1l[2][2];
#pragma unroll
    for (int ks = 0; ks < 2; ks++) {
        float h[2][8];
#pragma unroll
        for (int e = 0; e < 8; e++) {
            int chn = ks * 32 + 8 * g + e;
            float w0 = LDr(Wi0, chn, f32),       w1 = LDr(Wi0, 64 + chn, f32);
            float w2 = LDr(Wi0, 128 + chn, f32), w3 = LDr(Wi0, 192 + chn, f32);
            float b0 = LDr(bi0, chn, f32);
#pragma unroll
            for (int mt = 0; mt < 2; mt++)
                h[mt][e] = fmaxf(b0 + kpr[mt][0] * w0 + kpr[mt][1] * w1
                                    + kpr[mt][2] * w2 + kpr[mt][3] * w3, 0.f);
        }
#pragma unroll
        for (int mt = 0; mt < 2; mt++) {
            union { unsigned u[4]; short8_t v; } H, L;
#pragma unroll
            for (int p = 0; p < 4; p++) {
                unsigned hh, ll;
                split2(h[mt][2 * p], h[mt][2 * p + 1], hh, ll);
                H.u[p] = hh; L.u[p] = ll;
            }
            a1h[mt][ks] = H.v; a1l[mt][ks] = L.v;
        }
    }

    // ---- layer1 (MFMA): this wave computes h2 cols [ch*64, ch*64+64) ----
#pragma unroll
    for (int i = 0; i < 4; i++) {
        int n0 = ch * 4 + i;
        const unsigned short* bp = W1T + (n0 * 16 + l15) * 64 + 8 * g;
        short8_t bh0 = *(const short8_t*)bp;
        short8_t bh1 = *(const short8_t*)(bp + 32);
        short8_t bl0 = *(const short8_t*)(bp + 8192);
        short8_t bl1 = *(const short8_t*)(bp + 8224);
        float4_t c0 = {0.f, 0.f, 0.f, 0.f}, c1 = {0.f, 0.f, 0.f, 0.f};
        mfma16(c0, a1h[0][0], bh0); mfma16(c0, a1h[0][1], bh1);
        mfma16(c0, a1l[0][0], bh0); mfma16(c0, a1l[0][1], bh1);
        mfma16(c0, a1h[0][0], bl0); mfma16(c0, a1h[0][1], bl1);
        mfma16(c1, a1h[1][0], bh0); mfma16(c1, a1h[1][1], bh1);
        mfma16(c1, a1l[1][0], bh0); mfma16(c1, a1l[1][1], bh1);
        mfma16(c1, a1h[1][0], bl0); mfma16(c1, a1h[1][1], bl1);
        int col = n0 * 16 + l15;
        float bv = b1F[col];
#pragma unroll
        for (int i2 = 0; i2 < 4; i2++) {
            float v0 = fmaxf(c0[i2] + bv, 0.f);         // D row 4g+i2 (m-tile 0)
            bf16_t h0 = f2bf(v0);
            h2h[(4 * g + i2) * 136 + col] = h0;
            h2l[(4 * g + i2) * 136 + col] = f2bf(v0 - bf2f(h0));
            float v1 = fmaxf(c1[i2] + bv, 0.f);         // D row 16+4g+i2 (m-tile 1)
            bf16_t h1v = f2bf(v1);
            h2h[(16 + 4 * g + i2) * 136 + col] = h1v;
            h2l[(16 + 4 * g + i2) * 136 + col] = f2bf(v1 - bf2f(h1v));
        }
    }
    __syncthreads();

    // ---- layer2 (MFMA) + segmax8: ch 0 -> n0 0..9, ch 1 -> n0 10..18 ----
    short8_t a2h[2][4], a2l[2][4];
#pragma unroll
    for (int mt = 0; mt < 2; mt++)
#pragma unroll
        for (int ks = 0; ks < 4; ks++) {
            int off = (mt * 16 + l15) * 136 + ks * 32 + 8 * g;
            a2h[mt][ks] = *(const short8_t*)(h2h + off);
            a2l[mt][ks] = *(const short8_t*)(h2l + off);
        }
    int vb = blockIdx.x * 8 + rg * 4;
    int n0beg = ch ? 10 : 0, n0end = ch ? 19 : 10;
    for (int n0 = n0beg; n0 < n0end; n0++) {
        const unsigned short* bp = W2T + (n0 * 16 + l15) * 128 + 8 * g;
        short8_t bh[4], bl[4];
#pragma unroll
        for (int ks = 0; ks < 4; ks++) {
            bh[ks] = *(const short8_t*)(bp + ks * 32);
            bl[ks] = *(const short8_t*)(bp + 38912 + ks * 32);
        }
        float4_t c0 = {0.f, 0.f, 0.f, 0.f}, c1 = {0.f, 0.f, 0.f, 0.f};
#pragma unroll
        for (int ks = 0; ks < 4; ks++) {
            mfma16(c0, a2h[0][ks], bh[ks]); mfma16(c1, a2h[1][ks], bh[ks]);
        }
#pragma unroll
        for (int ks = 0; ks < 4; ks++) {
            mfma16(c0, a2l[0][ks], bh[ks]); mfma16(c1, a2l[1][ks], bh[ks]);
        }
#pragma unroll
        for (int ks = 0; ks < 4; ks++) {
            mfma16(c0, a2h[0][ks], bl[ks]); mfma16(c1, a2h[1][ks], bl[ks]);
        }
        float m0 = fmaxf(fmaxf(c0[0], c0[1]), fmaxf(c0[2], c0[3]));
        m0 = fmaxf(m0, __shfl_xor(m0, 16));
        float m1 = fmaxf(fmaxf(c1[0], c1[1]), fmaxf(c1[2], c1[3]));
        m1 = fmaxf(m1, __shfl_xor(m1, 16));
        int col = n0 * 16 + l15;
        if (col < SD) {
            float bv = b2F[col];
            if (g == 0) {
                kpmax[(size_t)(vb + 0) * SD + col] = fmaxf(m0 + bv, 0.f);
                kpmax[(size_t)(vb + 2) * SD + col] = fmaxf(m1 + bv, 0.f);
            } else if (g == 2) {
                kpmax[(size_t)(vb + 1) * SD + col] = fmaxf(m0 + bv, 0.f);
                kpmax[(size_t)(vb + 3) * SD + col] = fmaxf(m1 + bv, 0.f);
            }
        }
    }
}

// ---------- split-bf16 MFMA GEMM (z-batched, optional fused-AB epilogue) ----------
// If posp != null: C(=ua) = A@W + bias + pos@Wf3 ; bbag = dx@Wf3 - pos@Wf3.
__global__ __launch_bounds__(256) void k_gemm_mfma(
    const float* __restrict__ A, const unsigned short* __restrict__ WhiT,
    const unsigned short* __restrict__ WloT, const float* __restrict__ bias,
    const float* __restrict__ res, float* __restrict__ C,
    int M, int K, int Kpad, int N, int relu,
    long long zA, long long zW, int zB, long long zC,
    const void* posp, const float* dxv, const float* wf3F,
    float* bbag, const int* __restrict__ flag)
{
    int z = blockIdx.z;
    A    += (size_t)z * zA;
    WhiT += (size_t)z * zW;
    WloT += (size_t)z * zW;
    bias += (size_t)z * zB;
    C    += (size_t)z * zC;
    int tid = threadIdx.x;
    int w = tid >> 6, lane = tid & 63;
    int l15 = lane & 15, g = lane >> 4;
    int row0 = blockIdx.y * 256 + w * 64;   // wave owns 64 rows
    int col0 = blockIdx.x * 64;

    float4_t acc[4][4];
#pragma unroll
    for (int i = 0; i < 4; i++)
#pragma unroll
        for (int j = 0; j < 4; j++) acc[i][j] = (float4_t){0.f, 0.f, 0.f, 0.f};

    const unsigned short* bhp[4];
    const unsigned short* blp[4];
#pragma unroll
    for (int ns = 0; ns < 4; ns++) {
        size_t o = (size_t)(col0 + ns * 16 + l15) * Kpad + 8 * g;
        bhp[ns] = WhiT + o; blp[ns] = WloT + o;
    }
    const float* app[4];
    int amode[4]; bool adead[4];
#pragma unroll
    for (int ms = 0; ms < 4; ms++) {
        int base = row0 + ms * 16;
        int gr = base + l15;
        amode[ms] = (base + 16 <= M) ? 2 : (base < M ? 1 : 0);
        adead[ms] = gr >= M;
        int grc = gr < M ? gr : (M - 1);
        app[ms] = A + (size_t)grc * K + 8 * g;
    }
    const short8_t z8 = {0, 0, 0, 0, 0, 0, 0, 0};

    for (int k0 = 0; k0 < K; k0 += 32) {
        short8_t bh[4], bl[4], ah[4], al[4];
#pragma unroll
        for (int ns = 0; ns < 4; ns++) {
            bh[ns] = *(const short8_t*)bhp[ns]; bhp[ns] += 32;
            bl[ns] = *(const short8_t*)blp[ns]; blp[ns] += 32;
        }
#pragma unroll
        for (int ms = 0; ms < 4; ms++) {
            if (amode[ms] == 0) { ah[ms] = z8; al[ms] = z8; continue; }
            float4_t x0 = *(const float4_t*)app[ms];
            float4_t x1 = *(const float4_t*)(app[ms] + 4);
            app[ms] += 32;
            if (amode[ms] == 1 && adead[ms]) {
                x0 = (float4_t){0.f, 0.f, 0.f, 0.f};
                x1 = (float4_t){0.f, 0.f, 0.f, 0.f};
            }
            split8(x0, x1, &ah[ms], &al[ms]);
        }
#pragma unroll
        for (int ms = 0; ms < 4; ms++)
#pragma unroll
            for (int ns = 0; ns < 4; ns++) {
                mfma16(acc[ms][ns], ah[ms], bh[ns]);
                mfma16(acc[ms][ns], al[ms], bh[ns]);
                mfma16(acc[ms][ns], ah[ms], bl[ns]);
            }
    }

    bool ab = posp != nullptr;
    bool pf32 = ab && (flag[0] != 0);
#pragma unroll
    for (int ns = 0; ns < 4; ns++) {
        int gn = col0 + ns * 16 + l15;
        if (gn >= N) continue;
        float bv = bias[gn];
        float w30 = 0.f, w31 = 0.f, w32 = 0.f;
        if (ab) { w30 = wf3F[gn]; w31 = wf3F[300 + gn]; w32 = wf3F[600 + gn]; }
#pragma unroll
        for (int ms = 0; ms < 4; ms++) {
            int rb = row0 + ms * 16 + 4 * g;
#pragma unroll
            for (int r = 0; r < 4; r++) {
                int gr = rb + r;
                if (gr >= M) continue;
                float c = acc[ms][ns][r] + bv;
                if (ab) {
                    float P = LDr(posp, (long long)gr * 3 + 0, pf32) * w30
                            + LDr(posp, (long long)gr * 3 + 1, pf32) * w31
                            + LDr(posp, (long long)gr * 3 + 2, pf32) * w32;
                    float D = dxv[gr * 3 + 0] * w30 + dxv[gr * 3 + 1] * w31
                            + dxv[gr * 3 + 2] * w32;
                    c += P;
                    bbag[(size_t)gr * N + gn] = D - P;
                }
                if (res) c += res[(size_t)gr * N + gn];
                if (relu) c = fmaxf(c, 0.f);
                C[(size_t)gr * N + gn] = c;
            }
        }
    }
}

// ---------- runtime-dtype single-launch small kernels (fast path) ----------
__global__ void k_dx2(const float* __restrict__ s, const void* __restrict__ Wh,
                      const void* __restrict__ bh, int t, float* __restrict__ dx,
                      const int* __restrict__ flag) {
    bool f32 = flag[0] != 0;
    long long wo = (long long)t * SD * 3, bo = (long long)t * 3;
    int wv = threadIdx.x >> 6, lane = threadIdx.x & 63;
    int v = blockIdx.x * 4 + wv;
    if (v >= N_V) return;
    float p0 = 0.f, p1 = 0.f, p2 = 0.f;
    for (int d = lane; d < SD; d += 64) {
        float sv = s[(size_t)v * SD + d];
        p0 += sv * LDr(Wh, wo + d * 3 + 0, f32);
        p1 += sv * LDr(Wh, wo + d * 3 + 1, f32);
        p2 += sv * LDr(Wh, wo + d * 3 + 2, f32);
    }
#pragma unroll
    for (int off = 32; off > 0; off >>= 1) {
        p0 += __shfl_down(p0, off);
        p1 += __shfl_down(p1, off);
        p2 += __shfl_down(p2, off);
    }
    if (lane == 0) {
        dx[v * 3 + 0] = p0 + LDr(bh, bo + 0, f32);
        dx[v * 3 + 1] = p1 + LDr(bh, bo + 1, f32);
        dx[v * 3 + 2] = p2 + LDr(bh, bo + 2, f32);
    }
}

__global__ void k_cls2(const float* __restrict__ hc, const void* __restrict__ W,
                       const void* __restrict__ b, void* __restrict__ out,
                       const int* __restrict__ flag) {
    bool f32 = flag[0] != 0;
    int v = blockIdx.x * blockDim.x + threadIdx.x;
    if (v >= N_V) return;
    float acc[4];
#pragma unroll
    for (int j = 0; j < 4; j++) acc[j] = LDr(b, j, f32);
    for (int k = 0; k < 64; k++) {
        float h = hc[(size_t)v * 64 + k];
#pragma unroll
        for (int j = 0; j < 4; j++) acc[j] += h * LDr(W, k * 4 + j, f32);
    }
#pragma unroll
    for (int j = 0; j < 4; j++) STr(out, v * 4 + j, fmaxf(acc[j], 0.f), f32);
}

// batched over classes via blockIdx.y; hl2all = 4 x [N_V,64]
__global__ void k_loc32(const float* __restrict__ hl2all, const void* __restrict__ Wl3,
                        const void* __restrict__ bl3, void* __restrict__ out,
                        const int* __restrict__ flag) {
    bool f32 = flag[0] != 0;
    int cls = blockIdx.y;
    const float* h2 = hl2all + (size_t)cls * N_V * 64;
    long long wo = (long long)cls * 64 * 7, bo = (long long)cls * 7;
    int v = blockIdx.x * blockDim.x + threadIdx.x;
    if (v >= N_V) return;
    float acc[7];
#pragma unroll
    for (int j = 0; j < 7; j++) acc[j] = LDr(bl3, bo + j, f32);
    for (int k = 0; k < 64; k++) {
        float h = h2[(size_t)v * 64 + k];
#pragma unroll
        for (int j = 0; j < 7; j++) acc[j] += h * LDr(Wl3, wo + k * 7 + j, f32);
    }
#pragma unroll
    for (int j = 0; j < 7; j++)
        STr(out, 80000 + (size_t)v * 28 + cls * 7 + j, fmaxf(acc[j], 0.f), f32);
}

// ---------- fallback-path small kernels (templated, unchanged) ----------
template<bool F32>
__global__ void k_dx(const float* __restrict__ s, const void* __restrict__ Wh,
                     const void* __restrict__ bh, float* __restrict__ dx,
                     const int* __restrict__ flag) {
    if ((flag[0] != 0) != F32) return;
    int wv = threadIdx.x >> 6, lane = threadIdx.x & 63;
    int v = blockIdx.x * 4 + wv;
    if (v >= N_V) return;
    float p0 = 0.f, p1 = 0.f, p2 = 0.f;
    for (int d = lane; d < SD; d += 64) {
        float sv = s[(size_t)v * SD + d];
        p0 += sv * LD<F32>(Wh, d * 3 + 0);
        p1 += sv * LD<F32>(Wh, d * 3 + 1);
        p2 += sv * LD<F32>(Wh, d * 3 + 2);
    }
#pragma unroll
    for (int off = 32; off > 0; off >>= 1) {
        p0 += __shfl_down(p0, off);
        p1 += __shfl_down(p1, off);
        p2 += __shfl_down(p2, off);
    }
    if (lane == 0) {
        dx[v * 3 + 0] = p0 + LD<F32>(bh, 0);
        dx[v * 3 + 1] = p1 + LD<F32>(bh, 1);
        dx[v * 3 + 2] = p2 + LD<F32>(bh, 2);
    }
}

template<bool F32>
__global__ void k_ab(const float* __restrict__ dx, const void* __restrict__ pos,
                     const void* __restrict__ Wf3, float* __restrict__ ua,
                     float* __restrict__ bbag, const int* __restrict__ flag) {
    if ((flag[0] != 0) != F32) return;
    int idx = blockIdx.x * blockDim.x + threadIdx.x;
    if (idx >= N_V * SD) return;
    int v = idx / SD, c = idx - v * SD;
    float w0 = LD<F32>(Wf3, c), w1 = LD<F32>(Wf3, SD + c), w2 = LD<F32>(Wf3, 2 * SD + c);
    float P = LD<F32>(pos, v * 3 + 0) * w0 + LD<F32>(pos, v * 3 + 1) * w1
            + LD<F32>(pos, v * 3 + 2) * w2;
    float D = dx[v * 3 + 0] * w0 + dx[v * 3 + 1] * w1 + dx[v * 3 + 2] * w2;
    ua[idx] += P;
    bbag[idx] = D - P;
}

__global__ __launch_bounds__(256) void k_aggr(
    const float* __restrict__ a, float* bbag,
    const int* __restrict__ offs, const int* __restrict__ esrc) {
    int wv = threadIdx.x >> 6, lane = threadIdx.x & 63;
    int v = blockIdx.x * 4 + wv;
    if (v >= N_V) return;
    int e0 = offs[v], e1 = offs[v + 1];
    float r0 = -3.0e38f, r1 = r0, r2 = r0, r3 = r0, r4 = r0;
    bool c4 = lane < SD - 256;
    for (int e = e0; e < e1; e++) {
        const float* ar = a + (size_t)esrc[e] * SD + lane;
        r0 = fmaxf(r0, ar[0]);
        r1 = fmaxf(r1, ar[64]);
        r2 = fmaxf(r2, ar[128]);
        r3 = fmaxf(r3, ar[192]);
        if (c4) r4 = fmaxf(r4, ar[256]);
    }
    float* bv = bbag + (size_t)v * SD + lane;
    bv[0]   = fmaxf(0.f, r0 + bv[0]);
    bv[64]  = fmaxf(0.f, r1 + bv[64]);
    bv[128] = fmaxf(0.f, r2 + bv[128]);
    bv[192] = fmaxf(0.f, r3 + bv[192]);
    if (c4) bv[256] = fmaxf(0.f, r4 + bv[256]);
}

template<bool F32>
__global__ void k_cls(const float* __restrict__ hc, const void* __restrict__ W,
                      const void* __restrict__ b, void* __restrict__ out,
                      const int* __restrict__ flag) {
    if ((flag[0] != 0) != F32) return;
    int v = blockIdx.x * blockDim.x + threadIdx.x;
    if (v >= N_V) return;
    float acc[4];
#pragma unroll
    for (int j = 0; j < 4; j++) acc[j] = LD<F32>(b, j);
    for (int k = 0; k < 64; k++) {
        float h = hc[(size_t)v * 64 + k];
#pragma unroll
        for (int j = 0; j < 4; j++) acc[j] += h * LD<F32>(W, k * 4 + j);
    }
#pragma unroll
    for (int j = 0; j < 4; j++) ST<F32>(out, v * 4 + j, fmaxf(acc[j], 0.f));
}

template<bool F32>
__global__ void k_loc3(const float* __restrict__ h2, const void* __restrict__ W,
                       const void* __restrict__ b, void* __restrict__ out, int cls,
                       const int* __restrict__ flag) {
    if ((flag[0] != 0) != F32) return;
    int v = blockIdx.x * blockDim.x + threadIdx.x;
    if (v >= N_V) return;
    float acc[7];
#pragma unroll
    for (int j = 0; j < 7; j++) acc[j] = LD<F32>(b, j);
    for (int k = 0; k < 64; k++) {
        float h = h2[(size_t)v * 64 + k];
#pragma unroll
        for (int j = 0; j < 7; j++) acc[j] += h * LD<F32>(W, k * 7 + j);
    }
#pragma unroll
    for (int j = 0; j < 7; j++)
        ST<F32>(out, 80000 + (size_t)v * 28 + cls * 7 + j, fmaxf(acc[j], 0.f));
}

#define LAUNCH2(kname, grid, blk, ...) \
    do { kname<false><<<grid, blk, 0, stream>>>(__VA_ARGS__); \
         kname<true><<<grid, blk, 0, stream>>>(__VA_ARGS__); } while (0)

extern "C" void kernel_launch(void* const* d_in, const int* in_sizes, int n_in,
                              void* d_out, int out_size, void* d_ws, size_t ws_size,
                              hipStream_t stream) {
    const void* kp  = d_in[0];
    const void* pos = d_in[1];
    const int* eidx = (const int*)d_in[3];
    const int* e_src = eidx;
    const int* e_dst = eidx + E_N;
    const void* Wi0 = d_in[4];   const void* bi0 = d_in[5];
    const void* Wi1 = d_in[6];   const void* bi1 = d_in[7];
    const void* Wi2 = d_in[8];   const void* bi2 = d_in[9];
    const void* Wa  = d_in[10];  const void* ba  = d_in[11];
    const char* Wh  = (const char*)d_in[12];  const char* bh = (const char*)d_in[13];
    const char* Wf  = (const char*)d_in[14];  const char* bff = (const char*)d_in[15];
    const char* Wg  = (const char*)d_in[16];  const char* bg = (const char*)d_in[17];
    const void* Wc1 = d_in[18];  const void* bc1 = d_in[19];
    const void* Wc2 = d_in[20];  const void* bc2 = d_in[21];
    const char* Wl1 = (const char*)d_in[22];  const char* bl1 = (const char*)d_in[23];
    const char* Wl2 = (const char*)d_in[24];  const char* bl2 = (const char*)d_in[25];
    const char* Wl3 = (const char*)d_in[26];  const char* bl3 = (const char*)d_in[27];

    char* ws = (char*)d_ws;
    // region A (24MB): kpmax (init) -> ua (GNN) -> hc -> hl1[4] (heads, sequential reuse)
    float* regA  = (float*)(ws + 0);
    float* kpmax = regA;
    float* ua    = regA;
    float* hc    = (float*)(ws + 0);
    float* hl1m  = (float*)(ws + 0);          // mf path: 4 x 5.12 MB
    float* hl1f  = (float*)(ws + 6000000);    // fallback
    float* hl2f  = (float*)(ws + 12000000);   // fallback
    // region B (24MB): bbag (GNN) -> hl2[4] (heads)
    float* bbag  = (float*)(ws + 24000000);
    float* hl2m  = (float*)(ws + 24000000);
    // region C (24MB): s
    float* s     = (float*)(ws + 48000000);
    // small stuff
    int*   cnt   = (int*)(ws + 72000000);
    int*   offs  = (int*)(ws + 72100000);
    int*   cur   = (int*)(ws + 72200000);
    int*   esrc  = (int*)(ws + 72300000);
    float* dx    = (float*)(ws + 73600000);   // ends 73,840,000
    float* wf3F  = (float*)(ws + 73844000);   // 10.8 KB, ends 73,854,800
    int*   flag  = (int*)(ws + 73900000);
    // MFMA-path extras
    unsigned short* SPLIT = (unsigned short*)(ws + 73950000); // 3.53 MB
    float* biasF = (float*)(ws + 77481000);                   // 12.4 KB
    // total footprint < 77.5 MB

    bool mf = (ws_size == 0) || (ws_size >= (size_t)77500000);
    auto HI = [&](long long cum) { return SPLIT + 2 * cum; };

    // ----- dtype detect -----
    k_detect<<<1, 128, 0, stream>>>((const unsigned*)Wi0, flag);

    // ----- CSR build -----
    k_zero<<<(N_V + 255) / 256, 256, 0, stream>>>(cnt, N_V);
    k_hist<<<(E_N + 255) / 256, 256, 0, stream>>>(e_dst, cnt);
    k_scan<<<1, 1024, 0, stream>>>(cnt, offs, cur);
    k_scatter<<<(E_N + 255) / 256, 256, 0, stream>>>(e_src, e_dst, cur, esrc);

    // ----- weight prep for MFMA path -----
    if (mf)
        k_prep<<<(PREP_TOT + 255) / 256, 256, 0, stream>>>(
            Wa, Wf, Wg, Wc1, Wl1, Wl2, Wi1, Wi2,
            ba, bff, bg, bc1, bl1, bl2, bi1, bi2,
            SPLIT, biasF, wf3F, bbag, flag);

    // ----- init MLP + segmax -----
    if (mf) {
        const unsigned short* W1T = SPLIT + 2LL * 835584;
        const unsigned short* W2T = SPLIT + 2LL * 843776;
        k_init_mfma<<<M_KP / 64, 256, 0, stream>>>(kp, Wi0, bi0, W1T, W2T,
                                                   biasF + 2676, biasF + 2804,
                                                   kpmax, flag);
    } else {
        LAUNCH2(k_init_fused, M_KP / 64, 256, kp, Wi0, bi0, Wi1, bi1, Wi2, bi2, kpmax, flag);
    }

    const dim3 GSD(5, (N_V + 255) / 256);   // N=300 tiles x row-blocks of 256
    const dim3 G64(1, (N_V + 255) / 256);   // N=64 heads
    if (mf) {
        k_gemm_mfma<<<GSD, 256, 0, stream>>>(kpmax, HI(0), HI(0) + 102400,
                                             biasF, nullptr, s, N_V, SD, 320, SD, 1,
                                             0, 0, 0, 0,
                                             nullptr, nullptr, nullptr, nullptr, nullptr);
    } else {
        dim3 g((SD + 63) / 64, (N_V + 63) / 64);
        LAUNCH2(k_gemm, g, 256, kpmax, Wa, ba, nullptr, s, N_V, SD, SD, 1, flag);
    }

    // ----- GNN iterations -----
    for (int t = 0; t < T_IT; t++) {
        dim3 g5((SD + 63) / 64, (N_V + 63) / 64);
        if (mf) {
            k_dx2<<<(N_V + 3) / 4, 256, 0, stream>>>(s, Wh, bh, t, dx, flag);
            long long cum = (long long)(1 + t) * 102400;
            // ua = s@WfS + bf + pos@Wf3 ; bbag = dx@Wf3 - pos@Wf3 (fused)
            k_gemm_mfma<<<GSD, 256, 0, stream>>>(s, HI(cum), HI(cum) + 102400,
                                                 biasF + 300 + t * 300, nullptr, ua,
                                                 N_V, SD, 320, SD, 0, 0, 0, 0, 0,
                                                 pos, dx, wf3F + t * 900, bbag, flag);
        } else {
            for (int f32v = 0; f32v < 2; f32v++) {
                size_t es = f32v ? 4 : 2;
                const void* Wf_t = Wf + (size_t)t * 303 * SD * es;
                const void* WfS  = Wf + ((size_t)t * 303 + 3) * SD * es;
                const void* bf_t = bff + (size_t)t * SD * es;
                const void* Wh_t = Wh + (size_t)t * SD * 3 * es;
                const void* bh_t = bh + (size_t)t * 3 * es;
                if (f32v) {
                    k_gemm<true><<<g5, 256, 0, stream>>>(s, WfS, bf_t, nullptr, ua, N_V, SD, SD, 0, flag);
                    k_dx<true><<<(N_V + 3) / 4, 256, 0, stream>>>(s, Wh_t, bh_t, dx, flag);
                    k_ab<true><<<(N_V * SD + 255) / 256, 256, 0, stream>>>(dx, pos, Wf_t, ua, bbag, flag);
                } else {
                    k_gemm<false><<<g5, 256, 0, stream>>>(s, WfS, bf_t, nullptr, ua, N_V, SD, SD, 0, flag);
                    k_dx<false><<<(N_V + 3) / 4, 256, 0, stream>>>(s, Wh_t, bh_t, dx, flag);
                    k_ab<false><<<(N_V * SD + 255) / 256, 256, 0, stream>>>(dx, pos, Wf_t, ua, bbag, flag);
                }
            }
        }
        k_aggr<<<(N_V + 3) / 4, 256, 0, stream>>>(ua, bbag, offs, esrc);
        if (mf) {
            long long cum = (long long)(4 + t) * 102400;
            k_gemm_mfma<<<GSD, 256, 0, stream>>>(bbag, HI(cum), HI(cum) + 102400,
                                                 biasF + 1200 + t * 300, s, s,
                                                 N_V, SD, 320, SD, 0, 0, 0, 0, 0,
                                                 nullptr, nullptr, nullptr, nullptr, nullptr);
        } else {
            for (int f32v = 0; f32v < 2; f32v++) {
                size_t es = f32v ? 4 : 2;
                const void* Wg_t = Wg + (size_t)t * SD * SD * es;
                const void* bg_t = bg + (size_t)t * SD * es;
                if (f32v)
                    k_gemm<true><<<g5, 256, 0, stream>>>(bbag, Wg_t, bg_t, s, s, N_V, SD, SD, 0, flag);
                else
                    k_gemm<false><<<g5, 256, 0, stream>>>(bbag, Wg_t, bg_t, s, s, N_V, SD, SD, 0, flag);
            }
        }
    }

    // ----- heads -----
    if (mf) {
        k_gemm_mfma<<<G64, 256, 0, stream>>>(s, HI(716800), HI(716800) + 20480,
                                             biasF + 2100, nullptr, hc,
                                             N_V, SD, 320, 64, 1, 0, 0, 0, 0,
                                             nullptr, nullptr, nullptr, nullptr, nullptr);
        k_cls2<<<(N_V + 255) / 256, 256, 0, stream>>>(hc, Wc2, bc2, d_out, flag);
        dim3 gz1(1, (N_V + 255) / 256, 4);
        k_gemm_mfma<<<gz1, 256, 0, stream>>>(s, HI(737280), HI(737280) + 20480,
                                             biasF + 2164, nullptr, hl1m,
                                             N_V, SD, 320, 64, 1,
                                             0, 40960, 64, 1280000,
                                             nullptr, nullptr, nullptr, nullptr, nullptr);
        k_gemm_mfma<<<gz1, 256, 0, stream>>>(hl1m, HI(819200), HI(819200) + 4096,
                                             biasF + 2420, nullptr, hl2m,
                                             N_V, 64, 64, 64, 1,
                                             1280000, 8192, 64, 1280000,
                                             nullptr, nullptr, nullptr, nullptr, nullptr);
        dim3 gz3((N_V + 255) / 256, 4);
        k_loc32<<<gz3, 256, 0, stream>>>(hl2m, Wl3, bl3, d_out, flag);
    } else {
        dim3 g(1, (N_V + 63) / 64);
        LAUNCH2(k_gemm, g, 256, s, Wc1, bc1, nullptr, hc, N_V, SD, 64, 1, flag);
        LAUNCH2(k_cls, (N_V + 255) / 256, 256, hc, Wc2, bc2, d_out, flag);
        for (int c = 0; c < 4; c++) {
            for (int f32v = 0; f32v < 2; f32v++) {
                size_t es = f32v ? 4 : 2;
                const void* Wl1c = Wl1 + (size_t)c * SD * 64 * es;
                const void* bl1c = bl1 + (size_t)c * 64 * es;
                const void* Wl2c = Wl2 + (size_t)c * 64 * 64 * es;
                const void* bl2c = bl2 + (size_t)c * 64 * es;
                const void* Wl3c = Wl3 + (size_t)c * 64 * 7 * es;
                const void* bl3c = bl3 + (size_t)c * 7 * es;
                if (f32v) {
                    k_gemm<true><<<g, 256, 0, stream>>>(s, Wl1c, bl1c, nullptr, hl1f, N_V, SD, 64, 1, flag);
                    k_gemm<true><<<g, 256, 0, stream>>>(hl1f, Wl2c, bl2c, nullptr, hl2f, N_V, 64, 64, 1, flag);
                    k_loc3<true><<<(N_V + 255) / 256, 256, 0, stream>>>(hl2f, Wl3c, bl3c, d_out, c, flag);
                } else {
                    k_gemm<false><<<g, 256, 0, stream>>>(s, Wl1c, bl1c, nullptr, hl1f, N_V, SD, 64, 1, flag);
                    k_gemm<false><<<g, 256, 0, stream>>>(hl1f, Wl2c, bl2c, nullptr, hl2f, N_V, 64, 64, 1, flag);
                    k_loc3<false><<<(N_V + 255) / 256, 256, 0, stream>>>(hl2f, Wl3c, bl3c, d_out, c, flag);
                }
            }
        }
    }
}

// Round 9
// 1181.888 us; speedup vs baseline: 1.0069x; 1.0069x over previous
//
#include <hip/hip_runtime.h>
#include <stdint.h>

#define N_V   20000
#define M_KP  160000
#define E_N   320000
#define SD    300
#define T_IT  3

typedef unsigned short bf16_t;
typedef __attribute__((ext_vector_type(8))) short short8_t;
typedef __attribute__((ext_vector_type(4))) float float4_t;

__device__ __forceinline__ float bf2f(bf16_t u) {
    return __uint_as_float(((unsigned)u) << 16);
}
__device__ __forceinline__ bf16_t f2bf(float f) {
    unsigned u = __float_as_uint(f);
    unsigned r = (u + 0x7FFFu + ((u >> 16) & 1u)) >> 16;
    return (bf16_t)r;
}

template<bool F32>
__device__ __forceinline__ float LD(const void* p, size_t i) {
    if (F32) return ((const float*)p)[i];
    return bf2f(((const bf16_t*)p)[i]);
}
template<bool F32>
__device__ __forceinline__ void ST(void* p, size_t i, float v) {
    if (F32) ((float*)p)[i] = v;
    else     ((bf16_t*)p)[i] = f2bf(v);
}
__device__ __forceinline__ float LDr(const void* p, long long i, bool f32) {
    return f32 ? ((const float*)p)[i] : bf2f(((const bf16_t*)p)[i]);
}
__device__ __forceinline__ void STr(void* p, size_t i, float v, bool f32) {
    if (f32) ((float*)p)[i] = v;
    else     ((bf16_t*)p)[i] = f2bf(v);
}

// ---------- dtype detect: flag=1 if float inputs are f32, 0 if bf16 ----------
__global__ void k_detect(const unsigned* __restrict__ w, int* __restrict__ flag) {
    __shared__ int cnt_s;
    if (threadIdx.x == 0) cnt_s = 0;
    __syncthreads();
    unsigned u = w[threadIdx.x];          // 128 dwords = 512B, safe for either dtype
    unsigned lo = u & 0xFFFFu;
    int e = (lo >> 7) & 0xFF;
    int plaus = (lo == 0u) || (e >= 96 && e <= 126);
    atomicAdd(&cnt_s, plaus);
    __syncthreads();
    if (threadIdx.x == 0) flag[0] = (cnt_s >= 64) ? 0 : 1;
}

// ---------- CSR build (dst-grouped edges) ----------
__global__ void k_zero(int* p, int n) {
    int i = blockIdx.x * blockDim.x + threadIdx.x;
    if (i < n) p[i] = 0;
}
__global__ void k_hist(const int* __restrict__ dst, int* __restrict__ cnt) {
    int e = blockIdx.x * blockDim.x + threadIdx.x;
    if (e < E_N) atomicAdd(&cnt[dst[e]], 1);
}
__global__ void k_scan(const int* __restrict__ cnt, int* __restrict__ offs,
                       int* __restrict__ cur) {
    __shared__ int buf[1024];
    __shared__ int carry_s;
    int tid = threadIdx.x;
    if (tid == 0) { carry_s = 0; offs[0] = 0; }
    __syncthreads();
    for (int base = 0; base < N_V; base += 1024) {
        int i = base + tid;
        int v = (i < N_V) ? cnt[i] : 0;
        buf[tid] = v;
        __syncthreads();
        for (int off = 1; off < 1024; off <<= 1) {
            int t = (tid >= off) ? buf[tid - off] : 0;
            __syncthreads();
            buf[tid] += t;
            __syncthreads();
        }
        int incl = buf[tid] + carry_s;
        if (i < N_V) { offs[i + 1] = incl; cur[i] = incl - v; }
        __syncthreads();
        if (tid == 1023) carry_s = incl;
        __syncthreads();
    }
}
__global__ void k_scatter(const int* __restrict__ src, const int* __restrict__ dst,
                          int* __restrict__ cur, int* __restrict__ esrc) {
    int e = blockIdx.x * blockDim.x + threadIdx.x;
    if (e < E_N) {
        int p = atomicAdd(&cur[dst[e]], 1);
        esrc[p] = src[e];
    }
}

// ---------- fused init MLP (fallback VALU path) ----------
template<bool F32>
__global__ __launch_bounds__(256) void k_init_fused(
    const void* __restrict__ kp,
    const void* __restrict__ Wi0, const void* __restrict__ bi0,
    const void* __restrict__ Wi1, const void* __restrict__ bi1,
    const void* __restrict__ Wi2, const void* __restrict__ bi2,
    float* __restrict__ kpmax, const int* __restrict__ flag) {
    if ((flag[0] != 0) != F32) return;
    __shared__ float kps[256];
    __shared__ float h1s[64][64];
    __shared__ float h2s[64 * 128];
    int tid = threadIdx.x;
    int row0 = blockIdx.x * 64;
    kps[tid] = LD<F32>(kp, (size_t)row0 * 4 + tid);
    __syncthreads();
    {
        int c = tid & 63;
        float w0 = LD<F32>(Wi0, c), w1 = LD<F32>(Wi0, 64 + c);
        float w2 = LD<F32>(Wi0, 128 + c), w3 = LD<F32>(Wi0, 192 + c);
        float b0 = LD<F32>(bi0, c);
        int rbase = (tid >> 6) * 16;
#pragma unroll
        for (int rr = 0; rr < 16; rr++) {
            int r = rbase + rr;
            float a = b0 + kps[r * 4] * w0 + kps[r * 4 + 1] * w1
                         + kps[r * 4 + 2] * w2 + kps[r * 4 + 3] * w3;
            h1s[r][c] = fmaxf(a, 0.f);
        }
    }
    __syncthreads();
    {
        int c = tid & 127;
        int rbase = (tid >> 7) * 32;
        float b1 = LD<F32>(bi1, c);
        float acc[32];
#pragma unroll
        for (int rr = 0; rr < 32; rr++) acc[rr] = b1;
        for (int k = 0; k < 64; k++) {
            float wv = LD<F32>(Wi1, (size_t)k * 128 + c);
#pragma unroll
            for (int rr = 0; rr < 32; rr++) acc[rr] += h1s[rbase + rr][k] * wv;
        }
#pragma unroll
        for (int rr = 0; rr < 32; rr++)
            h2s[(size_t)(rbase + rr) * 128 + c] = fmaxf(acc[rr], 0.f);
    }
    __syncthreads();
    {
        int cx = tid & 63, rg = tid >> 6;
        float acc[16][5];
#pragma unroll
        for (int r = 0; r < 16; r++)
#pragma unroll
            for (int j = 0; j < 5; j++) acc[r][j] = 0.f;
        bool ok4 = (cx < SD - 256);
        for (int k = 0; k < 128; k++) {
            float w[5];
#pragma unroll
            for (int j = 0; j < 4; j++) w[j] = LD<F32>(Wi2, (size_t)k * SD + cx + 64 * j);
            w[4] = ok4 ? LD<F32>(Wi2, (size_t)k * SD + cx + 256) : 0.f;
#pragma unroll
            for (int r = 0; r < 16; r++) {
                float av = h2s[(rg * 16 + r) * 128 + k];
#pragma unroll
                for (int j = 0; j < 5; j++) acc[r][j] += av * w[j];
            }
        }
        int vbase = (row0 >> 3) + rg * 2;
#pragma unroll
        for (int half = 0; half < 2; half++) {
            int v = vbase + half;
#pragma unroll
            for (int j = 0; j < 5; j++) {
                int c = cx + 64 * j;
                if (c >= SD) continue;
                float m = acc[half * 8][j];
#pragma unroll
                for (int r = 1; r < 8; r++) m = fmaxf(m, acc[half * 8 + r][j]);
                kpmax[(size_t)v * SD + c] = fmaxf(m + LD<F32>(bi2, c), 0.f);
            }
        }
    }
}

// ---------- generic tiled f32 GEMM (fallback path only) ----------
template<bool F32>
__global__ __launch_bounds__(256) void k_gemm(
    const float* __restrict__ A, const void* __restrict__ W,
    const void* __restrict__ bias, const float* res,
    float* C, int Mr, int K, int Nc, int do_relu, const int* __restrict__ flag) {
    if ((flag[0] != 0) != F32) return;
    __shared__ float As[16][65];
    __shared__ float Ws[16][64];
    int tid = threadIdx.x;
    int tx = tid & 15, ty = tid >> 4;
    int row0 = blockIdx.y * 64, col0 = blockIdx.x * 64;
    float acc[4][4] = {{0.f}};
    int lk = tid & 15, lr = tid >> 4;
    int ln = tid & 63, lk4 = tid >> 6;
    for (int k0 = 0; k0 < K; k0 += 16) {
#pragma unroll
        for (int i = 0; i < 4; i++) {
            int r = lr + i * 16;
            int gr = row0 + r, gk = k0 + lk;
            As[lk][r] = (gr < Mr && gk < K) ? A[(size_t)gr * K + gk] : 0.f;
        }
#pragma unroll
        for (int p = 0; p < 4; p++) {
            int kk = lk4 + p * 4;
            int gk = k0 + kk, gn = col0 + ln;
            Ws[kk][ln] = (gk < K && gn < Nc) ? LD<F32>(W, (size_t)gk * Nc + gn) : 0.f;
        }
        __syncthreads();
#pragma unroll
        for (int kk = 0; kk < 16; kk++) {
            float a[4], w[4];
#pragma unroll
            for (int i = 0; i < 4; i++) a[i] = As[kk][ty * 4 + i];
#pragma unroll
            for (int j = 0; j < 4; j++) w[j] = Ws[kk][tx * 4 + j];
#pragma unroll
            for (int i = 0; i < 4; i++)
#pragma unroll
                for (int j = 0; j < 4; j++) acc[i][j] += a[i] * w[j];
        }
        __syncthreads();
    }
#pragma unroll
    for (int i = 0; i < 4; i++) {
        int gr = row0 + ty * 4 + i;
        if (gr >= Mr) continue;
#pragma unroll
        for (int j = 0; j < 4; j++) {
            int gn = col0 + tx * 4 + j;
            if (gn >= Nc) continue;
            float c = acc[i][j] + LD<F32>(bias, gn);
            if (res) c += res[(size_t)gr * Nc + gn];
            if (do_relu) c = fmaxf(c, 0.f);
            C[(size_t)gr * Nc + gn] = c;
        }
    }
}

// ---------- weight prep: split to hi/lo bf16, transposed [Npad][Kpad], zero-padded ----------
// Split matrices (padded elems each):
//   m0:    Wa       320x320 (102400)          cum 0
//   m1-3:  WfS[t]   320x320 (rows 3..302 of Wf[t])
//   m4-6:  Wg[t]    320x320
//   m7:    Wc1      64x320  (20480)           cum 716800
//   m8-11: Wl1[c]   64x320
//   m12-15:Wl2[c]   64x64   (4096)            cum 819200
//   m16:   Wi1      128x64  (8192)            cum 835584
//   m17:   Wi2      304x128 (38912)           cum 843776
// biasF (f32): [0,300) ba | [300,1200) bf | [1200,2100) bg | [2100,2164) bc1
//            | [2164,2420) bl1 | [2420,2676) bl2 | [2676,2804) bi1 | [2804,3104) bi2
// wf3F (f32): 3 x [3][300] rows 0..2 of Wf[t] (for fused-AB GEMM epilogue)
#define PREP_SPLIT 882688
#define PREP_BIAS  3104
#define PREP_WF3   2700
#define PREP_TOT   (PREP_SPLIT + PREP_BIAS + PREP_WF3 + 32)

__global__ __launch_bounds__(256) void k_prep(
    const void* __restrict__ Wa, const void* __restrict__ Wf,
    const void* __restrict__ Wg, const void* __restrict__ Wc1,
    const void* __restrict__ Wl1, const void* __restrict__ Wl2,
    const void* __restrict__ Wi1, const void* __restrict__ Wi2,
    const void* __restrict__ ba, const void* __restrict__ bfb,
    const void* __restrict__ bgb, const void* __restrict__ bc1,
    const void* __restrict__ bl1b, const void* __restrict__ bl2b,
    const void* __restrict__ bi1, const void* __restrict__ bi2,
    unsigned short* __restrict__ SP, float* __restrict__ biasF,
    float* __restrict__ wf3F,
    float* __restrict__ bzero, const int* __restrict__ flag)
{
    int idx = blockIdx.x * 256 + threadIdx.x;
    if (idx >= PREP_TOT) return;
    bool f32 = flag[0] != 0;
    if (idx < PREP_SPLIT) {
        const void* src; long long eoff, cum; int srcN, Nn, Kk, Kpad, pe, local;
        if (idx < 716800) {
            int m = idx / 102400; local = idx - m * 102400;
            pe = 102400; cum = (long long)m * 102400;
            Kpad = 320; Nn = 300; Kk = 300; srcN = 300;
            src = (m == 0) ? Wa : (m <= 3 ? Wf : Wg);
            eoff = (m == 0) ? 0 : (m <= 3 ? (long long)((m - 1) * 303 + 3) * 300
                                          : (long long)(m - 4) * 90000);
        } else if (idx < 819200) {
            int j = (idx - 716800) / 20480; local = (idx - 716800) - j * 20480;
            pe = 20480; cum = 716800 + (long long)j * 20480;
            Kpad = 320; Nn = 64; Kk = 300; srcN = 64;
            src = (j == 0) ? Wc1 : Wl1;
            eoff = (j == 0) ? 0 : (long long)(j - 1) * 19200;
        } else if (idx < 835584) {
            int c = (idx - 819200) / 4096; local = (idx - 819200) - c * 4096;
            pe = 4096; cum = 819200 + (long long)c * 4096;
            Kpad = 64; Nn = 64; Kk = 64; srcN = 64;
            src = Wl2; eoff = (long long)c * 4096;
        } else if (idx < 843776) {
            local = idx - 835584;
            pe = 8192; cum = 835584;
            Kpad = 64; Nn = 128; Kk = 64; srcN = 128;
            src = Wi1; eoff = 0;
        } else {
            local = idx - 843776;
            pe = 38912; cum = 843776;
            Kpad = 128; Nn = 300; Kk = 128; srcN = 300;
            src = Wi2; eoff = 0;
        }
        int n = local / Kpad, k = local - n * Kpad;
        float v = 0.f;
        if (n < Nn && k < Kk) v = LDr(src, eoff + (long long)k * srcN + n, f32);
        bf16_t hi = f2bf(v);                 // RN split
        bf16_t lo = f2bf(v - bf2f(hi));      // bf16 input -> hi exact, lo = 0
        SP[2 * cum + local] = hi;
        SP[2 * cum + pe + local] = lo;
    } else if (idx < PREP_SPLIT + PREP_BIAS) {
        int b = idx - PREP_SPLIT;
        const void* src; int o;
        if (b < 300)       { src = ba;   o = b; }
        else if (b < 1200) { src = bfb;  o = b - 300; }
        else if (b < 2100) { src = bgb;  o = b - 1200; }
        else if (b < 2164) { src = bc1;  o = b - 2100; }
        else if (b < 2420) { src = bl1b; o = b - 2164; }
        else if (b < 2676) { src = bl2b; o = b - 2420; }
        else if (b < 2804) { src = bi1;  o = b - 2676; }
        else               { src = bi2;  o = b - 2804; }
        biasF[b] = LDr(src, o, f32);
    } else if (idx < PREP_SPLIT + PREP_BIAS + PREP_WF3) {
        int b2 = idx - (PREP_SPLIT + PREP_BIAS);
        int t = b2 / 900, rem = b2 - t * 900;     // rem = r*300 + c, r in [0,3)
        wf3F[b2] = LDr(Wf, (long long)t * 303 * SD + rem, f32);
    } else {
        // zero 32 floats after kpmax (== bbag[0..32)) so the K-tail overread of
        // kpmax's last row hits finite zeros on the first MFMA GEMM
        bzero[idx - (PREP_SPLIT + PREP_BIAS + PREP_WF3)] = 0.f;
    }
}

// ---------- MFMA helpers ----------
__device__ __forceinline__ void mfma16(float4_t& c, short8_t a, short8_t b) {
    asm("v_mfma_f32_16x16x32_bf16 %0, %1, %2, %0" : "+v"(c) : "v"(a), "v"(b));
}
__device__ __forceinline__ void split2(float a, float b, unsigned& h, unsigned& l) {
    asm("v_cvt_pk_bf16_f32 %0, %1, %2" : "=v"(h) : "v"(a), "v"(b));
    float la = a - __uint_as_float(h << 16);
    float lb = b - __uint_as_float(h & 0xFFFF0000u);
    asm("v_cvt_pk_bf16_f32 %0, %1, %2" : "=v"(l) : "v"(la), "v"(lb));
}
__device__ __forceinline__ void split8(float4_t x0, float4_t x1,
                                       short8_t* hi, short8_t* lo) {
    union { unsigned u[4]; short8_t v; } H, L;
#pragma unroll
    for (int p = 0; p < 4; p++) {
        float a, b;
        if (p == 0)      { a = x0[0]; b = x0[1]; }
        else if (p == 1) { a = x0[2]; b = x0[3]; }
        else if (p == 2) { a = x1[0]; b = x1[1]; }
        else             { a = x1[2]; b = x1[3]; }
        unsigned ph, pl;
        split2(a, b, ph, pl);
        H.u[p] = ph; L.u[p] = pl;
    }
    *hi = H.v; *lo = L.v;
}

// ---------- MFMA init MLP v3: 4 waves/block, column-split (unchanged from r7) ----
__global__ __launch_bounds__(256) void k_init_mfma(
    const void* __restrict__ kp,
    const void* __restrict__ Wi0, const void* __restrict__ bi0,
    const unsigned short* __restrict__ W1T,   // [128][64], lo at +8192
    const unsigned short* __restrict__ W2T,   // [304][128], lo at +38912
    const float* __restrict__ b1F, const float* __restrict__ b2F,
    float* __restrict__ kpmax, const int* __restrict__ flag)
{
    bool f32 = flag[0] != 0;
    __shared__ __attribute__((aligned(16))) unsigned short lds[2][8704]; // 34,816 B
    int tid = threadIdx.x;
    int w = tid >> 6, lane = tid & 63;
    int rg = w >> 1, ch = w & 1;
    int l15 = lane & 15, g = lane >> 4;
    unsigned short* h2h = lds[rg];
    unsigned short* h2l = lds[rg] + 4352;
    int rw0 = blockIdx.x * 64 + rg * 32;      // row-group's first kp row

    float kpr[2][4];
#pragma unroll
    for (int mt = 0; mt < 2; mt++) {
        long long r = rw0 + mt * 16 + l15;
#pragma unroll
        for (int j = 0; j < 4; j++) kpr[mt][j] = LDr(kp, r * 4 + j, f32);
    }
    short8_t a1h[2][2], a1l[2][2];
#pragma unroll
    for (int ks = 0; ks < 2; ks++) {
        float h[2][8];
#pragma unroll
        for (int e = 0; e < 8; e++) {
            int chn = ks * 32 + 8 * g + e;
            float w0 = LDr(Wi0, chn, f32),       w1 = LDr(Wi0, 64 + chn, f32);
            float w2 = LDr(Wi0, 128 + chn, f32), w3 = LDr(Wi0, 192 + chn, f32);
            float b0 = LDr(bi0, chn, f32);
#pragma unroll
            for (int mt = 0; mt < 2; mt++)
                h[mt][e] = fmaxf(b0 + kpr[mt][0] * w0 + kpr[mt][1] * w1
                                    + kpr[mt][2] * w2 + kpr[mt][3] * w3, 0.f);
        }
#pragma unroll
        for (int mt = 0; mt < 2; mt++) {
            union { unsigned u[4]; short8_t v; } H, L;
#pragma unroll
            for (int p = 0; p < 4; p++) {
                unsigned hh, ll;
                split2(h[mt][2 * p], h[mt][2 * p + 1], hh, ll);
                H.u[p] = hh; L.u[p] = ll;
            }
            a1h[mt][ks] = H.v; a1l[mt][ks] = L.v;
        }
    }

#pragma unroll
    for (int i = 0; i < 4; i++) {
        int n0 = ch * 4 + i;
        const unsigned short* bp = W1T + (n0 * 16 + l15) * 64 + 8 * g;
        short8_t bh0 = *(const short8_t*)bp;
        short8_t bh1 = *(const short8_t*)(bp + 32);
        short8_t bl0 = *(const short8_t*)(bp + 8192);
        short8_t bl1 = *(const short8_t*)(bp + 8224);
        float4_t c0 = {0.f, 0.f, 0.f, 0.f}, c1 = {0.f, 0.f, 0.f, 0.f};
        mfma16(c0, a1h[0][0], bh0); mfma16(c0, a1h[0][1], bh1);
        mfma16(c0, a1l[0][0], bh0); mfma16(c0, a1l[0][1], bh1);
        mfma16(c0, a1h[0][0], bl0); mfma16(c0, a1h[0][1], bl1);
        mfma16(c1, a1h[1][0], bh0); mfma16(c1, a1h[1][1], bh1);
        mfma16(c1, a1l[1][0], bh0); mfma16(c1, a1l[1][1], bh1);
        mfma16(c1, a1h[1][0], bl0); mfma16(c1, a1h[1][1], bl1);
        int col = n0 * 16 + l15;
        float bv = b1F[col];
#pragma unroll
        for (int i2 = 0; i2 < 4; i2++) {
            float v0 = fmaxf(c0[i2] + bv, 0.f);
            bf16_t h0 = f2bf(v0);
            h2h[(4 * g + i2) * 136 + col] = h0;
            h2l[(4 * g + i2) * 136 + col] = f2bf(v0 - bf2f(h0));
            float v1 = fmaxf(c1[i2] + bv, 0.f);
            bf16_t h1v = f2bf(v1);
            h2h[(16 + 4 * g + i2) * 136 + col] = h1v;
            h2l[(16 + 4 * g + i2) * 136 + col] = f2bf(v1 - bf2f(h1v));
        }
    }
    __syncthreads();

    short8_t a2h[2][4], a2l[2][4];
#pragma unroll
    for (int mt = 0; mt < 2; mt++)
#pragma unroll
        for (int ks = 0; ks < 4; ks++) {
            int off = (mt * 16 + l15) * 136 + ks * 32 + 8 * g;
            a2h[mt][ks] = *(const short8_t*)(h2h + off);
            a2l[mt][ks] = *(const short8_t*)(h2l + off);
        }
    int vb = blockIdx.x * 8 + rg * 4;
    int n0beg = ch ? 10 : 0, n0end = ch ? 19 : 10;
    for (int n0 = n0beg; n0 < n0end; n0++) {
        const unsigned short* bp = W2T + (n0 * 16 + l15) * 128 + 8 * g;
        short8_t bh[4], bl[4];
#pragma unroll
        for (int ks = 0; ks < 4; ks++) {
            bh[ks] = *(const short8_t*)(bp + ks * 32);
            bl[ks] = *(const short8_t*)(bp + 38912 + ks * 32);
        }
        float4_t c0 = {0.f, 0.f, 0.f, 0.f}, c1 = {0.f, 0.f, 0.f, 0.f};
#pragma unroll
        for (int ks = 0; ks < 4; ks++) {
            mfma16(c0, a2h[0][ks], bh[ks]); mfma16(c1, a2h[1][ks], bh[ks]);
        }
#pragma unroll
        for (int ks = 0; ks < 4; ks++) {
            mfma16(c0, a2l[0][ks], bh[ks]); mfma16(c1, a2l[1][ks], bh[ks]);
        }
#pragma unroll
        for (int ks = 0; ks < 4; ks++) {
            mfma16(c0, a2h[0][ks], bl[ks]); mfma16(c1, a2h[1][ks], bl[ks]);
        }
        float m0 = fmaxf(fmaxf(c0[0], c0[1]), fmaxf(c0[2], c0[3]));
        m0 = fmaxf(m0, __shfl_xor(m0, 16));
        float m1 = fmaxf(fmaxf(c1[0], c1[1]), fmaxf(c1[2], c1[3]));
        m1 = fmaxf(m1, __shfl_xor(m1, 16));
        int col = n0 * 16 + l15;
        if (col < SD) {
            float bv = b2F[col];
            if (g == 0) {
                kpmax[(size_t)(vb + 0) * SD + col] = fmaxf(m0 + bv, 0.f);
                kpmax[(size_t)(vb + 2) * SD + col] = fmaxf(m1 + bv, 0.f);
            } else if (g == 2) {
                kpmax[(size_t)(vb + 1) * SD + col] = fmaxf(m0 + bv, 0.f);
                kpmax[(size_t)(vb + 3) * SD + col] = fmaxf(m1 + bv, 0.f);
            }
        }
    }
}

// ---------- split-bf16 MFMA GEMM v2: 32x64 per wave, ping-pong prefetch ----------
// Grid: x = ceil(N/64), y = ceil(M/128), z batched. Requires (K+31)/32 EVEN
// (K=300 -> 10 iters, K=64 -> 2 iters).
// If posp != null: C(=ua) = A@W + bias + pos@Wf3 ; bbag = dx@Wf3 - pos@Wf3.
__global__ __launch_bounds__(256) void k_gemm_mfma(
    const float* __restrict__ A, const unsigned short* __restrict__ WhiT,
    const unsigned short* __restrict__ WloT, const float* __restrict__ bias,
    const float* __restrict__ res, float* __restrict__ C,
    int M, int K, int Kpad, int N, int relu,
    long long zA, long long zW, int zB, long long zC,
    const void* posp, const float* dxv, const float* wf3F,
    float* bbag, const int* __restrict__ flag)
{
    int z = blockIdx.z;
    A    += (size_t)z * zA;
    WhiT += (size_t)z * zW;
    WloT += (size_t)z * zW;
    bias += (size_t)z * zB;
    C    += (size_t)z * zC;
    int tid = threadIdx.x;
    int w = tid >> 6, lane = tid & 63;
    int l15 = lane & 15, g = lane >> 4;
    int row0 = blockIdx.y * 128 + w * 32;   // wave owns 32 rows
    int col0 = blockIdx.x * 64;

    float4_t acc[2][4];
#pragma unroll
    for (int i = 0; i < 2; i++)
#pragma unroll
        for (int j = 0; j < 4; j++) acc[i][j] = (float4_t){0.f, 0.f, 0.f, 0.f};

    const unsigned short* bhp[4];
    const unsigned short* blp[4];
#pragma unroll
    for (int ns = 0; ns < 4; ns++) {
        size_t o = (size_t)(col0 + ns * 16 + l15) * Kpad + 8 * g;
        bhp[ns] = WhiT + o; blp[ns] = WloT + o;
    }
    const float* app[2];
    int amode[2]; bool adead[2];
#pragma unroll
    for (int ms = 0; ms < 2; ms++) {
        int base = row0 + ms * 16;
        int gr = base + l15;
        amode[ms] = (base + 16 <= M) ? 2 : (base < M ? 1 : 0);
        adead[ms] = gr >= M;
        int grc = gr < M ? gr : (M - 1);
        app[ms] = A + (size_t)grc * K + 8 * g;
    }
    const float4_t zf4 = {0.f, 0.f, 0.f, 0.f};

    auto LOADB = [&](short8_t* bh, short8_t* bl) {
#pragma unroll
        for (int ns = 0; ns < 4; ns++) {
            bh[ns] = *(const short8_t*)bhp[ns];
            bl[ns] = *(const short8_t*)blp[ns];
            bhp[ns] += 32; blp[ns] += 32;
        }
    };
    auto LOADA = [&](float4_t* x0, float4_t* x1) {
#pragma unroll
        for (int ms = 0; ms < 2; ms++) {
            if (amode[ms] == 0) { x0[ms] = zf4; x1[ms] = zf4; }
            else {
                x0[ms] = *(const float4_t*)app[ms];
                x1[ms] = *(const float4_t*)(app[ms] + 4);
                if (amode[ms] == 1 && adead[ms]) { x0[ms] = zf4; x1[ms] = zf4; }
            }
            app[ms] += 32;
        }
    };
    auto COMPUTE = [&](const short8_t* bh, const short8_t* bl,
                       const float4_t* x0, const float4_t* x1) {
#pragma unroll
        for (int ms = 0; ms < 2; ms++) {
            short8_t ah, al;
            split8(x0[ms], x1[ms], &ah, &al);
#pragma unroll
            for (int ns = 0; ns < 4; ns++) {
                mfma16(acc[ms][ns], ah, bh[ns]);
                mfma16(acc[ms][ns], al, bh[ns]);
                mfma16(acc[ms][ns], ah, bl[ns]);
            }
        }
    };

    short8_t bhA[4], blA[4], bhB[4], blB[4];
    float4_t x0A[2], x1A[2], x0B[2], x1B[2];
    int iters = (K + 31) / 32;                 // 10 or 2 (even)
    LOADB(bhA, blA); LOADA(x0A, x1A);
    for (int it = 0; it < iters; it += 2) {
        LOADB(bhB, blB); LOADA(x0B, x1B);      // prefetch it+1
        COMPUTE(bhA, blA, x0A, x1A);
        if (it + 2 < iters) { LOADB(bhA, blA); LOADA(x0A, x1A); }  // prefetch it+2
        COMPUTE(bhB, blB, x0B, x1B);
    }

    bool ab = posp != nullptr;
    bool pf32 = ab && (flag[0] != 0);
    int gnv[4]; float bvv[4], w30v[4], w31v[4], w32v[4];
#pragma unroll
    for (int ns = 0; ns < 4; ns++) {
        int gn = col0 + ns * 16 + l15;
        gnv[ns] = gn;
        bvv[ns] = (gn < N) ? bias[gn] : 0.f;
        if (ab && gn < N) {
            w30v[ns] = wf3F[gn]; w31v[ns] = wf3F[300 + gn]; w32v[ns] = wf3F[600 + gn];
        } else { w30v[ns] = 0.f; w31v[ns] = 0.f; w32v[ns] = 0.f; }
    }
#pragma unroll
    for (int ms = 0; ms < 2; ms++) {
#pragma unroll
        for (int r = 0; r < 4; r++) {
            int gr = row0 + ms * 16 + 4 * g + r;
            if (gr >= M) continue;
            float p0 = 0.f, p1 = 0.f, p2 = 0.f, d0 = 0.f, d1 = 0.f, d2 = 0.f;
            if (ab) {
                p0 = LDr(posp, (long long)gr * 3 + 0, pf32);
                p1 = LDr(posp, (long long)gr * 3 + 1, pf32);
                p2 = LDr(posp, (long long)gr * 3 + 2, pf32);
                d0 = dxv[gr * 3 + 0]; d1 = dxv[gr * 3 + 1]; d2 = dxv[gr * 3 + 2];
            }
#pragma unroll
            for (int ns = 0; ns < 4; ns++) {
                int gn = gnv[ns];
                if (gn >= N) continue;
                float c = acc[ms][ns][r] + bvv[ns];
                if (ab) {
                    float P = p0 * w30v[ns] + p1 * w31v[ns] + p2 * w32v[ns];
                    float D = d0 * w30v[ns] + d1 * w31v[ns] + d2 * w32v[ns];
                    c += P;
                    bbag[(size_t)gr * N + gn] = D - P;
                }
                if (res) c += res[(size_t)gr * N + gn];
                if (relu) c = fmaxf(c, 0.f);
                C[(size_t)gr * N + gn] = c;
            }
        }
    }
}

// ---------- runtime-dtype single-launch small kernels (fast path) ----------
__global__ void k_dx2(const float* __restrict__ s, const void* __restrict__ Wh,
                      const void* __restrict__ bh, int t, float* __restrict__ dx,
                      const int* __restrict__ flag) {
    bool f32 = flag[0] != 0;
    long long wo = (long long)t * SD * 3, bo = (long long)t * 3;
    int wv = threadIdx.x >> 6, lane = threadIdx.x & 63;
    int v = blockIdx.x * 4 + wv;
    if (v >= N_V) return;
    float p0 = 0.f, p1 = 0.f, p2 = 0.f;
    for (int d = lane; d < SD; d += 64) {
        float sv = s[(size_t)v * SD + d];
        p0 += sv * LDr(Wh, wo + d * 3 + 0, f32);
        p1 += sv * LDr(Wh, wo + d * 3 + 1, f32);
        p2 += sv * LDr(Wh, wo + d * 3 + 2, f32);
    }
#pragma unroll
    for (int off = 32; off > 0; off >>= 1) {
        p0 += __shfl_down(p0, off);
        p1 += __shfl_down(p1, off);
        p2 += __shfl_down(p2, off);
    }
    if (lane == 0) {
        dx[v * 3 + 0] = p0 + LDr(bh, bo + 0, f32);
        dx[v * 3 + 1] = p1 + LDr(bh, bo + 1, f32);
        dx[v * 3 + 2] = p2 + LDr(bh, bo + 2, f32);
    }
}

__global__ void k_cls2(const float* __restrict__ hc, const void* __restrict__ W,
                       const void* __restrict__ b, void* __restrict__ out,
                       const int* __restrict__ flag) {
    bool f32 = flag[0] != 0;
    int v = blockIdx.x * blockDim.x + threadIdx.x;
    if (v >= N_V) return;
    float acc[4];
#pragma unroll
    for (int j = 0; j < 4; j++) acc[j] = LDr(b, j, f32);
    for (int k = 0; k < 64; k++) {
        float h = hc[(size_t)v * 64 + k];
#pragma unroll
        for (int j = 0; j < 4; j++) acc[j] += h * LDr(W, k * 4 + j, f32);
    }
#pragma unroll
    for (int j = 0; j < 4; j++) STr(out, v * 4 + j, fmaxf(acc[j], 0.f), f32);
}

// batched over classes via blockIdx.y; hl2all = 4 x [N_V,64]
__global__ void k_loc32(const float* __restrict__ hl2all, const void* __restrict__ Wl3,
                        const void* __restrict__ bl3, void* __restrict__ out,
                        const int* __restrict__ flag) {
    bool f32 = flag[0] != 0;
    int cls = blockIdx.y;
    const float* h2 = hl2all + (size_t)cls * N_V * 64;
    long long wo = (long long)cls * 64 * 7, bo = (long long)cls * 7;
    int v = blockIdx.x * blockDim.x + threadIdx.x;
    if (v >= N_V) return;
    float acc[7];
#pragma unroll
    for (int j = 0; j < 7; j++) acc[j] = LDr(bl3, bo + j, f32);
    for (int k = 0; k < 64; k++) {
        float h = h2[(size_t)v * 64 + k];
#pragma unroll
        for (int j = 0; j < 7; j++) acc[j] += h * LDr(Wl3, wo + k * 7 + j, f32);
    }
#pragma unroll
    for (int j = 0; j < 7; j++)
        STr(out, 80000 + (size_t)v * 28 + cls * 7 + j, fmaxf(acc[j], 0.f), f32);
}

// ---------- fallback-path small kernels (templated, unchanged) ----------
template<bool F32>
__global__ void k_dx(const float* __restrict__ s, const void* __restrict__ Wh,
                     const void* __restrict__ bh, float* __restrict__ dx,
                     const int* __restrict__ flag) {
    if ((flag[0] != 0) != F32) return;
    int wv = threadIdx.x >> 6, lane = threadIdx.x & 63;
    int v = blockIdx.x * 4 + wv;
    if (v >= N_V) return;
    float p0 = 0.f, p1 = 0.f, p2 = 0.f;
    for (int d = lane; d < SD; d += 64) {
        float sv = s[(size_t)v * SD + d];
        p0 += sv * LD<F32>(Wh, d * 3 + 0);
        p1 += sv * LD<F32>(Wh, d * 3 + 1);
        p2 += sv * LD<F32>(Wh, d * 3 + 2);
    }
#pragma unroll
    for (int off = 32; off > 0; off >>= 1) {
        p0 += __shfl_down(p0, off);
        p1 += __shfl_down(p1, off);
        p2 += __shfl_down(p2, off);
    }
    if (lane == 0) {
        dx[v * 3 + 0] = p0 + LD<F32>(bh, 0);
        dx[v * 3 + 1] = p1 + LD<F32>(bh, 1);
        dx[v * 3 + 2] = p2 + LD<F32>(bh, 2);
    }
}

template<bool F32>
__global__ void k_ab(const float* __restrict__ dx, const void* __restrict__ pos,
                     const void* __restrict__ Wf3, float* __restrict__ ua,
                     float* __restrict__ bbag, const int* __restrict__ flag) {
    if ((flag[0] != 0) != F32) return;
    int idx = blockIdx.x * blockDim.x + threadIdx.x;
    if (idx >= N_V * SD) return;
    int v = idx / SD, c = idx - v * SD;
    float w0 = LD<F32>(Wf3, c), w1 = LD<F32>(Wf3, SD + c), w2 = LD<F32>(Wf3, 2 * SD + c);
    float P = LD<F32>(pos, v * 3 + 0) * w0 + LD<F32>(pos, v * 3 + 1) * w1
            + LD<F32>(pos, v * 3 + 2) * w2;
    float D = dx[v * 3 + 0] * w0 + dx[v * 3 + 1] * w1 + dx[v * 3 + 2] * w2;
    ua[idx] += P;
    bbag[idx] = D - P;
}

__global__ __launch_bounds__(256) void k_aggr(
    const float* __restrict__ a, float* bbag,
    const int* __restrict__ offs, const int* __restrict__ esrc) {
    int wv = threadIdx.x >> 6, lane = threadIdx.x & 63;
    int v = blockIdx.x * 4 + wv;
    if (v >= N_V) return;
    int e0 = offs[v], e1 = offs[v + 1];
    float r0 = -3.0e38f, r1 = r0, r2 = r0, r3 = r0, r4 = r0;
    bool c4 = lane < SD - 256;
    for (int e = e0; e < e1; e++) {
        const float* ar = a + (size_t)esrc[e] * SD + lane;
        r0 = fmaxf(r0, ar[0]);
        r1 = fmaxf(r1, ar[64]);
        r2 = fmaxf(r2, ar[128]);
        r3 = fmaxf(r3, ar[192]);
        if (c4) r4 = fmaxf(r4, ar[256]);
    }
    float* bv = bbag + (size_t)v * SD + lane;
    bv[0]   = fmaxf(0.f, r0 + bv[0]);
    bv[64]  = fmaxf(0.f, r1 + bv[64]);
    bv[128] = fmaxf(0.f, r2 + bv[128]);
    bv[192] = fmaxf(0.f, r3 + bv[192]);
    if (c4) bv[256] = fmaxf(0.f, r4 + bv[256]);
}

template<bool F32>
__global__ void k_cls(const float* __restrict__ hc, const void* __restrict__ W,
                      const void* __restrict__ b, void* __restrict__ out,
                      const int* __restrict__ flag) {
    if ((flag[0] != 0) != F32) return;
    int v = blockIdx.x * blockDim.x + threadIdx.x;
    if (v >= N_V) return;
    float acc[4];
#pragma unroll
    for (int j = 0; j < 4; j++) acc[j] = LD<F32>(b, j);
    for (int k = 0; k < 64; k++) {
        float h = hc[(size_t)v * 64 + k];
#pragma unroll
        for (int j = 0; j < 4; j++) acc[j] += h * LD<F32>(W, k * 4 + j);
    }
#pragma unroll
    for (int j = 0; j < 4; j++) ST<F32>(out, v * 4 + j, fmaxf(acc[j], 0.f));
}

template<bool F32>
__global__ void k_loc3(const float* __restrict__ h2, const void* __restrict__ W,
                       const void* __restrict__ b, void* __restrict__ out, int cls,
                       const int* __restrict__ flag) {
    if ((flag[0] != 0) != F32) return;
    int v = blockIdx.x * blockDim.x + threadIdx.x;
    if (v >= N_V) return;
    float acc[7];
#pragma unroll
    for (int j = 0; j < 7; j++) acc[j] = LD<F32>(b, j);
    for (int k = 0; k < 64; k++) {
        float h = h2[(size_t)v * 64 + k];
#pragma unroll
        for (int j = 0; j < 7; j++) acc[j] += h * LD<F32>(W, k * 7 + j);
    }
#pragma unroll
    for (int j = 0; j < 7; j++)
        ST<F32>(out, 80000 + (size_t)v * 28 + cls * 7 + j, fmaxf(acc[j], 0.f));
}

#define LAUNCH2(kname, grid, blk, ...) \
    do { kname<false><<<grid, blk, 0, stream>>>(__VA_ARGS__); \
         kname<true><<<grid, blk, 0, stream>>>(__VA_ARGS__); } while (0)

extern "C" void kernel_launch(void* const* d_in, const int* in_sizes, int n_in,
                              void* d_out, int out_size, void* d_ws, size_t ws_size,
                              hipStream_t stream) {
    const void* kp  = d_in[0];
    const void* pos = d_in[1];
    const int* eidx = (const int*)d_in[3];
    const int* e_src = eidx;
    const int* e_dst = eidx + E_N;
    const void* Wi0 = d_in[4];   const void* bi0 = d_in[5];
    const void* Wi1 = d_in[6];   const void* bi1 = d_in[7];
    const void* Wi2 = d_in[8];   const void* bi2 = d_in[9];
    const void* Wa  = d_in[10];  const void* ba  = d_in[11];
    const char* Wh  = (const char*)d_in[12];  const char* bh = (const char*)d_in[13];
    const char* Wf  = (const char*)d_in[14];  const char* bff = (const char*)d_in[15];
    const char* Wg  = (const char*)d_in[16];  const char* bg = (const char*)d_in[17];
    const void* Wc1 = d_in[18];  const void* bc1 = d_in[19];
    const void* Wc2 = d_in[20];  const void* bc2 = d_in[21];
    const char* Wl1 = (const char*)d_in[22];  const char* bl1 = (const char*)d_in[23];
    const char* Wl2 = (const char*)d_in[24];  const char* bl2 = (const char*)d_in[25];
    const char* Wl3 = (const char*)d_in[26];  const char* bl3 = (const char*)d_in[27];

    char* ws = (char*)d_ws;
    // region A (24MB): kpmax (init) -> ua (GNN) -> hc -> hl1[4] (heads, sequential reuse)
    float* regA  = (float*)(ws + 0);
    float* kpmax = regA;
    float* ua    = regA;
    float* hc    = (float*)(ws + 0);
    float* hl1m  = (float*)(ws + 0);          // mf path: 4 x 5.12 MB
    float* hl1f  = (float*)(ws + 6000000);    // fallback
    float* hl2f  = (float*)(ws + 12000000);   // fallback
    // region B (24MB): bbag (GNN) -> hl2[4] (heads)
    float* bbag  = (float*)(ws + 24000000);
    float* hl2m  = (float*)(ws + 24000000);
    // region C (24MB): s
    float* s     = (float*)(ws + 48000000);
    // small stuff
    int*   cnt   = (int*)(ws + 72000000);
    int*   offs  = (int*)(ws + 72100000);
    int*   cur   = (int*)(ws + 72200000);
    int*   esrc  = (int*)(ws + 72300000);
    float* dx    = (float*)(ws + 73600000);   // ends 73,840,000
    float* wf3F  = (float*)(ws + 73844000);   // 10.8 KB
    int*   flag  = (int*)(ws + 73900000);
    // MFMA-path extras
    unsigned short* SPLIT = (unsigned short*)(ws + 73950000); // 3.53 MB
    float* biasF = (float*)(ws + 77481000);                   // 12.4 KB
    // total footprint < 77.5 MB

    bool mf = (ws_size == 0) || (ws_size >= (size_t)77500000);
    auto HI = [&](long long cum) { return SPLIT + 2 * cum; };

    // ----- dtype detect -----
    k_detect<<<1, 128, 0, stream>>>((const unsigned*)Wi0, flag);

    // ----- CSR build -----
    k_zero<<<(N_V + 255) / 256, 256, 0, stream>>>(cnt, N_V);
    k_hist<<<(E_N + 255) / 256, 256, 0, stream>>>(e_dst, cnt);
    k_scan<<<1, 1024, 0, stream>>>(cnt, offs, cur);
    k_scatter<<<(E_N + 255) / 256, 256, 0, stream>>>(e_src, e_dst, cur, esrc);

    // ----- weight prep for MFMA path -----
    if (mf)
        k_prep<<<(PREP_TOT + 255) / 256, 256, 0, stream>>>(
            Wa, Wf, Wg, Wc1, Wl1, Wl2, Wi1, Wi2,
            ba, bff, bg, bc1, bl1, bl2, bi1, bi2,
            SPLIT, biasF, wf3F, bbag, flag);

    // ----- init MLP + segmax -----
    if (mf) {
        const unsigned short* W1T = SPLIT + 2LL * 835584;
        const unsigned short* W2T = SPLIT + 2LL * 843776;
        k_init_mfma<<<M_KP / 64, 256, 0, stream>>>(kp, Wi0, bi0, W1T, W2T,
                                                   biasF + 2676, biasF + 2804,
                                                   kpmax, flag);
    } else {
        LAUNCH2(k_init_fused, M_KP / 64, 256, kp, Wi0, bi0, Wi1, bi1, Wi2, bi2, kpmax, flag);
    }

    const dim3 GSD(5, (N_V + 127) / 128);   // N=300 tiles x 128-row blocks (157)
    const dim3 G64(1, (N_V + 127) / 128);   // N=64 heads
    if (mf) {
        k_gemm_mfma<<<GSD, 256, 0, stream>>>(kpmax, HI(0), HI(0) + 102400,
                                             biasF, nullptr, s, N_V, SD, 320, SD, 1,
                                             0, 0, 0, 0,
                                             nullptr, nullptr, nullptr, nullptr, nullptr);
    } else {
        dim3 g((SD + 63) / 64, (N_V + 63) / 64);
        LAUNCH2(k_gemm, g, 256, kpmax, Wa, ba, nullptr, s, N_V, SD, SD, 1, flag);
    }

    // ----- GNN iterations -----
    for (int t = 0; t < T_IT; t++) {
        dim3 g5((SD + 63) / 64, (N_V + 63) / 64);
        if (mf) {
            k_dx2<<<(N_V + 3) / 4, 256, 0, stream>>>(s, Wh, bh, t, dx, flag);
            long long cum = (long long)(1 + t) * 102400;
            // ua = s@WfS + bf + pos@Wf3 ; bbag = dx@Wf3 - pos@Wf3 (fused)
            k_gemm_mfma<<<GSD, 256, 0, stream>>>(s, HI(cum), HI(cum) + 102400,
                                                 biasF + 300 + t * 300, nullptr, ua,
                                                 N_V, SD, 320, SD, 0, 0, 0, 0, 0,
                                                 pos, dx, wf3F + t * 900, bbag, flag);
        } else {
            for (int f32v = 0; f32v < 2; f32v++) {
                size_t es = f32v ? 4 : 2;
                const void* Wf_t = Wf + (size_t)t * 303 * SD * es;
                const void* WfS  = Wf + ((size_t)t * 303 + 3) * SD * es;
                const void* bf_t = bff + (size_t)t * SD * es;
                const void* Wh_t = Wh + (size_t)t * SD * 3 * es;
                const void* bh_t = bh + (size_t)t * 3 * es;
                if (f32v) {
                    k_gemm<true><<<g5, 256, 0, stream>>>(s, WfS, bf_t, nullptr, ua, N_V, SD, SD, 0, flag);
                    k_dx<true><<<(N_V + 3) / 4, 256, 0, stream>>>(s, Wh_t, bh_t, dx, flag);
                    k_ab<true><<<(N_V * SD + 255) / 256, 256, 0, stream>>>(dx, pos, Wf_t, ua, bbag, flag);
                } else {
                    k_gemm<false><<<g5, 256, 0, stream>>>(s, WfS, bf_t, nullptr, ua, N_V, SD, SD, 0, flag);
                    k_dx<false><<<(N_V + 3) / 4, 256, 0, stream>>>(s, Wh_t, bh_t, dx, flag);
                    k_ab<false><<<(N_V * SD + 255) / 256, 256, 0, stream>>>(dx, pos, Wf_t, ua, bbag, flag);
                }
            }
        }
        k_aggr<<<(N_V + 3) / 4, 256, 0, stream>>>(ua, bbag, offs, esrc);
        if (mf) {
            long long cum = (long long)(4 + t) * 102400;
            k_gemm_mfma<<<GSD, 256, 0, stream>>>(bbag, HI(cum), HI(cum) + 102400,
                                                 biasF + 1200 + t * 300, s, s,
                                                 N_V, SD, 320, SD, 0, 0, 0, 0, 0,
                                                 nullptr, nullptr, nullptr, nullptr, nullptr);
        } else {
            for (int f32v = 0; f32v < 2; f32v++) {
                size_t es = f32v ? 4 : 2;
                const void* Wg_t = Wg + (size_t)t * SD * SD * es;
                const void* bg_t = bg + (size_t)t * SD * es;
                if (f32v)
                    k_gemm<true><<<g5, 256, 0, stream>>>(bbag, Wg_t, bg_t, s, s, N_V, SD, SD, 0, flag);
                else
                    k_gemm<false><<<g5, 256, 0, stream>>>(bbag, Wg_t, bg_t, s, s, N_V, SD, SD, 0, flag);
            }
        }
    }

    // ----- heads -----
    if (mf) {
        k_gemm_mfma<<<G64, 256, 0, stream>>>(s, HI(716800), HI(716800) + 20480,
                                             biasF + 2100, nullptr, hc,
                                             N_V, SD, 320, 64, 1, 0, 0, 0, 0,
                                             nullptr, nullptr, nullptr, nullptr, nullptr);
        k_cls2<<<(N_V + 255) / 256, 256, 0, stream>>>(hc, Wc2, bc2, d_out, flag);
        dim3 gz1(1, (N_V + 127) / 128, 4);
        k_gemm_mfma<<<gz1, 256, 0, stream>>>(s, HI(737280), HI(737280) + 20480,
                                             biasF + 2164, nullptr, hl1m,
                                             N_V, SD, 320, 64, 1,
                                             0, 40960, 64, 1280000,
                                             nullptr, nullptr, nullptr, nullptr, nullptr);
        k_gemm_mfma<<<gz1, 256, 0, stream>>>(hl1m, HI(819200), HI(819200) + 4096,
                                             biasF + 2420, nullptr, hl2m,
                                             N_V, 64, 64, 64, 1,
                                             1280000, 8192, 64, 1280000,
                                             nullptr, nullptr, nullptr, nullptr, nullptr);
        dim3 gz3((N_V + 255) / 256, 4);
        k_loc32<<<gz3, 256, 0, stream>>>(hl2m, Wl3, bl3, d_out, flag);
    } else {
        dim3 g(1, (N_V + 63) / 64);
        LAUNCH2(k_gemm, g, 256, s, Wc1, bc1, nullptr, hc, N_V, SD, 64, 1, flag);
        LAUNCH2(k_cls, (N_V + 255) / 256, 256, hc, Wc2, bc2, d_out, flag);
        for (int c = 0; c < 4; c++) {
            for (int f32v = 0; f32v < 2; f32v++) {
                size_t es = f32v ? 4 : 2;
                const void* Wl1c = Wl1 + (size_t)c * SD * 64 * es;
                const void* bl1c = bl1 + (size_t)c * 64 * es;
                const void* Wl2c = Wl2 + (size_t)c * 64 * 64 * es;
                const void* bl2c = bl2 + (size_t)c * 64 * es;
                const void* Wl3c = Wl3 + (size_t)c * 64 * 7 * es;
                const void* bl3c = bl3 + (size_t)c * 7 * es;
                if (f32v) {
                    k_gemm<true><<<g, 256, 0, stream>>>(s, Wl1c, bl1c, nullptr, hl1f, N_V, SD, 64, 1, flag);
                    k_gemm<true><<<g, 256, 0, stream>>>(hl1f, Wl2c, bl2c, nullptr, hl2f, N_V, 64, 64, 1, flag);
                    k_loc3<true><<<(N_V + 255) / 256, 256, 0, stream>>>(hl2f, Wl3c, bl3c, d_out, c, flag);
                } else {
                    k_gemm<false><<<g, 256, 0, stream>>>(s, Wl1c, bl1c, nullptr, hl1f, N_V, SD, 64, 1, flag);
                    k_gemm<false><<<g, 256, 0, stream>>>(hl1f, Wl2c, bl2c, nullptr, hl2f, N_V, 64, 64, 1, flag);
                    k_loc3<false><<<(N_V + 255) / 256, 256, 0, stream>>>(hl2f, Wl3c, bl3c, d_out, c, flag);
                }
            }
        }
    }
}

// Round 10
// 1168.720 us; speedup vs baseline: 1.0182x; 1.0113x over previous
//
#include <hip/hip_runtime.h>
#include <stdint.h>

#define N_V   20000
#define M_KP  160000
#define E_N   320000
#define SD    300
#define T_IT  3

typedef unsigned short bf16_t;
typedef __attribute__((ext_vector_type(8))) short short8_t;
typedef __attribute__((ext_vector_type(4))) float float4_t;

__device__ __forceinline__ float bf2f(bf16_t u) {
    return __uint_as_float(((unsigned)u) << 16);
}
__device__ __forceinline__ bf16_t f2bf(float f) {
    unsigned u = __float_as_uint(f);
    unsigned r = (u + 0x7FFFu + ((u >> 16) & 1u)) >> 16;
    return (bf16_t)r;
}

template<bool F32>
__device__ __forceinline__ float LD(const void* p, size_t i) {
    if (F32) return ((const float*)p)[i];
    return bf2f(((const bf16_t*)p)[i]);
}
template<bool F32>
__device__ __forceinline__ void ST(void* p, size_t i, float v) {
    if (F32) ((float*)p)[i] = v;
    else     ((bf16_t*)p)[i] = f2bf(v);
}
__device__ __forceinline__ float LDr(const void* p, long long i, bool f32) {
    return f32 ? ((const float*)p)[i] : bf2f(((const bf16_t*)p)[i]);
}
__device__ __forceinline__ void STr(void* p, size_t i, float v, bool f32) {
    if (f32) ((float*)p)[i] = v;
    else     ((bf16_t*)p)[i] = f2bf(v);
}

// ---------- merged: zero cnt + dtype detect (flag=1 if f32, 0 if bf16) ----------
__global__ __launch_bounds__(256) void k_detz(const unsigned* __restrict__ w,
                                              int* __restrict__ flag,
                                              int* __restrict__ cnt) {
    if (blockIdx.x < 79) {
        int i = blockIdx.x * 256 + threadIdx.x;
        if (i < N_V) cnt[i] = 0;
        return;
    }
    __shared__ int cnt_s;
    if (threadIdx.x == 0) cnt_s = 0;
    __syncthreads();
    if (threadIdx.x < 128) {
        unsigned u = w[threadIdx.x];      // 128 dwords = 512B, safe for either dtype
        unsigned lo = u & 0xFFFFu;
        int e = (lo >> 7) & 0xFF;
        int plaus = (lo == 0u) || (e >= 96 && e <= 126);
        atomicAdd(&cnt_s, plaus);
    }
    __syncthreads();
    if (threadIdx.x == 0) flag[0] = (cnt_s >= 64) ? 0 : 1;
}

__global__ void k_hist(const int* __restrict__ dst, int* __restrict__ cnt) {
    int e = blockIdx.x * blockDim.x + threadIdx.x;
    if (e < E_N) atomicAdd(&cnt[dst[e]], 1);
}

// ---------- fast single-block scan: 20 elems/thread, 3 phases ----------
__global__ __launch_bounds__(1024) void k_scan(const int* __restrict__ cnt,
                                               int* __restrict__ offs,
                                               int* __restrict__ cur) {
    __shared__ int sums[1024];
    int tid = threadIdx.x;
    int base = tid * 20;
    int vals[20];
    int s = 0;
#pragma unroll
    for (int j = 0; j < 20; j++) {
        int i = base + j;
        int v = (i < N_V) ? cnt[i] : 0;
        vals[j] = v;
        s += v;
    }
    sums[tid] = s;
    __syncthreads();
    for (int off = 1; off < 1024; off <<= 1) {
        int t = (tid >= off) ? sums[tid - off] : 0;
        __syncthreads();
        sums[tid] += t;
        __syncthreads();
    }
    int run = (tid == 0) ? 0 : sums[tid - 1];
    if (tid == 0) offs[0] = 0;
#pragma unroll
    for (int j = 0; j < 20; j++) {
        int i = base + j;
        if (i < N_V) {
            cur[i] = run;
            run += vals[j];
            offs[i + 1] = run;
        }
    }
}

// ---------- weight prep layout ----------
// Split matrices (padded elems each):
//   m0: Wa 320x320 (102400) cum 0 | m1-3 WfS[t] | m4-6 Wg[t]
//   m7: Wc1 64x320 (20480) cum 716800 | m8-11 Wl1[c]
//   m12-15 Wl2[c] 64x64 (4096) cum 819200
//   m16 Wi1 128x64 (8192) cum 835584 | m17 Wi2 304x128 (38912) cum 843776
// biasF: [0,300) ba | [300,1200) bf | [1200,2100) bg | [2100,2164) bc1
//      | [2164,2420) bl1 | [2420,2676) bl2 | [2676,2804) bi1 | [2804,3104) bi2
// wf3F: 3 x [3][300] rows 0..2 of Wf[t]
#define PREP_SPLIT 882688
#define PREP_BIAS  3104
#define PREP_WF3   2700
#define PREP_TOT   (PREP_SPLIT + PREP_BIAS + PREP_WF3 + 32)
#define SCAT_BLOCKS 1250
#define PREP_BLOCKS ((PREP_TOT + 255) / 256)

// ---------- merged: edge scatter + weight prep ----------
__global__ __launch_bounds__(256) void k_scprep(
    const int* __restrict__ src, const int* __restrict__ dst,
    int* __restrict__ cur, int* __restrict__ esrc,
    const void* __restrict__ Wa, const void* __restrict__ Wf,
    const void* __restrict__ Wg, const void* __restrict__ Wc1,
    const void* __restrict__ Wl1, const void* __restrict__ Wl2,
    const void* __restrict__ Wi1, const void* __restrict__ Wi2,
    const void* __restrict__ ba, const void* __restrict__ bfb,
    const void* __restrict__ bgb, const void* __restrict__ bc1,
    const void* __restrict__ bl1b, const void* __restrict__ bl2b,
    const void* __restrict__ bi1, const void* __restrict__ bi2,
    unsigned short* __restrict__ SP, float* __restrict__ biasF,
    float* __restrict__ wf3F, float* __restrict__ bzero,
    const int* __restrict__ flag)
{
    if (blockIdx.x < SCAT_BLOCKS) {
        int e = blockIdx.x * 256 + threadIdx.x;
        if (e < E_N) {
            int p = atomicAdd(&cur[dst[e]], 1);
            esrc[p] = src[e];
        }
        return;
    }
    int idx = (blockIdx.x - SCAT_BLOCKS) * 256 + threadIdx.x;
    if (idx >= PREP_TOT) return;
    bool f32 = flag[0] != 0;
    if (idx < PREP_SPLIT) {
        const void* srcp; long long eoff, cum; int srcN, Nn, Kk, Kpad, pe, local;
        if (idx < 716800) {
            int m = idx / 102400; local = idx - m * 102400;
            pe = 102400; cum = (long long)m * 102400;
            Kpad = 320; Nn = 300; Kk = 300; srcN = 300;
            srcp = (m == 0) ? Wa : (m <= 3 ? Wf : Wg);
            eoff = (m == 0) ? 0 : (m <= 3 ? (long long)((m - 1) * 303 + 3) * 300
                                          : (long long)(m - 4) * 90000);
        } else if (idx < 819200) {
            int j = (idx - 716800) / 20480; local = (idx - 716800) - j * 20480;
            pe = 20480; cum = 716800 + (long long)j * 20480;
            Kpad = 320; Nn = 64; Kk = 300; srcN = 64;
            srcp = (j == 0) ? Wc1 : Wl1;
            eoff = (j == 0) ? 0 : (long long)(j - 1) * 19200;
        } else if (idx < 835584) {
            int c = (idx - 819200) / 4096; local = (idx - 819200) - c * 4096;
            pe = 4096; cum = 819200 + (long long)c * 4096;
            Kpad = 64; Nn = 64; Kk = 64; srcN = 64;
            srcp = Wl2; eoff = (long long)c * 4096;
        } else if (idx < 843776) {
            local = idx - 835584;
            pe = 8192; cum = 835584;
            Kpad = 64; Nn = 128; Kk = 64; srcN = 128;
            srcp = Wi1; eoff = 0;
        } else {
            local = idx - 843776;
            pe = 38912; cum = 843776;
            Kpad = 128; Nn = 300; Kk = 128; srcN = 300;
            srcp = Wi2; eoff = 0;
        }
        int n = local / Kpad, k = local - n * Kpad;
        float v = 0.f;
        if (n < Nn && k < Kk) v = LDr(srcp, eoff + (long long)k * srcN + n, f32);
        bf16_t hi = f2bf(v);                 // RN split
        bf16_t lo = f2bf(v - bf2f(hi));      // bf16 input -> hi exact, lo = 0
        SP[2 * cum + local] = hi;
        SP[2 * cum + pe + local] = lo;
    } else if (idx < PREP_SPLIT + PREP_BIAS) {
        int b = idx - PREP_SPLIT;
        const void* srcp; int o;
        if (b < 300)       { srcp = ba;   o = b; }
        else if (b < 1200) { srcp = bfb;  o = b - 300; }
        else if (b < 2100) { srcp = bgb;  o = b - 1200; }
        else if (b < 2164) { srcp = bc1;  o = b - 2100; }
        else if (b < 2420) { srcp = bl1b; o = b - 2164; }
        else if (b < 2676) { srcp = bl2b; o = b - 2420; }
        else if (b < 2804) { srcp = bi1;  o = b - 2676; }
        else               { srcp = bi2;  o = b - 2804; }
        biasF[b] = LDr(srcp, o, f32);
    } else if (idx < PREP_SPLIT + PREP_BIAS + PREP_WF3) {
        int b2 = idx - (PREP_SPLIT + PREP_BIAS);
        int t = b2 / 900, rem = b2 - t * 900;
        wf3F[b2] = LDr(Wf, (long long)t * 303 * SD + rem, f32);
    } else {
        bzero[idx - (PREP_SPLIT + PREP_BIAS + PREP_WF3)] = 0.f;
    }
}

// ---------- fused init MLP (fallback VALU path) ----------
template<bool F32>
__global__ __launch_bounds__(256) void k_init_fused(
    const void* __restrict__ kp,
    const void* __restrict__ Wi0, const void* __restrict__ bi0,
    const void* __restrict__ Wi1, const void* __restrict__ bi1,
    const void* __restrict__ Wi2, const void* __restrict__ bi2,
    float* __restrict__ kpmax, const int* __restrict__ flag) {
    if ((flag[0] != 0) != F32) return;
    __shared__ float kps[256];
    __shared__ float h1s[64][64];
    __shared__ float h2s[64 * 128];
    int tid = threadIdx.x;
    int row0 = blockIdx.x * 64;
    kps[tid] = LD<F32>(kp, (size_t)row0 * 4 + tid);
    __syncthreads();
    {
        int c = tid & 63;
        float w0 = LD<F32>(Wi0, c), w1 = LD<F32>(Wi0, 64 + c);
        float w2 = LD<F32>(Wi0, 128 + c), w3 = LD<F32>(Wi0, 192 + c);
        float b0 = LD<F32>(bi0, c);
        int rbase = (tid >> 6) * 16;
#pragma unroll
        for (int rr = 0; rr < 16; rr++) {
            int r = rbase + rr;
            float a = b0 + kps[r * 4] * w0 + kps[r * 4 + 1] * w1
                         + kps[r * 4 + 2] * w2 + kps[r * 4 + 3] * w3;
            h1s[r][c] = fmaxf(a, 0.f);
        }
    }
    __syncthreads();
    {
        int c = tid & 127;
        int rbase = (tid >> 7) * 32;
        float b1 = LD<F32>(bi1, c);
        float acc[32];
#pragma unroll
        for (int rr = 0; rr < 32; rr++) acc[rr] = b1;
        for (int k = 0; k < 64; k++) {
            float wv = LD<F32>(Wi1, (size_t)k * 128 + c);
#pragma unroll
            for (int rr = 0; rr < 32; rr++) acc[rr] += h1s[rbase + rr][k] * wv;
        }
#pragma unroll
        for (int rr = 0; rr < 32; rr++)
            h2s[(size_t)(rbase + rr) * 128 + c] = fmaxf(acc[rr], 0.f);
    }
    __syncthreads();
    {
        int cx = tid & 63, rg = tid >> 6;
        float acc[16][5];
#pragma unroll
        for (int r = 0; r < 16; r++)
#pragma unroll
            for (int j = 0; j < 5; j++) acc[r][j] = 0.f;
        bool ok4 = (cx < SD - 256);
        for (int k = 0; k < 128; k++) {
            float w[5];
#pragma unroll
            for (int j = 0; j < 4; j++) w[j] = LD<F32>(Wi2, (size_t)k * SD + cx + 64 * j);
            w[4] = ok4 ? LD<F32>(Wi2, (size_t)k * SD + cx + 256) : 0.f;
#pragma unroll
            for (int r = 0; r < 16; r++) {
                float av = h2s[(rg * 16 + r) * 128 + k];
#pragma unroll
                for (int j = 0; j < 5; j++) acc[r][j] += av * w[j];
            }
        }
        int vbase = (row0 >> 3) + rg * 2;
#pragma unroll
        for (int half = 0; half < 2; half++) {
            int v = vbase + half;
#pragma unroll
            for (int j = 0; j < 5; j++) {
                int c = cx + 64 * j;
                if (c >= SD) continue;
                float m = acc[half * 8][j];
#pragma unroll
                for (int r = 1; r < 8; r++) m = fmaxf(m, acc[half * 8 + r][j]);
                kpmax[(size_t)v * SD + c] = fmaxf(m + LD<F32>(bi2, c), 0.f);
            }
        }
    }
}

// ---------- generic tiled f32 GEMM (fallback path only) ----------
template<bool F32>
__global__ __launch_bounds__(256) void k_gemm(
    const float* __restrict__ A, const void* __restrict__ W,
    const void* __restrict__ bias, const float* res,
    float* C, int Mr, int K, int Nc, int do_relu, const int* __restrict__ flag) {
    if ((flag[0] != 0) != F32) return;
    __shared__ float As[16][65];
    __shared__ float Ws[16][64];
    int tid = threadIdx.x;
    int tx = tid & 15, ty = tid >> 4;
    int row0 = blockIdx.y * 64, col0 = blockIdx.x * 64;
    float acc[4][4] = {{0.f}};
    int lk = tid & 15, lr = tid >> 4;
    int ln = tid & 63, lk4 = tid >> 6;
    for (int k0 = 0; k0 < K; k0 += 16) {
#pragma unroll
        for (int i = 0; i < 4; i++) {
            int r = lr + i * 16;
            int gr = row0 + r, gk = k0 + lk;
            As[lk][r] = (gr < Mr && gk < K) ? A[(size_t)gr * K + gk] : 0.f;
        }
#pragma unroll
        for (int p = 0; p < 4; p++) {
            int kk = lk4 + p * 4;
            int gk = k0 + kk, gn = col0 + ln;
            Ws[kk][ln] = (gk < K && gn < Nc) ? LD<F32>(W, (size_t)gk * Nc + gn) : 0.f;
        }
        __syncthreads();
#pragma unroll
        for (int kk = 0; kk < 16; kk++) {
            float a[4], w[4];
#pragma unroll
            for (int i = 0; i < 4; i++) a[i] = As[kk][ty * 4 + i];
#pragma unroll
            for (int j = 0; j < 4; j++) w[j] = Ws[kk][tx * 4 + j];
#pragma unroll
            for (int i = 0; i < 4; i++)
#pragma unroll
                for (int j = 0; j < 4; j++) acc[i][j] += a[i] * w[j];
        }
        __syncthreads();
    }
#pragma unroll
    for (int i = 0; i < 4; i++) {
        int gr = row0 + ty * 4 + i;
        if (gr >= Mr) continue;
#pragma unroll
        for (int j = 0; j < 4; j++) {
            int gn = col0 + tx * 4 + j;
            if (gn >= Nc) continue;
            float c = acc[i][j] + LD<F32>(bias, gn);
            if (res) c += res[(size_t)gr * Nc + gn];
            if (do_relu) c = fmaxf(c, 0.f);
            C[(size_t)gr * Nc + gn] = c;
        }
    }
}

// ---------- MFMA helpers ----------
__device__ __forceinline__ void mfma16(float4_t& c, short8_t a, short8_t b) {
    asm("v_mfma_f32_16x16x32_bf16 %0, %1, %2, %0" : "+v"(c) : "v"(a), "v"(b));
}
__device__ __forceinline__ void split2(float a, float b, unsigned& h, unsigned& l) {
    asm("v_cvt_pk_bf16_f32 %0, %1, %2" : "=v"(h) : "v"(a), "v"(b));
    float la = a - __uint_as_float(h << 16);
    float lb = b - __uint_as_float(h & 0xFFFF0000u);
    asm("v_cvt_pk_bf16_f32 %0, %1, %2" : "=v"(l) : "v"(la), "v"(lb));
}
__device__ __forceinline__ void split8(float4_t x0, float4_t x1,
                                       short8_t* hi, short8_t* lo) {
    union { unsigned u[4]; short8_t v; } H, L;
#pragma unroll
    for (int p = 0; p < 4; p++) {
        float a, b;
        if (p == 0)      { a = x0[0]; b = x0[1]; }
        else if (p == 1) { a = x0[2]; b = x0[3]; }
        else if (p == 2) { a = x1[0]; b = x1[1]; }
        else             { a = x1[2]; b = x1[3]; }
        unsigned ph, pl;
        split2(a, b, ph, pl);
        H.u[p] = ph; L.u[p] = pl;
    }
    *hi = H.v; *lo = L.v;
}

// ---------- MFMA init MLP v3 (+ wlo skip: weight-lo == 0 in bf16 mode) ----------
__global__ __launch_bounds__(256) void k_init_mfma(
    const void* __restrict__ kp,
    const void* __restrict__ Wi0, const void* __restrict__ bi0,
    const unsigned short* __restrict__ W1T,   // [128][64], lo at +8192
    const unsigned short* __restrict__ W2T,   // [304][128], lo at +38912
    const float* __restrict__ b1F, const float* __restrict__ b2F,
    float* __restrict__ kpmax, const int* __restrict__ flag)
{
    bool f32 = flag[0] != 0;
    bool wlo = f32;   // weights have nonzero lo only in f32 mode
    __shared__ __attribute__((aligned(16))) unsigned short lds[2][8704]; // 34,816 B
    int tid = threadIdx.x;
    int w = tid >> 6, lane = tid & 63;
    int rg = w >> 1, ch = w & 1;
    int l15 = lane & 15, g = lane >> 4;
    unsigned short* h2h = lds[rg];
    unsigned short* h2l = lds[rg] + 4352;
    int rw0 = blockIdx.x * 64 + rg * 32;

    float kpr[2][4];
#pragma unroll
    for (int mt = 0; mt < 2; mt++) {
        long long r = rw0 + mt * 16 + l15;
#pragma unroll
        for (int j = 0; j < 4; j++) kpr[mt][j] = LDr(kp, r * 4 + j, f32);
    }
    short8_t a1h[2][2], a1l[2][2];
#pragma unroll
    for (int ks = 0; ks < 2; ks++) {
        float h[2][8];
#pragma unroll
        for (int e = 0; e < 8; e++) {
            int chn = ks * 32 + 8 * g + e;
            float w0 = LDr(Wi0, chn, f32),       w1 = LDr(Wi0, 64 + chn, f32);
            float w2 = LDr(Wi0, 128 + chn, f32), w3 = LDr(Wi0, 192 + chn, f32);
            float b0 = LDr(bi0, chn, f32);
#pragma unroll
            for (int mt = 0; mt < 2; mt++)
                h[mt][e] = fmaxf(b0 + kpr[mt][0] * w0 + kpr[mt][1] * w1
                                    + kpr[mt][2] * w2 + kpr[mt][3] * w3, 0.f);
        }
#pragma unroll
        for (int mt = 0; mt < 2; mt++) {
            union { unsigned u[4]; short8_t v; } H, L;
#pragma unroll
            for (int p = 0; p < 4; p++) {
                unsigned hh, ll;
                split2(h[mt][2 * p], h[mt][2 * p + 1], hh, ll);
                H.u[p] = hh; L.u[p] = ll;
            }
            a1h[mt][ks] = H.v; a1l[mt][ks] = L.v;
        }
    }

#pragma unroll
    for (int i = 0; i < 4; i++) {
        int n0 = ch * 4 + i;
        const unsigned short* bp = W1T + (n0 * 16 + l15) * 64 + 8 * g;
        short8_t bh0 = *(const short8_t*)bp;
        short8_t bh1 = *(const short8_t*)(bp + 32);
        float4_t c0 = {0.f, 0.f, 0.f, 0.f}, c1 = {0.f, 0.f, 0.f, 0.f};
        mfma16(c0, a1h[0][0], bh0); mfma16(c0, a1h[0][1], bh1);
        mfma16(c0, a1l[0][0], bh0); mfma16(c0, a1l[0][1], bh1);
        mfma16(c1, a1h[1][0], bh0); mfma16(c1, a1h[1][1], bh1);
        mfma16(c1, a1l[1][0], bh0); mfma16(c1, a1l[1][1], bh1);
        if (wlo) {
            short8_t bl0 = *(const short8_t*)(bp + 8192);
            short8_t bl1 = *(const short8_t*)(bp + 8224);
            mfma16(c0, a1h[0][0], bl0); mfma16(c0, a1h[0][1], bl1);
            mfma16(c1, a1h[1][0], bl0); mfma16(c1, a1h[1][1], bl1);
        }
        int col = n0 * 16 + l15;
        float bv = b1F[col];
#pragma unroll
        for (int i2 = 0; i2 < 4; i2++) {
            float v0 = fmaxf(c0[i2] + bv, 0.f);
            bf16_t h0 = f2bf(v0);
            h2h[(4 * g + i2) * 136 + col] = h0;
            h2l[(4 * g + i2) * 136 + col] = f2bf(v0 - bf2f(h0));
            float v1 = fmaxf(c1[i2] + bv, 0.f);
            bf16_t h1v = f2bf(v1);
            h2h[(16 + 4 * g + i2) * 136 + col] = h1v;
            h2l[(16 + 4 * g + i2) * 136 + col] = f2bf(v1 - bf2f(h1v));
        }
    }
    __syncthreads();

    short8_t a2h[2][4], a2l[2][4];
#pragma unroll
    for (int mt = 0; mt < 2; mt++)
#pragma unroll
        for (int ks = 0; ks < 4; ks++) {
            int off = (mt * 16 + l15) * 136 + ks * 32 + 8 * g;
            a2h[mt][ks] = *(const short8_t*)(h2h + off);
            a2l[mt][ks] = *(const short8_t*)(h2l + off);
        }
    int vb = blockIdx.x * 8 + rg * 4;
    int n0beg = ch ? 10 : 0, n0end = ch ? 19 : 10;
    for (int n0 = n0beg; n0 < n0end; n0++) {
        const unsigned short* bp = W2T + (n0 * 16 + l15) * 128 + 8 * g;
        short8_t bh[4];
#pragma unroll
        for (int ks = 0; ks < 4; ks++) bh[ks] = *(const short8_t*)(bp + ks * 32);
        float4_t c0 = {0.f, 0.f, 0.f, 0.f}, c1 = {0.f, 0.f, 0.f, 0.f};
#pragma unroll
        for (int ks = 0; ks < 4; ks++) {
            mfma16(c0, a2h[0][ks], bh[ks]); mfma16(c1, a2h[1][ks], bh[ks]);
        }
#pragma unroll
        for (int ks = 0; ks < 4; ks++) {
            mfma16(c0, a2l[0][ks], bh[ks]); mfma16(c1, a2l[1][ks], bh[ks]);
        }
        if (wlo) {
            short8_t bl[4];
#pragma unroll
            for (int ks = 0; ks < 4; ks++)
                bl[ks] = *(const short8_t*)(bp + 38912 + ks * 32);
#pragma unroll
            for (int ks = 0; ks < 4; ks++) {
                mfma16(c0, a2h[0][ks], bl[ks]); mfma16(c1, a2h[1][ks], bl[ks]);
            }
        }
        float m0 = fmaxf(fmaxf(c0[0], c0[1]), fmaxf(c0[2], c0[3]));
        m0 = fmaxf(m0, __shfl_xor(m0, 16));
        float m1 = fmaxf(fmaxf(c1[0], c1[1]), fmaxf(c1[2], c1[3]));
        m1 = fmaxf(m1, __shfl_xor(m1, 16));
        int col = n0 * 16 + l15;
        if (col < SD) {
            float bv = b2F[col];
            if (g == 0) {
                kpmax[(size_t)(vb + 0) * SD + col] = fmaxf(m0 + bv, 0.f);
                kpmax[(size_t)(vb + 2) * SD + col] = fmaxf(m1 + bv, 0.f);
            } else if (g == 2) {
                kpmax[(size_t)(vb + 1) * SD + col] = fmaxf(m0 + bv, 0.f);
                kpmax[(size_t)(vb + 3) * SD + col] = fmaxf(m1 + bv, 0.f);
            }
        }
    }
}

// ---------- split-bf16 MFMA GEMM v2 (+ wlo skip) ----------
// Grid: x = ceil(N/64), y = ceil(M/128), z batched. (K+31)/32 must be EVEN.
// If posp != null: C(=ua) = A@W + bias + pos@Wf3 ; bbag = dx@Wf3 - pos@Wf3.
// flag must always be a valid pointer.
__global__ __launch_bounds__(256) void k_gemm_mfma(
    const float* __restrict__ A, const unsigned short* __restrict__ WhiT,
    const unsigned short* __restrict__ WloT, const float* __restrict__ bias,
    const float* __restrict__ res, float* __restrict__ C,
    int M, int K, int Kpad, int N, int relu,
    long long zA, long long zW, int zB, long long zC,
    const void* posp, const float* dxv, const float* wf3F,
    float* bbag, const int* __restrict__ flag)
{
    bool wlo = flag[0] != 0;   // weight-lo nonzero only in f32 mode
    int z = blockIdx.z;
    A    += (size_t)z * zA;
    WhiT += (size_t)z * zW;
    WloT += (size_t)z * zW;
    bias += (size_t)z * zB;
    C    += (size_t)z * zC;
    int tid = threadIdx.x;
    int w = tid >> 6, lane = tid & 63;
    int l15 = lane & 15, g = lane >> 4;
    int row0 = blockIdx.y * 128 + w * 32;   // wave owns 32 rows
    int col0 = blockIdx.x * 64;

    float4_t acc[2][4];
#pragma unroll
    for (int i = 0; i < 2; i++)
#pragma unroll
        for (int j = 0; j < 4; j++) acc[i][j] = (float4_t){0.f, 0.f, 0.f, 0.f};

    const unsigned short* bhp[4];
    const unsigned short* blp[4];
#pragma unroll
    for (int ns = 0; ns < 4; ns++) {
        size_t o = (size_t)(col0 + ns * 16 + l15) * Kpad + 8 * g;
        bhp[ns] = WhiT + o; blp[ns] = WloT + o;
    }
    const float* app[2];
    int amode[2]; bool adead[2];
#pragma unroll
    for (int ms = 0; ms < 2; ms++) {
        int base = row0 + ms * 16;
        int gr = base + l15;
        amode[ms] = (base + 16 <= M) ? 2 : (base < M ? 1 : 0);
        adead[ms] = gr >= M;
        int grc = gr < M ? gr : (M - 1);
        app[ms] = A + (size_t)grc * K + 8 * g;
    }
    const float4_t zf4 = {0.f, 0.f, 0.f, 0.f};
    const short8_t z8 = {0, 0, 0, 0, 0, 0, 0, 0};

    auto LOADB = [&](short8_t* bh, short8_t* bl) {
#pragma unroll
        for (int ns = 0; ns < 4; ns++) {
            bh[ns] = *(const short8_t*)bhp[ns];
            bl[ns] = wlo ? *(const short8_t*)blp[ns] : z8;
            bhp[ns] += 32; blp[ns] += 32;
        }
    };
    auto LOADA = [&](float4_t* x0, float4_t* x1) {
#pragma unroll
        for (int ms = 0; ms < 2; ms++) {
            if (amode[ms] == 0) { x0[ms] = zf4; x1[ms] = zf4; }
            else {
                x0[ms] = *(const float4_t*)app[ms];
                x1[ms] = *(const float4_t*)(app[ms] + 4);
                if (amode[ms] == 1 && adead[ms]) { x0[ms] = zf4; x1[ms] = zf4; }
            }
            app[ms] += 32;
        }
    };
    auto COMPUTE = [&](const short8_t* bh, const short8_t* bl,
                       const float4_t* x0, const float4_t* x1) {
#pragma unroll
        for (int ms = 0; ms < 2; ms++) {
            short8_t ah, al;
            split8(x0[ms], x1[ms], &ah, &al);
#pragma unroll
            for (int ns = 0; ns < 4; ns++) {
                mfma16(acc[ms][ns], ah, bh[ns]);
                mfma16(acc[ms][ns], al, bh[ns]);
            }
            if (wlo) {
#pragma unroll
                for (int ns = 0; ns < 4; ns++) mfma16(acc[ms][ns], ah, bl[ns]);
            }
        }
    };

    short8_t bhA[4], blA[4], bhB[4], blB[4];
    float4_t x0A[2], x1A[2], x0B[2], x1B[2];
    int iters = (K + 31) / 32;                 // 10 or 2 (even)
    LOADB(bhA, blA); LOADA(x0A, x1A);
    for (int it = 0; it < iters; it += 2) {
        LOADB(bhB, blB); LOADA(x0B, x1B);      // prefetch it+1
        COMPUTE(bhA, blA, x0A, x1A);
        if (it + 2 < iters) { LOADB(bhA, blA); LOADA(x0A, x1A); }  // prefetch it+2
        COMPUTE(bhB, blB, x0B, x1B);
    }

    bool ab = posp != nullptr;
    bool pf32 = ab && wlo;
    int gnv[4]; float bvv[4], w30v[4], w31v[4], w32v[4];
#pragma unroll
    for (int ns = 0; ns < 4; ns++) {
        int gn = col0 + ns * 16 + l15;
        gnv[ns] = gn;
        bvv[ns] = (gn < N) ? bias[gn] : 0.f;
        if (ab && gn < N) {
            w30v[ns] = wf3F[gn]; w31v[ns] = wf3F[300 + gn]; w32v[ns] = wf3F[600 + gn];
        } else { w30v[ns] = 0.f; w31v[ns] = 0.f; w32v[ns] = 0.f; }
    }
#pragma unroll
    for (int ms = 0; ms < 2; ms++) {
#pragma unroll
        for (int r = 0; r < 4; r++) {
            int gr = row0 + ms * 16 + 4 * g + r;
            if (gr >= M) continue;
            float p0 = 0.f, p1 = 0.f, p2 = 0.f, d0 = 0.f, d1 = 0.f, d2 = 0.f;
            if (ab) {
                p0 = LDr(posp, (long long)gr * 3 + 0, pf32);
                p1 = LDr(posp, (long long)gr * 3 + 1, pf32);
                p2 = LDr(posp, (long long)gr * 3 + 2, pf32);
                d0 = dxv[gr * 3 + 0]; d1 = dxv[gr * 3 + 1]; d2 = dxv[gr * 3 + 2];
            }
#pragma unroll
            for (int ns = 0; ns < 4; ns++) {
                int gn = gnv[ns];
                if (gn >= N) continue;
                float c = acc[ms][ns][r] + bvv[ns];
                if (ab) {
                    float P = p0 * w30v[ns] + p1 * w31v[ns] + p2 * w32v[ns];
                    float D = d0 * w30v[ns] + d1 * w31v[ns] + d2 * w32v[ns];
                    c += P;
                    bbag[(size_t)gr * N + gn] = D - P;
                }
                if (res) c += res[(size_t)gr * N + gn];
                if (relu) c = fmaxf(c, 0.f);
                C[(size_t)gr * N + gn] = c;
            }
        }
    }
}

// ---------- runtime-dtype small kernels (fast path) ----------
__global__ void k_dx2(const float* __restrict__ s, const void* __restrict__ Wh,
                      const void* __restrict__ bh, int t, float* __restrict__ dx,
                      const int* __restrict__ flag) {
    bool f32 = flag[0] != 0;
    long long wo = (long long)t * SD * 3, bo = (long long)t * 3;
    int wv = threadIdx.x >> 6, lane = threadIdx.x & 63;
    int v = blockIdx.x * 4 + wv;
    if (v >= N_V) return;
    float p0 = 0.f, p1 = 0.f, p2 = 0.f;
    for (int d = lane; d < SD; d += 64) {
        float sv = s[(size_t)v * SD + d];
        p0 += sv * LDr(Wh, wo + d * 3 + 0, f32);
        p1 += sv * LDr(Wh, wo + d * 3 + 1, f32);
        p2 += sv * LDr(Wh, wo + d * 3 + 2, f32);
    }
#pragma unroll
    for (int off = 32; off > 0; off >>= 1) {
        p0 += __shfl_down(p0, off);
        p1 += __shfl_down(p1, off);
        p2 += __shfl_down(p2, off);
    }
    if (lane == 0) {
        dx[v * 3 + 0] = p0 + LDr(bh, bo + 0, f32);
        dx[v * 3 + 1] = p1 + LDr(bh, bo + 1, f32);
        dx[v * 3 + 2] = p2 + LDr(bh, bo + 2, f32);
    }
}

__global__ __launch_bounds__(256) void k_aggr(
    const float* __restrict__ a, float* bbag,
    const int* __restrict__ offs, const int* __restrict__ esrc) {
    int wv = threadIdx.x >> 6, lane = threadIdx.x & 63;
    int v = blockIdx.x * 4 + wv;
    if (v >= N_V) return;
    int e0 = offs[v], e1 = offs[v + 1];
    float r0 = -3.0e38f, r1 = r0, r2 = r0, r3 = r0, r4 = r0;
    bool c4 = lane < SD - 256;
    for (int e = e0; e < e1; e++) {
        const float* ar = a + (size_t)esrc[e] * SD + lane;
        r0 = fmaxf(r0, ar[0]);
        r1 = fmaxf(r1, ar[64]);
        r2 = fmaxf(r2, ar[128]);
        r3 = fmaxf(r3, ar[192]);
        if (c4) r4 = fmaxf(r4, ar[256]);
    }
    float* bv = bbag + (size_t)v * SD + lane;
    bv[0]   = fmaxf(0.f, r0 + bv[0]);
    bv[64]  = fmaxf(0.f, r1 + bv[64]);
    bv[128] = fmaxf(0.f, r2 + bv[128]);
    bv[192] = fmaxf(0.f, r3 + bv[192]);
    if (c4) bv[256] = fmaxf(0.f, r4 + bv[256]);
}

// merged heads output: y in [0,4) -> loc3 class y from hl2all; y==4 -> cls from hc
__global__ void k_headout(const float* __restrict__ hc,
                          const float* __restrict__ hl2all,
                          const void* __restrict__ Wc2, const void* __restrict__ bc2,
                          const void* __restrict__ Wl3, const void* __restrict__ bl3,
                          void* __restrict__ out, const int* __restrict__ flag) {
    bool f32 = flag[0] != 0;
    int y = blockIdx.y;
    int v = blockIdx.x * blockDim.x + threadIdx.x;
    if (v >= N_V) return;
    if (y == 4) {
        float acc[4];
#pragma unroll
        for (int j = 0; j < 4; j++) acc[j] = LDr(bc2, j, f32);
        for (int k = 0; k < 64; k++) {
            float h = hc[(size_t)v * 64 + k];
#pragma unroll
            for (int j = 0; j < 4; j++) acc[j] += h * LDr(Wc2, k * 4 + j, f32);
        }
#pragma unroll
        for (int j = 0; j < 4; j++) STr(out, v * 4 + j, fmaxf(acc[j], 0.f), f32);
    } else {
        const float* h2 = hl2all + (size_t)y * N_V * 64;
        long long wo = (long long)y * 64 * 7, bo = (long long)y * 7;
        float acc[7];
#pragma unroll
        for (int j = 0; j < 7; j++) acc[j] = LDr(bl3, bo + j, f32);
        for (int k = 0; k < 64; k++) {
            float h = h2[(size_t)v * 64 + k];
#pragma unroll
            for (int j = 0; j < 7; j++) acc[j] += h * LDr(Wl3, wo + k * 7 + j, f32);
        }
#pragma unroll
        for (int j = 0; j < 7; j++)
            STr(out, 80000 + (size_t)v * 28 + y * 7 + j, fmaxf(acc[j], 0.f), f32);
    }
}

// ---------- fallback-path small kernels ----------
template<bool F32>
__global__ void k_dx(const float* __restrict__ s, const void* __restrict__ Wh,
                     const void* __restrict__ bh, float* __restrict__ dx,
                     const int* __restrict__ flag) {
    if ((flag[0] != 0) != F32) return;
    int wv = threadIdx.x >> 6, lane = threadIdx.x & 63;
    int v = blockIdx.x * 4 + wv;
    if (v >= N_V) return;
    float p0 = 0.f, p1 = 0.f, p2 = 0.f;
    for (int d = lane; d < SD; d += 64) {
        float sv = s[(size_t)v * SD + d];
        p0 += sv * LD<F32>(Wh, d * 3 + 0);
        p1 += sv * LD<F32>(Wh, d * 3 + 1);
        p2 += sv * LD<F32>(Wh, d * 3 + 2);
    }
#pragma unroll
    for (int off = 32; off > 0; off >>= 1) {
        p0 += __shfl_down(p0, off);
        p1 += __shfl_down(p1, off);
        p2 += __shfl_down(p2, off);
    }
    if (lane == 0) {
        dx[v * 3 + 0] = p0 + LD<F32>(bh, 0);
        dx[v * 3 + 1] = p1 + LD<F32>(bh, 1);
        dx[v * 3 + 2] = p2 + LD<F32>(bh, 2);
    }
}

template<bool F32>
__global__ void k_ab(const float* __restrict__ dx, const void* __restrict__ pos,
                     const void* __restrict__ Wf3, float* __restrict__ ua,
                     float* __restrict__ bbag, const int* __restrict__ flag) {
    if ((flag[0] != 0) != F32) return;
    int idx = blockIdx.x * blockDim.x + threadIdx.x;
    if (idx >= N_V * SD) return;
    int v = idx / SD, c = idx - v * SD;
    float w0 = LD<F32>(Wf3, c), w1 = LD<F32>(Wf3, SD + c), w2 = LD<F32>(Wf3, 2 * SD + c);
    float P = LD<F32>(pos, v * 3 + 0) * w0 + LD<F32>(pos, v * 3 + 1) * w1
            + LD<F32>(pos, v * 3 + 2) * w2;
    float D = dx[v * 3 + 0] * w0 + dx[v * 3 + 1] * w1 + dx[v * 3 + 2] * w2;
    ua[idx] += P;
    bbag[idx] = D - P;
}

template<bool F32>
__global__ void k_cls(const float* __restrict__ hc, const void* __restrict__ W,
                      const void* __restrict__ b, void* __restrict__ out,
                      const int* __restrict__ flag) {
    if ((flag[0] != 0) != F32) return;
    int v = blockIdx.x * blockDim.x + threadIdx.x;
    if (v >= N_V) return;
    float acc[4];
#pragma unroll
    for (int j = 0; j < 4; j++) acc[j] = LD<F32>(b, j);
    for (int k = 0; k < 64; k++) {
        float h = hc[(size_t)v * 64 + k];
#pragma unroll
        for (int j = 0; j < 4; j++) acc[j] += h * LD<F32>(W, k * 4 + j);
    }
#pragma unroll
    for (int j = 0; j < 4; j++) ST<F32>(out, v * 4 + j, fmaxf(acc[j], 0.f));
}

template<bool F32>
__global__ void k_loc3(const float* __restrict__ h2, const void* __restrict__ W,
                       const void* __restrict__ b, void* __restrict__ out, int cls,
                       const int* __restrict__ flag) {
    if ((flag[0] != 0) != F32) return;
    int v = blockIdx.x * blockDim.x + threadIdx.x;
    if (v >= N_V) return;
    float acc[7];
#pragma unroll
    for (int j = 0; j < 7; j++) acc[j] = LD<F32>(b, j);
    for (int k = 0; k < 64; k++) {
        float h = h2[(size_t)v * 64 + k];
#pragma unroll
        for (int j = 0; j < 7; j++) acc[j] += h * LD<F32>(W, k * 7 + j);
    }
#pragma unroll
    for (int j = 0; j < 7; j++)
        ST<F32>(out, 80000 + (size_t)v * 28 + cls * 7 + j, fmaxf(acc[j], 0.f));
}

#define LAUNCH2(kname, grid, blk, ...) \
    do { kname<false><<<grid, blk, 0, stream>>>(__VA_ARGS__); \
         kname<true><<<grid, blk, 0, stream>>>(__VA_ARGS__); } while (0)

extern "C" void kernel_launch(void* const* d_in, const int* in_sizes, int n_in,
                              void* d_out, int out_size, void* d_ws, size_t ws_size,
                              hipStream_t stream) {
    const void* kp  = d_in[0];
    const void* pos = d_in[1];
    const int* eidx = (const int*)d_in[3];
    const int* e_src = eidx;
    const int* e_dst = eidx + E_N;
    const void* Wi0 = d_in[4];   const void* bi0 = d_in[5];
    const void* Wi1 = d_in[6];   const void* bi1 = d_in[7];
    const void* Wi2 = d_in[8];   const void* bi2 = d_in[9];
    const void* Wa  = d_in[10];  const void* ba  = d_in[11];
    const char* Wh  = (const char*)d_in[12];  const char* bh = (const char*)d_in[13];
    const char* Wf  = (const char*)d_in[14];  const char* bff = (const char*)d_in[15];
    const char* Wg  = (const char*)d_in[16];  const char* bg = (const char*)d_in[17];
    const void* Wc1 = d_in[18];  const void* bc1 = d_in[19];
    const void* Wc2 = d_in[20];  const void* bc2 = d_in[21];
    const char* Wl1 = (const char*)d_in[22];  const char* bl1 = (const char*)d_in[23];
    const char* Wl2 = (const char*)d_in[24];  const char* bl2 = (const char*)d_in[25];
    const char* Wl3 = (const char*)d_in[26];  const char* bl3 = (const char*)d_in[27];

    char* ws = (char*)d_ws;
    // region A (24MB): kpmax/ua -> hc(z0)+hl1m(z1..4, spills 1.6MB into dead bbag)
    float* regA  = (float*)(ws + 0);
    float* kpmax = regA;
    float* ua    = regA;
    float* hc    = regA;                      // head z=0
    float* hl1m  = regA + 1280000;            // head z=1..4
    float* hl1f  = (float*)(ws + 6000000);    // fallback
    float* hl2f  = (float*)(ws + 12000000);   // fallback
    // region B (24MB): bbag (GNN; dead at head time)
    float* bbag  = (float*)(ws + 24000000);
    // region C (24MB): s (GNN; dead after head GEMM1) -> hl2m
    float* s     = (float*)(ws + 48000000);
    float* hl2m  = (float*)(ws + 48000000);
    // small stuff
    int*   cnt   = (int*)(ws + 72000000);
    int*   offs  = (int*)(ws + 72100000);
    int*   cur   = (int*)(ws + 72200000);
    int*   esrc  = (int*)(ws + 72300000);
    float* dx    = (float*)(ws + 73600000);
    float* wf3F  = (float*)(ws + 73844000);
    int*   flag  = (int*)(ws + 73900000);
    // MFMA-path extras
    unsigned short* SPLIT = (unsigned short*)(ws + 73950000); // 3.53 MB
    float* biasF = (float*)(ws + 77481000);                   // 12.4 KB
    // total footprint < 77.5 MB

    bool mf = (ws_size == 0) || (ws_size >= (size_t)77500000);
    auto HI = [&](long long cum) { return SPLIT + 2 * cum; };

    // ----- zero cnt + dtype detect (merged) -----
    k_detz<<<80, 256, 0, stream>>>((const unsigned*)Wi0, flag, cnt);

    // ----- CSR: hist, scan, then scatter (+ weight prep merged) -----
    k_hist<<<(E_N + 255) / 256, 256, 0, stream>>>(e_dst, cnt);
    k_scan<<<1, 1024, 0, stream>>>(cnt, offs, cur);
    {
        int grid = SCAT_BLOCKS + (mf ? PREP_BLOCKS : 0);
        k_scprep<<<grid, 256, 0, stream>>>(
            e_src, e_dst, cur, esrc,
            Wa, Wf, Wg, Wc1, Wl1, Wl2, Wi1, Wi2,
            ba, bff, bg, bc1, bl1, bl2, bi1, bi2,
            SPLIT, biasF, wf3F, bbag, flag);
    }

    // ----- init MLP + segmax -----
    if (mf) {
        const unsigned short* W1T = SPLIT + 2LL * 835584;
        const unsigned short* W2T = SPLIT + 2LL * 843776;
        k_init_mfma<<<M_KP / 64, 256, 0, stream>>>(kp, Wi0, bi0, W1T, W2T,
                                                   biasF + 2676, biasF + 2804,
                                                   kpmax, flag);
    } else {
        LAUNCH2(k_init_fused, M_KP / 64, 256, kp, Wi0, bi0, Wi1, bi1, Wi2, bi2, kpmax, flag);
    }

    const dim3 GSD(5, (N_V + 127) / 128);   // N=300 x 128-row blocks
    if (mf) {
        k_gemm_mfma<<<GSD, 256, 0, stream>>>(kpmax, HI(0), HI(0) + 102400,
                                             biasF, nullptr, s, N_V, SD, 320, SD, 1,
                                             0, 0, 0, 0,
                                             nullptr, nullptr, nullptr, nullptr, flag);
    } else {
        dim3 g((SD + 63) / 64, (N_V + 63) / 64);
        LAUNCH2(k_gemm, g, 256, kpmax, Wa, ba, nullptr, s, N_V, SD, SD, 1, flag);
    }

    // ----- GNN iterations -----
    for (int t = 0; t < T_IT; t++) {
        dim3 g5((SD + 63) / 64, (N_V + 63) / 64);
        if (mf) {
            k_dx2<<<(N_V + 3) / 4, 256, 0, stream>>>(s, Wh, bh, t, dx, flag);
            long long cum = (long long)(1 + t) * 102400;
            // ua = s@WfS + bf + pos@Wf3 ; bbag = dx@Wf3 - pos@Wf3 (fused)
            k_gemm_mfma<<<GSD, 256, 0, stream>>>(s, HI(cum), HI(cum) + 102400,
                                                 biasF + 300 + t * 300, nullptr, ua,
                                                 N_V, SD, 320, SD, 0, 0, 0, 0, 0,
                                                 pos, dx, wf3F + t * 900, bbag, flag);
        } else {
            for (int f32v = 0; f32v < 2; f32v++) {
                size_t es = f32v ? 4 : 2;
                const void* Wf_t = Wf + (size_t)t * 303 * SD * es;
                const void* WfS  = Wf + ((size_t)t * 303 + 3) * SD * es;
                const void* bf_t = bff + (size_t)t * SD * es;
                const void* Wh_t = Wh + (size_t)t * SD * 3 * es;
                const void* bh_t = bh + (size_t)t * 3 * es;
                if (f32v) {
                    k_gemm<true><<<g5, 256, 0, stream>>>(s, WfS, bf_t, nullptr, ua, N_V, SD, SD, 0, flag);
                    k_dx<true><<<(N_V + 3) / 4, 256, 0, stream>>>(s, Wh_t, bh_t, dx, flag);
                    k_ab<true><<<(N_V * SD + 255) / 256, 256, 0, stream>>>(dx, pos, Wf_t, ua, bbag, flag);
                } else {
                    k_gemm<false><<<g5, 256, 0, stream>>>(s, WfS, bf_t, nullptr, ua, N_V, SD, SD, 0, flag);
                    k_dx<false><<<(N_V + 3) / 4, 256, 0, stream>>>(s, Wh_t, bh_t, dx, flag);
                    k_ab<false><<<(N_V * SD + 255) / 256, 256, 0, stream>>>(dx, pos, Wf_t, ua, bbag, flag);
                }
            }
        }
        k_aggr<<<(N_V + 3) / 4, 256, 0, stream>>>(ua, bbag, offs, esrc);
        if (mf) {
            long long cum = (long long)(4 + t) * 102400;
            k_gemm_mfma<<<GSD, 256, 0, stream>>>(bbag, HI(cum), HI(cum) + 102400,
                                                 biasF + 1200 + t * 300, s, s,
                                                 N_V, SD, 320, SD, 0, 0, 0, 0, 0,
                                                 nullptr, nullptr, nullptr, nullptr, flag);
        } else {
            for (int f32v = 0; f32v < 2; f32v++) {
                size_t es = f32v ? 4 : 2;
                const void* Wg_t = Wg + (size_t)t * SD * SD * es;
                const void* bg_t = bg + (size_t)t * SD * es;
                if (f32v)
                    k_gemm<true><<<g5, 256, 0, stream>>>(bbag, Wg_t, bg_t, s, s, N_V, SD, SD, 0, flag);
                else
                    k_gemm<false><<<g5, 256, 0, stream>>>(bbag, Wg_t, bg_t, s, s, N_V, SD, SD, 0, flag);
            }
        }
    }

    // ----- heads -----
    if (mf) {
        // z=0: Wc1 -> hc ; z=1..4: Wl1[c] -> hl1m  (split buffers contiguous)
        dim3 gz15(1, (N_V + 127) / 128, 5);
        k_gemm_mfma<<<gz15, 256, 0, stream>>>(s, HI(716800), HI(716800) + 20480,
                                              biasF + 2100, nullptr, regA,
                                              N_V, SD, 320, 64, 1,
                                              0, 40960, 64, 1280000,
                                              nullptr, nullptr, nullptr, nullptr, flag);
        // loc layer2 batched: hl1m -> hl2m (region C; s now dead)
        dim3 gz14(1, (N_V + 127) / 128, 4);
        k_gemm_mfma<<<gz14, 256, 0, stream>>>(hl1m, HI(819200), HI(819200) + 4096,
                                              biasF + 2420, nullptr, hl2m,
                                              N_V, 64, 64, 64, 1,
                                              1280000, 8192, 64, 1280000,
                                              nullptr, nullptr, nullptr, nullptr, flag);
        // merged cls (y=4) + loc layer3 (y=0..3)
        dim3 gho((N_V + 255) / 256, 5);
        k_headout<<<gho, 256, 0, stream>>>(hc, hl2m, Wc2, bc2, Wl3, bl3, d_out, flag);
    } else {
        dim3 g(1, (N_V + 63) / 64);
        LAUNCH2(k_gemm, g, 256, s, Wc1, bc1, nullptr, hl1f, N_V, SD, 64, 1, flag);
        LAUNCH2(k_cls, (N_V + 255) / 256, 256, hl1f, Wc2, bc2, d_out, flag);
        for (int c = 0; c < 4; c++) {
            for (int f32v = 0; f32v < 2; f32v++) {
                size_t es = f32v ? 4 : 2;
                const void* Wl1c = Wl1 + (size_t)c * SD * 64 * es;
                const void* bl1c = bl1 + (size_t)c * 64 * es;
                const void* Wl2c = Wl2 + (size_t)c * 64 * 64 * es;
                const void* bl2c = bl2 + (size_t)c * 64 * es;
                const void* Wl3c = Wl3 + (size_t)c * 64 * 7 * es;
                const void* bl3c = bl3 + (size_t)c * 7 * es;
                if (f32v) {
                    k_gemm<true><<<g, 256, 0, stream>>>(s, Wl1c, bl1c, nullptr, hl1f, N_V, SD, 64, 1, flag);
                    k_gemm<true><<<g, 256, 0, stream>>>(hl1f, Wl2c, bl2c, nullptr, hl2f, N_V, 64, 64, 1, flag);
                    k_loc3<true><<<(N_V + 255) / 256, 256, 0, stream>>>(hl2f, Wl3c, bl3c, d_out, c, flag);
                } else {
                    k_gemm<false><<<g, 256, 0, stream>>>(s, Wl1c, bl1c, nullptr, hl1f, N_V, SD, 64, 1, flag);
                    k_gemm<false><<<g, 256, 0, stream>>>(hl1f, Wl2c, bl2c, nullptr, hl2f, N_V, 64, 64, 1, flag);
                    k_loc3<false><<<(N_V + 255) / 256, 256, 0, stream>>>(hl2f, Wl3c, bl3c, d_out, c, flag);
                }
            }
        }
    }
}

// Round 11
// 1129.199 us; speedup vs baseline: 1.0538x; 1.0350x over previous
//
#include <hip/hip_runtime.h>
#include <stdint.h>

#define N_V   20000
#define M_KP  160000
#define E_N   320000
#define SD    300
#define T_IT  3

typedef unsigned short bf16_t;
typedef __attribute__((ext_vector_type(8))) short short8_t;
typedef __attribute__((ext_vector_type(4))) float float4_t;

__device__ __forceinline__ float bf2f(bf16_t u) {
    return __uint_as_float(((unsigned)u) << 16);
}
__device__ __forceinline__ bf16_t f2bf(float f) {
    unsigned u = __float_as_uint(f);
    unsigned r = (u + 0x7FFFu + ((u >> 16) & 1u)) >> 16;
    return (bf16_t)r;
}

template<bool F32>
__device__ __forceinline__ float LD(const void* p, size_t i) {
    if (F32) return ((const float*)p)[i];
    return bf2f(((const bf16_t*)p)[i]);
}
template<bool F32>
__device__ __forceinline__ void ST(void* p, size_t i, float v) {
    if (F32) ((float*)p)[i] = v;
    else     ((bf16_t*)p)[i] = f2bf(v);
}
__device__ __forceinline__ float LDr(const void* p, long long i, bool f32) {
    return f32 ? ((const float*)p)[i] : bf2f(((const bf16_t*)p)[i]);
}
__device__ __forceinline__ void STr(void* p, size_t i, float v, bool f32) {
    if (f32) ((float*)p)[i] = v;
    else     ((bf16_t*)p)[i] = f2bf(v);
}

// ---------- merged: zero cnt + dtype detect (flag=1 if f32, 0 if bf16) ----------
__global__ __launch_bounds__(256) void k_detz(const unsigned* __restrict__ w,
                                              int* __restrict__ flag,
                                              int* __restrict__ cnt) {
    if (blockIdx.x < 79) {
        int i = blockIdx.x * 256 + threadIdx.x;
        if (i < N_V) cnt[i] = 0;
        return;
    }
    __shared__ int cnt_s;
    if (threadIdx.x == 0) cnt_s = 0;
    __syncthreads();
    if (threadIdx.x < 128) {
        unsigned u = w[threadIdx.x];      // 128 dwords = 512B, safe for either dtype
        unsigned lo = u & 0xFFFFu;
        int e = (lo >> 7) & 0xFF;
        int plaus = (lo == 0u) || (e >= 96 && e <= 126);
        atomicAdd(&cnt_s, plaus);
    }
    __syncthreads();
    if (threadIdx.x == 0) flag[0] = (cnt_s >= 64) ? 0 : 1;
}

__global__ void k_hist(const int* __restrict__ dst, int* __restrict__ cnt) {
    int e = blockIdx.x * blockDim.x + threadIdx.x;
    if (e < E_N) atomicAdd(&cnt[dst[e]], 1);
}

// ---------- fast single-block scan: 20 elems/thread, 3 phases ----------
__global__ __launch_bounds__(1024) void k_scan(const int* __restrict__ cnt,
                                               int* __restrict__ offs,
                                               int* __restrict__ cur) {
    __shared__ int sums[1024];
    int tid = threadIdx.x;
    int base = tid * 20;
    int vals[20];
    int s = 0;
#pragma unroll
    for (int j = 0; j < 20; j++) {
        int i = base + j;
        int v = (i < N_V) ? cnt[i] : 0;
        vals[j] = v;
        s += v;
    }
    sums[tid] = s;
    __syncthreads();
    for (int off = 1; off < 1024; off <<= 1) {
        int t = (tid >= off) ? sums[tid - off] : 0;
        __syncthreads();
        sums[tid] += t;
        __syncthreads();
    }
    int run = (tid == 0) ? 0 : sums[tid - 1];
    if (tid == 0) offs[0] = 0;
#pragma unroll
    for (int j = 0; j < 20; j++) {
        int i = base + j;
        if (i < N_V) {
            cur[i] = run;
            run += vals[j];
            offs[i + 1] = run;
        }
    }
}

// ---------- weight prep layout ----------
// Split matrices: m0 Wa 320x320 cum 0 | m1-3 WfS[t] | m4-6 Wg[t]
//   m7 Wc1 64x320 cum 716800 | m8-11 Wl1[c] | m12-15 Wl2[c] cum 819200
//   m16 Wi1 128x64 cum 835584 | m17 Wi2 304x128 cum 843776
// biasF: [0,300) ba | [300,1200) bf | [1200,2100) bg | [2100,2164) bc1
//      | [2164,2420) bl1 | [2420,2676) bl2 | [2676,2804) bi1 | [2804,3104) bi2
// wf3F: 3 x [3][300] rows 0..2 of Wf[t]
// whTF (at wf3F+2700): 3 x [3][320] Wh[t] transposed, zero-padded
// bhF  (at wf3F+5580): 3 x [3] bh[t]
#define PREP_SPLIT 882688
#define PREP_BIAS  3104
#define PREP_WF3   2700
#define PREP_WHT   2880
#define PREP_BH    9
#define PREP_TOT   (PREP_SPLIT + PREP_BIAS + PREP_WF3 + PREP_WHT + PREP_BH + 32)
#define SCAT_BLOCKS 1250
#define PREP_BLOCKS ((PREP_TOT + 255) / 256)

// ---------- merged: edge scatter + weight prep ----------
__global__ __launch_bounds__(256) void k_scprep(
    const int* __restrict__ src, const int* __restrict__ dst,
    int* __restrict__ cur, int* __restrict__ esrc,
    const void* __restrict__ Wa, const void* __restrict__ Wf,
    const void* __restrict__ Wg, const void* __restrict__ Wc1,
    const void* __restrict__ Wl1, const void* __restrict__ Wl2,
    const void* __restrict__ Wi1, const void* __restrict__ Wi2,
    const void* __restrict__ Whw, const void* __restrict__ bhw,
    const void* __restrict__ ba, const void* __restrict__ bfb,
    const void* __restrict__ bgb, const void* __restrict__ bc1,
    const void* __restrict__ bl1b, const void* __restrict__ bl2b,
    const void* __restrict__ bi1, const void* __restrict__ bi2,
    unsigned short* __restrict__ SP, float* __restrict__ biasF,
    float* __restrict__ wf3F, float* __restrict__ bzero,
    const int* __restrict__ flag)
{
    if (blockIdx.x < SCAT_BLOCKS) {
        int e = blockIdx.x * 256 + threadIdx.x;
        if (e < E_N) {
            int p = atomicAdd(&cur[dst[e]], 1);
            esrc[p] = src[e];
        }
        return;
    }
    int idx = (blockIdx.x - SCAT_BLOCKS) * 256 + threadIdx.x;
    if (idx >= PREP_TOT) return;
    bool f32 = flag[0] != 0;
    if (idx < PREP_SPLIT) {
        const void* srcp; long long eoff, cum; int srcN, Nn, Kk, Kpad, pe, local;
        if (idx < 716800) {
            int m = idx / 102400; local = idx - m * 102400;
            pe = 102400; cum = (long long)m * 102400;
            Kpad = 320; Nn = 300; Kk = 300; srcN = 300;
            srcp = (m == 0) ? Wa : (m <= 3 ? Wf : Wg);
            eoff = (m == 0) ? 0 : (m <= 3 ? (long long)((m - 1) * 303 + 3) * 300
                                          : (long long)(m - 4) * 90000);
        } else if (idx < 819200) {
            int j = (idx - 716800) / 20480; local = (idx - 716800) - j * 20480;
            pe = 20480; cum = 716800 + (long long)j * 20480;
            Kpad = 320; Nn = 64; Kk = 300; srcN = 64;
            srcp = (j == 0) ? Wc1 : Wl1;
            eoff = (j == 0) ? 0 : (long long)(j - 1) * 19200;
        } else if (idx < 835584) {
            int c = (idx - 819200) / 4096; local = (idx - 819200) - c * 4096;
            pe = 4096; cum = 819200 + (long long)c * 4096;
            Kpad = 64; Nn = 64; Kk = 64; srcN = 64;
            srcp = Wl2; eoff = (long long)c * 4096;
        } else if (idx < 843776) {
            local = idx - 835584;
            pe = 8192; cum = 835584;
            Kpad = 64; Nn = 128; Kk = 64; srcN = 128;
            srcp = Wi1; eoff = 0;
        } else {
            local = idx - 843776;
            pe = 38912; cum = 843776;
            Kpad = 128; Nn = 300; Kk = 128; srcN = 300;
            srcp = Wi2; eoff = 0;
        }
        int n = local / Kpad, k = local - n * Kpad;
        float v = 0.f;
        if (n < Nn && k < Kk) v = LDr(srcp, eoff + (long long)k * srcN + n, f32);
        bf16_t hi = f2bf(v);                 // RN split
        bf16_t lo = f2bf(v - bf2f(hi));      // bf16 input -> hi exact, lo = 0
        SP[2 * cum + local] = hi;
        SP[2 * cum + pe + local] = lo;
    } else if (idx < PREP_SPLIT + PREP_BIAS) {
        int b = idx - PREP_SPLIT;
        const void* srcp; int o;
        if (b < 300)       { srcp = ba;   o = b; }
        else if (b < 1200) { srcp = bfb;  o = b - 300; }
        else if (b < 2100) { srcp = bgb;  o = b - 1200; }
        else if (b < 2164) { srcp = bc1;  o = b - 2100; }
        else if (b < 2420) { srcp = bl1b; o = b - 2164; }
        else if (b < 2676) { srcp = bl2b; o = b - 2420; }
        else if (b < 2804) { srcp = bi1;  o = b - 2676; }
        else               { srcp = bi2;  o = b - 2804; }
        biasF[b] = LDr(srcp, o, f32);
    } else if (idx < PREP_SPLIT + PREP_BIAS + PREP_WF3) {
        int b2 = idx - (PREP_SPLIT + PREP_BIAS);
        int t = b2 / 900, rem = b2 - t * 900;
        wf3F[b2] = LDr(Wf, (long long)t * 303 * SD + rem, f32);
    } else if (idx < PREP_SPLIT + PREP_BIAS + PREP_WF3 + PREP_WHT) {
        int b3 = idx - (PREP_SPLIT + PREP_BIAS + PREP_WF3);
        int t = b3 / 960, rem = b3 - t * 960;
        int j = rem / 320, k = rem - j * 320;
        // whTF at wf3F+2700: Wh[t][k][j] transposed, cols >=300 zero
        wf3F[2700 + b3] = (k < SD) ? LDr(Whw, (long long)t * SD * 3 + k * 3 + j, f32)
                                   : 0.f;
    } else if (idx < PREP_SPLIT + PREP_BIAS + PREP_WF3 + PREP_WHT + PREP_BH) {
        int b4 = idx - (PREP_SPLIT + PREP_BIAS + PREP_WF3 + PREP_WHT);
        wf3F[5580 + b4] = LDr(bhw, b4, f32);   // bh[t][j], t*3+j
    } else {
        bzero[idx - (PREP_SPLIT + PREP_BIAS + PREP_WF3 + PREP_WHT + PREP_BH)] = 0.f;
    }
}

// ---------- fused init MLP (fallback VALU path) ----------
template<bool F32>
__global__ __launch_bounds__(256) void k_init_fused(
    const void* __restrict__ kp,
    const void* __restrict__ Wi0, const void* __restrict__ bi0,
    const void* __restrict__ Wi1, const void* __restrict__ bi1,
    const void* __restrict__ Wi2, const void* __restrict__ bi2,
    float* __restrict__ kpmax, const int* __restrict__ flag) {
    if ((flag[0] != 0) != F32) return;
    __shared__ float kps[256];
    __shared__ float h1s[64][64];
    __shared__ float h2s[64 * 128];
    int tid = threadIdx.x;
    int row0 = blockIdx.x * 64;
    kps[tid] = LD<F32>(kp, (size_t)row0 * 4 + tid);
    __syncthreads();
    {
        int c = tid & 63;
        float w0 = LD<F32>(Wi0, c), w1 = LD<F32>(Wi0, 64 + c);
        float w2 = LD<F32>(Wi0, 128 + c), w3 = LD<F32>(Wi0, 192 + c);
        float b0 = LD<F32>(bi0, c);
        int rbase = (tid >> 6) * 16;
#pragma unroll
        for (int rr = 0; rr < 16; rr++) {
            int r = rbase + rr;
            float a = b0 + kps[r * 4] * w0 + kps[r * 4 + 1] * w1
                         + kps[r * 4 + 2] * w2 + kps[r * 4 + 3] * w3;
            h1s[r][c] = fmaxf(a, 0.f);
        }
    }
    __syncthreads();
    {
        int c = tid & 127;
        int rbase = (tid >> 7) * 32;
        float b1 = LD<F32>(bi1, c);
        float acc[32];
#pragma unroll
        for (int rr = 0; rr < 32; rr++) acc[rr] = b1;
        for (int k = 0; k < 64; k++) {
            float wv = LD<F32>(Wi1, (size_t)k * 128 + c);
#pragma unroll
            for (int rr = 0; rr < 32; rr++) acc[rr] += h1s[rbase + rr][k] * wv;
        }
#pragma unroll
        for (int rr = 0; rr < 32; rr++)
            h2s[(size_t)(rbase + rr) * 128 + c] = fmaxf(acc[rr], 0.f);
    }
    __syncthreads();
    {
        int cx = tid & 63, rg = tid >> 6;
        float acc[16][5];
#pragma unroll
        for (int r = 0; r < 16; r++)
#pragma unroll
            for (int j = 0; j < 5; j++) acc[r][j] = 0.f;
        bool ok4 = (cx < SD - 256);
        for (int k = 0; k < 128; k++) {
            float w[5];
#pragma unroll
            for (int j = 0; j < 4; j++) w[j] = LD<F32>(Wi2, (size_t)k * SD + cx + 64 * j);
            w[4] = ok4 ? LD<F32>(Wi2, (size_t)k * SD + cx + 256) : 0.f;
#pragma unroll
            for (int r = 0; r < 16; r++) {
                float av = h2s[(rg * 16 + r) * 128 + k];
#pragma unroll
                for (int j = 0; j < 5; j++) acc[r][j] += av * w[j];
            }
        }
        int vbase = (row0 >> 3) + rg * 2;
#pragma unroll
        for (int half = 0; half < 2; half++) {
            int v = vbase + half;
#pragma unroll
            for (int j = 0; j < 5; j++) {
                int c = cx + 64 * j;
                if (c >= SD) continue;
                float m = acc[half * 8][j];
#pragma unroll
                for (int r = 1; r < 8; r++) m = fmaxf(m, acc[half * 8 + r][j]);
                kpmax[(size_t)v * SD + c] = fmaxf(m + LD<F32>(bi2, c), 0.f);
            }
        }
    }
}

// ---------- generic tiled f32 GEMM (fallback path only) ----------
template<bool F32>
__global__ __launch_bounds__(256) void k_gemm(
    const float* __restrict__ A, const void* __restrict__ W,
    const void* __restrict__ bias, const float* res,
    float* C, int Mr, int K, int Nc, int do_relu, const int* __restrict__ flag) {
    if ((flag[0] != 0) != F32) return;
    __shared__ float As[16][65];
    __shared__ float Ws[16][64];
    int tid = threadIdx.x;
    int tx = tid & 15, ty = tid >> 4;
    int row0 = blockIdx.y * 64, col0 = blockIdx.x * 64;
    float acc[4][4] = {{0.f}};
    int lk = tid & 15, lr = tid >> 4;
    int ln = tid & 63, lk4 = tid >> 6;
    for (int k0 = 0; k0 < K; k0 += 16) {
#pragma unroll
        for (int i = 0; i < 4; i++) {
            int r = lr + i * 16;
            int gr = row0 + r, gk = k0 + lk;
            As[lk][r] = (gr < Mr && gk < K) ? A[(size_t)gr * K + gk] : 0.f;
        }
#pragma unroll
        for (int p = 0; p < 4; p++) {
            int kk = lk4 + p * 4;
            int gk = k0 + kk, gn = col0 + ln;
            Ws[kk][ln] = (gk < K && gn < Nc) ? LD<F32>(W, (size_t)gk * Nc + gn) : 0.f;
        }
        __syncthreads();
#pragma unroll
        for (int kk = 0; kk < 16; kk++) {
            float a[4], w[4];
#pragma unroll
            for (int i = 0; i < 4; i++) a[i] = As[kk][ty * 4 + i];
#pragma unroll
            for (int j = 0; j < 4; j++) w[j] = Ws[kk][tx * 4 + j];
#pragma unroll
            for (int i = 0; i < 4; i++)
#pragma unroll
                for (int j = 0; j < 4; j++) acc[i][j] += a[i] * w[j];
        }
        __syncthreads();
    }
#pragma unroll
    for (int i = 0; i < 4; i++) {
        int gr = row0 + ty * 4 + i;
        if (gr >= Mr) continue;
#pragma unroll
        for (int j = 0; j < 4; j++) {
            int gn = col0 + tx * 4 + j;
            if (gn >= Nc) continue;
            float c = acc[i][j] + LD<F32>(bias, gn);
            if (res) c += res[(size_t)gr * Nc + gn];
            if (do_relu) c = fmaxf(c, 0.f);
            C[(size_t)gr * Nc + gn] = c;
        }
    }
}

// ---------- MFMA helpers ----------
__device__ __forceinline__ void mfma16(float4_t& c, short8_t a, short8_t b) {
    asm("v_mfma_f32_16x16x32_bf16 %0, %1, %2, %0" : "+v"(c) : "v"(a), "v"(b));
}
__device__ __forceinline__ void split2(float a, float b, unsigned& h, unsigned& l) {
    asm("v_cvt_pk_bf16_f32 %0, %1, %2" : "=v"(h) : "v"(a), "v"(b));
    float la = a - __uint_as_float(h << 16);
    float lb = b - __uint_as_float(h & 0xFFFF0000u);
    asm("v_cvt_pk_bf16_f32 %0, %1, %2" : "=v"(l) : "v"(la), "v"(lb));
}
__device__ __forceinline__ void split8(float4_t x0, float4_t x1,
                                       short8_t* hi, short8_t* lo) {
    union { unsigned u[4]; short8_t v; } H, L;
#pragma unroll
    for (int p = 0; p < 4; p++) {
        float a, b;
        if (p == 0)      { a = x0[0]; b = x0[1]; }
        else if (p == 1) { a = x0[2]; b = x0[3]; }
        else if (p == 2) { a = x1[0]; b = x1[1]; }
        else             { a = x1[2]; b = x1[3]; }
        unsigned ph, pl;
        split2(a, b, ph, pl);
        H.u[p] = ph; L.u[p] = pl;
    }
    *hi = H.v; *lo = L.v;
}

// ---------- MFMA init MLP v3 (+ wlo skip) ----------
__global__ __launch_bounds__(256) void k_init_mfma(
    const void* __restrict__ kp,
    const void* __restrict__ Wi0, const void* __restrict__ bi0,
    const unsigned short* __restrict__ W1T,   // [128][64], lo at +8192
    const unsigned short* __restrict__ W2T,   // [304][128], lo at +38912
    const float* __restrict__ b1F, const float* __restrict__ b2F,
    float* __restrict__ kpmax, const int* __restrict__ flag)
{
    bool f32 = flag[0] != 0;
    bool wlo = f32;
    __shared__ __attribute__((aligned(16))) unsigned short lds[2][8704]; // 34,816 B
    int tid = threadIdx.x;
    int w = tid >> 6, lane = tid & 63;
    int rg = w >> 1, ch = w & 1;
    int l15 = lane & 15, g = lane >> 4;
    unsigned short* h2h = lds[rg];
    unsigned short* h2l = lds[rg] + 4352;
    int rw0 = blockIdx.x * 64 + rg * 32;

    float kpr[2][4];
#pragma unroll
    for (int mt = 0; mt < 2; mt++) {
        long long r = rw0 + mt * 16 + l15;
#pragma unroll
        for (int j = 0; j < 4; j++) kpr[mt][j] = LDr(kp, r * 4 + j, f32);
    }
    short8_t a1h[2][2], a1l[2][2];
#pragma unroll
    for (int ks = 0; ks < 2; ks++) {
        float h[2][8];
#pragma unroll
        for (int e = 0; e < 8; e++) {
            int chn = ks * 32 + 8 * g + e;
            float w0 = LDr(Wi0, chn, f32),       w1 = LDr(Wi0, 64 + chn, f32);
            float w2 = LDr(Wi0, 128 + chn, f32), w3 = LDr(Wi0, 192 + chn, f32);
            float b0 = LDr(bi0, chn, f32);
#pragma unroll
            for (int mt = 0; mt < 2; mt++)
                h[mt][e] = fmaxf(b0 + kpr[mt][0] * w0 + kpr[mt][1] * w1
                                    + kpr[mt][2] * w2 + kpr[mt][3] * w3, 0.f);
        }
#pragma unroll
        for (int mt = 0; mt < 2; mt++) {
            union { unsigned u[4]; short8_t v; } H, L;
#pragma unroll
            for (int p = 0; p < 4; p++) {
                unsigned hh, ll;
                split2(h[mt][2 * p], h[mt][2 * p + 1], hh, ll);
                H.u[p] = hh; L.u[p] = ll;
            }
            a1h[mt][ks] = H.v; a1l[mt][ks] = L.v;
        }
    }

#pragma unroll
    for (int i = 0; i < 4; i++) {
        int n0 = ch * 4 + i;
        const unsigned short* bp = W1T + (n0 * 16 + l15) * 64 + 8 * g;
        short8_t bh0 = *(const short8_t*)bp;
        short8_t bh1 = *(const short8_t*)(bp + 32);
        float4_t c0 = {0.f, 0.f, 0.f, 0.f}, c1 = {0.f, 0.f, 0.f, 0.f};
        mfma16(c0, a1h[0][0], bh0); mfma16(c0, a1h[0][1], bh1);
        mfma16(c0, a1l[0][0], bh0); mfma16(c0, a1l[0][1], bh1);
        mfma16(c1, a1h[1][0], bh0); mfma16(c1, a1h[1][1], bh1);
        mfma16(c1, a1l[1][0], bh0); mfma16(c1, a1l[1][1], bh1);
        if (wlo) {
            short8_t bl0 = *(const short8_t*)(bp + 8192);
            short8_t bl1 = *(const short8_t*)(bp + 8224);
            mfma16(c0, a1h[0][0], bl0); mfma16(c0, a1h[0][1], bl1);
            mfma16(c1, a1h[1][0], bl0); mfma16(c1, a1h[1][1], bl1);
        }
        int col = n0 * 16 + l15;
        float bv = b1F[col];
#pragma unroll
        for (int i2 = 0; i2 < 4; i2++) {
            float v0 = fmaxf(c0[i2] + bv, 0.f);
            bf16_t h0 = f2bf(v0);
            h2h[(4 * g + i2) * 136 + col] = h0;
            h2l[(4 * g + i2) * 136 + col] = f2bf(v0 - bf2f(h0));
            float v1 = fmaxf(c1[i2] + bv, 0.f);
            bf16_t h1v = f2bf(v1);
            h2h[(16 + 4 * g + i2) * 136 + col] = h1v;
            h2l[(16 + 4 * g + i2) * 136 + col] = f2bf(v1 - bf2f(h1v));
        }
    }
    __syncthreads();

    short8_t a2h[2][4], a2l[2][4];
#pragma unroll
    for (int mt = 0; mt < 2; mt++)
#pragma unroll
        for (int ks = 0; ks < 4; ks++) {
            int off = (mt * 16 + l15) * 136 + ks * 32 + 8 * g;
            a2h[mt][ks] = *(const short8_t*)(h2h + off);
            a2l[mt][ks] = *(const short8_t*)(h2l + off);
        }
    int vb = blockIdx.x * 8 + rg * 4;
    int n0beg = ch ? 10 : 0, n0end = ch ? 19 : 10;
    for (int n0 = n0beg; n0 < n0end; n0++) {
        const unsigned short* bp = W2T + (n0 * 16 + l15) * 128 + 8 * g;
        short8_t bh[4];
#pragma unroll
        for (int ks = 0; ks < 4; ks++) bh[ks] = *(const short8_t*)(bp + ks * 32);
        float4_t c0 = {0.f, 0.f, 0.f, 0.f}, c1 = {0.f, 0.f, 0.f, 0.f};
#pragma unroll
        for (int ks = 0; ks < 4; ks++) {
            mfma16(c0, a2h[0][ks], bh[ks]); mfma16(c1, a2h[1][ks], bh[ks]);
        }
#pragma unroll
        for (int ks = 0; ks < 4; ks++) {
            mfma16(c0, a2l[0][ks], bh[ks]); mfma16(c1, a2l[1][ks], bh[ks]);
        }
        if (wlo) {
            short8_t bl[4];
#pragma unroll
            for (int ks = 0; ks < 4; ks++)
                bl[ks] = *(const short8_t*)(bp + 38912 + ks * 32);
#pragma unroll
            for (int ks = 0; ks < 4; ks++) {
                mfma16(c0, a2h[0][ks], bl[ks]); mfma16(c1, a2h[1][ks], bl[ks]);
            }
        }
        float m0 = fmaxf(fmaxf(c0[0], c0[1]), fmaxf(c0[2], c0[3]));
        m0 = fmaxf(m0, __shfl_xor(m0, 16));
        float m1 = fmaxf(fmaxf(c1[0], c1[1]), fmaxf(c1[2], c1[3]));
        m1 = fmaxf(m1, __shfl_xor(m1, 16));
        int col = n0 * 16 + l15;
        if (col < SD) {
            float bv = b2F[col];
            if (g == 0) {
                kpmax[(size_t)(vb + 0) * SD + col] = fmaxf(m0 + bv, 0.f);
                kpmax[(size_t)(vb + 2) * SD + col] = fmaxf(m1 + bv, 0.f);
            } else if (g == 2) {
                kpmax[(size_t)(vb + 1) * SD + col] = fmaxf(m0 + bv, 0.f);
                kpmax[(size_t)(vb + 3) * SD + col] = fmaxf(m1 + bv, 0.f);
            }
        }
    }
}

// ---------- split-bf16 MFMA GEMM v3: fused dx (= A@WhT + bh) + AB epilogue ----------
// Grid: x = ceil(N/64), y = ceil(M/128), z batched. (K+31)/32 must be EVEN.
// If posp != null: dx computed in-kernel from raw A values and whTF[3][320];
//   C(=ua) = A@W + bias + pos@Wf3 ; bbag = dx@Wf3 - pos@Wf3.
__global__ __launch_bounds__(256) void k_gemm_mfma(
    const float* __restrict__ A, const unsigned short* __restrict__ WhiT,
    const unsigned short* __restrict__ WloT, const float* __restrict__ bias,
    const float* __restrict__ res, float* __restrict__ C,
    int M, int K, int Kpad, int N, int relu,
    long long zA, long long zW, int zB, long long zC,
    const void* posp, const float* whTF, const float* wf3F,
    const float* bhF, float* bbag, const int* __restrict__ flag)
{
    bool wlo = flag[0] != 0;   // weight-lo nonzero only in f32 mode
    int z = blockIdx.z;
    A    += (size_t)z * zA;
    WhiT += (size_t)z * zW;
    WloT += (size_t)z * zW;
    bias += (size_t)z * zB;
    C    += (size_t)z * zC;
    int tid = threadIdx.x;
    int w = tid >> 6, lane = tid & 63;
    int l15 = lane & 15, g = lane >> 4;
    int row0 = blockIdx.y * 128 + w * 32;   // wave owns 32 rows
    int col0 = blockIdx.x * 64;
    bool ab = posp != nullptr;

    __shared__ float dxs[4][2][16][3];

    float4_t acc[2][4];
#pragma unroll
    for (int i = 0; i < 2; i++)
#pragma unroll
        for (int j = 0; j < 4; j++) acc[i][j] = (float4_t){0.f, 0.f, 0.f, 0.f};
    float dxp[2][3] = {{0.f, 0.f, 0.f}, {0.f, 0.f, 0.f}};

    const unsigned short* bhp[4];
    const unsigned short* blp[4];
#pragma unroll
    for (int ns = 0; ns < 4; ns++) {
        size_t o = (size_t)(col0 + ns * 16 + l15) * Kpad + 8 * g;
        bhp[ns] = WhiT + o; blp[ns] = WloT + o;
    }
    const float* app[2];
    int amode[2]; bool adead[2];
#pragma unroll
    for (int ms = 0; ms < 2; ms++) {
        int base = row0 + ms * 16;
        int gr = base + l15;
        amode[ms] = (base + 16 <= M) ? 2 : (base < M ? 1 : 0);
        adead[ms] = gr >= M;
        int grc = gr < M ? gr : (M - 1);
        app[ms] = A + (size_t)grc * K + 8 * g;
    }
    const float4_t zf4 = {0.f, 0.f, 0.f, 0.f};
    const short8_t z8 = {0, 0, 0, 0, 0, 0, 0, 0};

    auto LOADB = [&](short8_t* bh, short8_t* bl) {
#pragma unroll
        for (int ns = 0; ns < 4; ns++) {
            bh[ns] = *(const short8_t*)bhp[ns];
            bl[ns] = wlo ? *(const short8_t*)blp[ns] : z8;
            bhp[ns] += 32; blp[ns] += 32;
        }
    };
    auto LOADA = [&](float4_t* x0, float4_t* x1) {
#pragma unroll
        for (int ms = 0; ms < 2; ms++) {
            if (amode[ms] == 0) { x0[ms] = zf4; x1[ms] = zf4; }
            else {
                x0[ms] = *(const float4_t*)app[ms];
                x1[ms] = *(const float4_t*)(app[ms] + 4);
                if (amode[ms] == 1 && adead[ms]) { x0[ms] = zf4; x1[ms] = zf4; }
            }
            app[ms] += 32;
        }
    };
    auto COMPUTE = [&](const short8_t* bh, const short8_t* bl,
                       const float4_t* x0, const float4_t* x1, int kbase) {
        if (ab) {
#pragma unroll
            for (int j = 0; j < 3; j++) {
                float4_t wa = *(const float4_t*)(whTF + j * 320 + kbase + 8 * g);
                float4_t wb = *(const float4_t*)(whTF + j * 320 + kbase + 8 * g + 4);
#pragma unroll
                for (int ms = 0; ms < 2; ms++) {
                    dxp[ms][j] += x0[ms][0] * wa[0] + x0[ms][1] * wa[1]
                                + x0[ms][2] * wa[2] + x0[ms][3] * wa[3]
                                + x1[ms][0] * wb[0] + x1[ms][1] * wb[1]
                                + x1[ms][2] * wb[2] + x1[ms][3] * wb[3];
                }
            }
        }
#pragma unroll
        for (int ms = 0; ms < 2; ms++) {
            short8_t ah, al;
            split8(x0[ms], x1[ms], &ah, &al);
#pragma unroll
            for (int ns = 0; ns < 4; ns++) {
                mfma16(acc[ms][ns], ah, bh[ns]);
                mfma16(acc[ms][ns], al, bh[ns]);
            }
            if (wlo) {
#pragma unroll
                for (int ns = 0; ns < 4; ns++) mfma16(acc[ms][ns], ah, bl[ns]);
            }
        }
    };

    short8_t bhA[4], blA[4], bhB[4], blB[4];
    float4_t x0A[2], x1A[2], x0B[2], x1B[2];
    int iters = (K + 31) / 32;                 // 10 or 2 (even)
    LOADB(bhA, blA); LOADA(x0A, x1A);
    for (int it = 0; it < iters; it += 2) {
        LOADB(bhB, blB); LOADA(x0B, x1B);      // prefetch it+1
        COMPUTE(bhA, blA, x0A, x1A, it * 32);
        if (it + 2 < iters) { LOADB(bhA, blA); LOADA(x0A, x1A); }  // prefetch it+2
        COMPUTE(bhB, blB, x0B, x1B, (it + 1) * 32);
    }

    if (ab) {
        // reduce dx partials over the 4 g-groups (lanes l15+16g share a row)
#pragma unroll
        for (int ms = 0; ms < 2; ms++)
#pragma unroll
            for (int j = 0; j < 3; j++) {
                float p = dxp[ms][j];
                p += __shfl_xor(p, 16);
                p += __shfl_xor(p, 32);
                dxp[ms][j] = p;
            }
        if (g == 0) {
#pragma unroll
            for (int ms = 0; ms < 2; ms++)
#pragma unroll
                for (int j = 0; j < 3; j++) dxs[w][ms][l15][j] = dxp[ms][j];
        }
        __syncthreads();
    }

    bool pf32 = ab && wlo;
    int gnv[4]; float bvv[4], w30v[4], w31v[4], w32v[4];
#pragma unroll
    for (int ns = 0; ns < 4; ns++) {
        int gn = col0 + ns * 16 + l15;
        gnv[ns] = gn;
        bvv[ns] = (gn < N) ? bias[gn] : 0.f;
        if (ab && gn < N) {
            w30v[ns] = wf3F[gn]; w31v[ns] = wf3F[300 + gn]; w32v[ns] = wf3F[600 + gn];
        } else { w30v[ns] = 0.f; w31v[ns] = 0.f; w32v[ns] = 0.f; }
    }
    float bh0 = 0.f, bh1 = 0.f, bh2 = 0.f;
    if (ab) { bh0 = bhF[0]; bh1 = bhF[1]; bh2 = bhF[2]; }
#pragma unroll
    for (int ms = 0; ms < 2; ms++) {
#pragma unroll
        for (int r = 0; r < 4; r++) {
            int gr = row0 + ms * 16 + 4 * g + r;
            if (gr >= M) continue;
            float p0 = 0.f, p1 = 0.f, p2 = 0.f, d0 = 0.f, d1 = 0.f, d2 = 0.f;
            if (ab) {
                p0 = LDr(posp, (long long)gr * 3 + 0, pf32);
                p1 = LDr(posp, (long long)gr * 3 + 1, pf32);
                p2 = LDr(posp, (long long)gr * 3 + 2, pf32);
                int rl = 4 * g + r;
                d0 = dxs[w][ms][rl][0] + bh0;
                d1 = dxs[w][ms][rl][1] + bh1;
                d2 = dxs[w][ms][rl][2] + bh2;
            }
#pragma unroll
            for (int ns = 0; ns < 4; ns++) {
                int gn = gnv[ns];
                if (gn >= N) continue;
                float c = acc[ms][ns][r] + bvv[ns];
                if (ab) {
                    float P = p0 * w30v[ns] + p1 * w31v[ns] + p2 * w32v[ns];
                    float D = d0 * w30v[ns] + d1 * w31v[ns] + d2 * w32v[ns];
                    c += P;
                    bbag[(size_t)gr * N + gn] = D - P;
                }
                if (res) c += res[(size_t)gr * N + gn];
                if (relu) c = fmaxf(c, 0.f);
                C[(size_t)gr * N + gn] = c;
            }
        }
    }
}

__global__ __launch_bounds__(256) void k_aggr(
    const float* __restrict__ a, float* bbag,
    const int* __restrict__ offs, const int* __restrict__ esrc) {
    int wv = threadIdx.x >> 6, lane = threadIdx.x & 63;
    int v = blockIdx.x * 4 + wv;
    if (v >= N_V) return;
    int e0 = offs[v], e1 = offs[v + 1];
    float r0 = -3.0e38f, r1 = r0, r2 = r0, r3 = r0, r4 = r0;
    bool c4 = lane < SD - 256;
    for (int e = e0; e < e1; e++) {
        const float* ar = a + (size_t)esrc[e] * SD + lane;
        r0 = fmaxf(r0, ar[0]);
        r1 = fmaxf(r1, ar[64]);
        r2 = fmaxf(r2, ar[128]);
        r3 = fmaxf(r3, ar[192]);
        if (c4) r4 = fmaxf(r4, ar[256]);
    }
    float* bv = bbag + (size_t)v * SD + lane;
    bv[0]   = fmaxf(0.f, r0 + bv[0]);
    bv[64]  = fmaxf(0.f, r1 + bv[64]);
    bv[128] = fmaxf(0.f, r2 + bv[128]);
    bv[192] = fmaxf(0.f, r3 + bv[192]);
    if (c4) bv[256] = fmaxf(0.f, r4 + bv[256]);
}

// merged heads output: y in [0,4) -> loc3 class y from hl2all; y==4 -> cls from hc
__global__ void k_headout(const float* __restrict__ hc,
                          const float* __restrict__ hl2all,
                          const void* __restrict__ Wc2, const void* __restrict__ bc2,
                          const void* __restrict__ Wl3, const void* __restrict__ bl3,
                          void* __restrict__ out, const int* __restrict__ flag) {
    bool f32 = flag[0] != 0;
    int y = blockIdx.y;
    int v = blockIdx.x * blockDim.x + threadIdx.x;
    if (v >= N_V) return;
    if (y == 4) {
        float acc[4];
#pragma unroll
        for (int j = 0; j < 4; j++) acc[j] = LDr(bc2, j, f32);
        for (int k = 0; k < 64; k++) {
            float h = hc[(size_t)v * 64 + k];
#pragma unroll
            for (int j = 0; j < 4; j++) acc[j] += h * LDr(Wc2, k * 4 + j, f32);
        }
#pragma unroll
        for (int j = 0; j < 4; j++) STr(out, v * 4 + j, fmaxf(acc[j], 0.f), f32);
    } else {
        const float* h2 = hl2all + (size_t)y * N_V * 64;
        long long wo = (long long)y * 64 * 7, bo = (long long)y * 7;
        float acc[7];
#pragma unroll
        for (int j = 0; j < 7; j++) acc[j] = LDr(bl3, bo + j, f32);
        for (int k = 0; k < 64; k++) {
            float h = h2[(size_t)v * 64 + k];
#pragma unroll
            for (int j = 0; j < 7; j++) acc[j] += h * LDr(Wl3, wo + k * 7 + j, f32);
        }
#pragma unroll
        for (int j = 0; j < 7; j++)
            STr(out, 80000 + (size_t)v * 28 + y * 7 + j, fmaxf(acc[j], 0.f), f32);
    }
}

// ---------- fallback-path small kernels ----------
template<bool F32>
__global__ void k_dx(const float* __restrict__ s, const void* __restrict__ Wh,
                     const void* __restrict__ bh, float* __restrict__ dx,
                     const int* __restrict__ flag) {
    if ((flag[0] != 0) != F32) return;
    int wv = threadIdx.x >> 6, lane = threadIdx.x & 63;
    int v = blockIdx.x * 4 + wv;
    if (v >= N_V) return;
    float p0 = 0.f, p1 = 0.f, p2 = 0.f;
    for (int d = lane; d < SD; d += 64) {
        float sv = s[(size_t)v * SD + d];
        p0 += sv * LD<F32>(Wh, d * 3 + 0);
        p1 += sv * LD<F32>(Wh, d * 3 + 1);
        p2 += sv * LD<F32>(Wh, d * 3 + 2);
    }
#pragma unroll
    for (int off = 32; off > 0; off >>= 1) {
        p0 += __shfl_down(p0, off);
        p1 += __shfl_down(p1, off);
        p2 += __shfl_down(p2, off);
    }
    if (lane == 0) {
        dx[v * 3 + 0] = p0 + LD<F32>(bh, 0);
        dx[v * 3 + 1] = p1 + LD<F32>(bh, 1);
        dx[v * 3 + 2] = p2 + LD<F32>(bh, 2);
    }
}

template<bool F32>
__global__ void k_ab(const float* __restrict__ dx, const void* __restrict__ pos,
                     const void* __restrict__ Wf3, float* __restrict__ ua,
                     float* __restrict__ bbag, const int* __restrict__ flag) {
    if ((flag[0] != 0) != F32) return;
    int idx = blockIdx.x * blockDim.x + threadIdx.x;
    if (idx >= N_V * SD) return;
    int v = idx / SD, c = idx - v * SD;
    float w0 = LD<F32>(Wf3, c), w1 = LD<F32>(Wf3, SD + c), w2 = LD<F32>(Wf3, 2 * SD + c);
    float P = LD<F32>(pos, v * 3 + 0) * w0 + LD<F32>(pos, v * 3 + 1) * w1
            + LD<F32>(pos, v * 3 + 2) * w2;
    float D = dx[v * 3 + 0] * w0 + dx[v * 3 + 1] * w1 + dx[v * 3 + 2] * w2;
    ua[idx] += P;
    bbag[idx] = D - P;
}

template<bool F32>
__global__ void k_cls(const float* __restrict__ hc, const void* __restrict__ W,
                      const void* __restrict__ b, void* __restrict__ out,
                      const int* __restrict__ flag) {
    if ((flag[0] != 0) != F32) return;
    int v = blockIdx.x * blockDim.x + threadIdx.x;
    if (v >= N_V) return;
    float acc[4];
#pragma unroll
    for (int j = 0; j < 4; j++) acc[j] = LD<F32>(b, j);
    for (int k = 0; k < 64; k++) {
        float h = hc[(size_t)v * 64 + k];
#pragma unroll
        for (int j = 0; j < 4; j++) acc[j] += h * LD<F32>(W, k * 4 + j);
    }
#pragma unroll
    for (int j = 0; j < 4; j++) ST<F32>(out, v * 4 + j, fmaxf(acc[j], 0.f));
}

template<bool F32>
__global__ void k_loc3(const float* __restrict__ h2, const void* __restrict__ W,
                       const void* __restrict__ b, void* __restrict__ out, int cls,
                       const int* __restrict__ flag) {
    if ((flag[0] != 0) != F32) return;
    int v = blockIdx.x * blockDim.x + threadIdx.x;
    if (v >= N_V) return;
    float acc[7];
#pragma unroll
    for (int j = 0; j < 7; j++) acc[j] = LD<F32>(b, j);
    for (int k = 0; k < 64; k++) {
        float h = h2[(size_t)v * 64 + k];
#pragma unroll
        for (int j = 0; j < 7; j++) acc[j] += h * LD<F32>(W, k * 7 + j);
    }
#pragma unroll
    for (int j = 0; j < 7; j++)
        ST<F32>(out, 80000 + (size_t)v * 28 + cls * 7 + j, fmaxf(acc[j], 0.f));
}

#define LAUNCH2(kname, grid, blk, ...) \
    do { kname<false><<<grid, blk, 0, stream>>>(__VA_ARGS__); \
         kname<true><<<grid, blk, 0, stream>>>(__VA_ARGS__); } while (0)

extern "C" void kernel_launch(void* const* d_in, const int* in_sizes, int n_in,
                              void* d_out, int out_size, void* d_ws, size_t ws_size,
                              hipStream_t stream) {
    const void* kp  = d_in[0];
    const void* pos = d_in[1];
    const int* eidx = (const int*)d_in[3];
    const int* e_src = eidx;
    const int* e_dst = eidx + E_N;
    const void* Wi0 = d_in[4];   const void* bi0 = d_in[5];
    const void* Wi1 = d_in[6];   const void* bi1 = d_in[7];
    const void* Wi2 = d_in[8];   const void* bi2 = d_in[9];
    const void* Wa  = d_in[10];  const void* ba  = d_in[11];
    const char* Wh  = (const char*)d_in[12];  const char* bh = (const char*)d_in[13];
    const char* Wf  = (const char*)d_in[14];  const char* bff = (const char*)d_in[15];
    const char* Wg  = (const char*)d_in[16];  const char* bg = (const char*)d_in[17];
    const void* Wc1 = d_in[18];  const void* bc1 = d_in[19];
    const void* Wc2 = d_in[20];  const void* bc2 = d_in[21];
    const char* Wl1 = (const char*)d_in[22];  const char* bl1 = (const char*)d_in[23];
    const char* Wl2 = (const char*)d_in[24];  const char* bl2 = (const char*)d_in[25];
    const char* Wl3 = (const char*)d_in[26];  const char* bl3 = (const char*)d_in[27];

    char* ws = (char*)d_ws;
    // region A (24MB): kpmax/ua -> hc(z0)+hl1m(z1..4, spills 1.6MB into dead bbag)
    float* regA  = (float*)(ws + 0);
    float* kpmax = regA;
    float* ua    = regA;
    float* hc    = regA;                      // head z=0
    float* hl1m  = regA + 1280000;            // head z=1..4
    float* hl1f  = (float*)(ws + 6000000);    // fallback
    float* hl2f  = (float*)(ws + 12000000);   // fallback
    // region B (24MB): bbag (GNN; dead at head time)
    float* bbag  = (float*)(ws + 24000000);
    // region C (24MB): s (GNN; dead after head GEMM1) -> hl2m
    float* s     = (float*)(ws + 48000000);
    float* hl2m  = (float*)(ws + 48000000);
    // small stuff
    int*   cnt   = (int*)(ws + 72000000);
    int*   offs  = (int*)(ws + 72100000);
    int*   cur   = (int*)(ws + 72200000);
    int*   esrc  = (int*)(ws + 72300000);
    float* dx    = (float*)(ws + 73600000);   // fallback-path only
    float* wf3F  = (float*)(ws + 73844000);   // wf3(2700) | whT(2880) | bh(9)
    int*   flag  = (int*)(ws + 73900000);
    // MFMA-path extras
    unsigned short* SPLIT = (unsigned short*)(ws + 73950000); // 3.53 MB
    float* biasF = (float*)(ws + 77481000);                   // 12.4 KB
    // total footprint < 77.5 MB

    bool mf = (ws_size == 0) || (ws_size >= (size_t)77500000);
    auto HI = [&](long long cum) { return SPLIT + 2 * cum; };
    float* whTF = wf3F + 2700;
    float* bhF  = wf3F + 5580;

    // ----- zero cnt + dtype detect (merged) -----
    k_detz<<<80, 256, 0, stream>>>((const unsigned*)Wi0, flag, cnt);

    // ----- CSR: hist, scan, then scatter (+ weight prep merged) -----
    k_hist<<<(E_N + 255) / 256, 256, 0, stream>>>(e_dst, cnt);
    k_scan<<<1, 1024, 0, stream>>>(cnt, offs, cur);
    {
        int grid = SCAT_BLOCKS + (mf ? PREP_BLOCKS : 0);
        k_scprep<<<grid, 256, 0, stream>>>(
            e_src, e_dst, cur, esrc,
            Wa, Wf, Wg, Wc1, Wl1, Wl2, Wi1, Wi2, Wh, bh,
            ba, bff, bg, bc1, bl1, bl2, bi1, bi2,
            SPLIT, biasF, wf3F, bbag, flag);
    }

    // ----- init MLP + segmax -----
    if (mf) {
        const unsigned short* W1T = SPLIT + 2LL * 835584;
        const unsigned short* W2T = SPLIT + 2LL * 843776;
        k_init_mfma<<<M_KP / 64, 256, 0, stream>>>(kp, Wi0, bi0, W1T, W2T,
                                                   biasF + 2676, biasF + 2804,
                                                   kpmax, flag);
    } else {
        LAUNCH2(k_init_fused, M_KP / 64, 256, kp, Wi0, bi0, Wi1, bi1, Wi2, bi2, kpmax, flag);
    }

    const dim3 GSD(5, (N_V + 127) / 128);   // N=300 x 128-row blocks
    if (mf) {
        k_gemm_mfma<<<GSD, 256, 0, stream>>>(kpmax, HI(0), HI(0) + 102400,
                                             biasF, nullptr, s, N_V, SD, 320, SD, 1,
                                             0, 0, 0, 0,
                                             nullptr, nullptr, nullptr, nullptr,
                                             nullptr, flag);
    } else {
        dim3 g((SD + 63) / 64, (N_V + 63) / 64);
        LAUNCH2(k_gemm, g, 256, kpmax, Wa, ba, nullptr, s, N_V, SD, SD, 1, flag);
    }

    // ----- GNN iterations -----
    for (int t = 0; t < T_IT; t++) {
        dim3 g5((SD + 63) / 64, (N_V + 63) / 64);
        if (mf) {
            long long cum = (long long)(1 + t) * 102400;
            // ua = s@WfS + bf + pos@Wf3 ; dx = s@WhT + bh (in-kernel);
            // bbag = dx@Wf3 - pos@Wf3 (fully fused)
            k_gemm_mfma<<<GSD, 256, 0, stream>>>(s, HI(cum), HI(cum) + 102400,
                                                 biasF + 300 + t * 300, nullptr, ua,
                                                 N_V, SD, 320, SD, 0, 0, 0, 0, 0,
                                                 pos, whTF + t * 960, wf3F + t * 900,
                                                 bhF + t * 3, bbag, flag);
        } else {
            for (int f32v = 0; f32v < 2; f32v++) {
                size_t es = f32v ? 4 : 2;
                const void* Wf_t = Wf + (size_t)t * 303 * SD * es;
                const void* WfS  = Wf + ((size_t)t * 303 + 3) * SD * es;
                const void* bf_t = bff + (size_t)t * SD * es;
                const void* Wh_t = Wh + (size_t)t * SD * 3 * es;
                const void* bh_t = bh + (size_t)t * 3 * es;
                if (f32v) {
                    k_gemm<true><<<g5, 256, 0, stream>>>(s, WfS, bf_t, nullptr, ua, N_V, SD, SD, 0, flag);
                    k_dx<true><<<(N_V + 3) / 4, 256, 0, stream>>>(s, Wh_t, bh_t, dx, flag);
                    k_ab<true><<<(N_V * SD + 255) / 256, 256, 0, stream>>>(dx, pos, Wf_t, ua, bbag, flag);
                } else {
                    k_gemm<false><<<g5, 256, 0, stream>>>(s, WfS, bf_t, nullptr, ua, N_V, SD, SD, 0, flag);
                    k_dx<false><<<(N_V + 3) / 4, 256, 0, stream>>>(s, Wh_t, bh_t, dx, flag);
                    k_ab<false><<<(N_V * SD + 255) / 256, 256, 0, stream>>>(dx, pos, Wf_t, ua, bbag, flag);
                }
            }
        }
        k_aggr<<<(N_V + 3) / 4, 256, 0, stream>>>(ua, bbag, offs, esrc);
        if (mf) {
            long long cum = (long long)(4 + t) * 102400;
            k_gemm_mfma<<<GSD, 256, 0, stream>>>(bbag, HI(cum), HI(cum) + 102400,
                                                 biasF + 1200 + t * 300, s, s,
                                                 N_V, SD, 320, SD, 0, 0, 0, 0, 0,
                                                 nullptr, nullptr, nullptr, nullptr,
                                                 nullptr, flag);
        } else {
            for (int f32v = 0; f32v < 2; f32v++) {
                size_t es = f32v ? 4 : 2;
                const void* Wg_t = Wg + (size_t)t * SD * SD * es;
                const void* bg_t = bg + (size_t)t * SD * es;
                if (f32v)
                    k_gemm<true><<<g5, 256, 0, stream>>>(bbag, Wg_t, bg_t, s, s, N_V, SD, SD, 0, flag);
                else
                    k_gemm<false><<<g5, 256, 0, stream>>>(bbag, Wg_t, bg_t, s, s, N_V, SD, SD, 0, flag);
            }
        }
    }

    // ----- heads -----
    if (mf) {
        // z=0: Wc1 -> hc ; z=1..4: Wl1[c] -> hl1m  (split buffers contiguous)
        dim3 gz15(1, (N_V + 127) / 128, 5);
        k_gemm_mfma<<<gz15, 256, 0, stream>>>(s, HI(716800), HI(716800) + 20480,
                                              biasF + 2100, nullptr, regA,
                                              N_V, SD, 320, 64, 1,
                                              0, 40960, 64, 1280000,
                                              nullptr, nullptr, nullptr, nullptr,
                                              nullptr, flag);
        // loc layer2 batched: hl1m -> hl2m (region C; s now dead)
        dim3 gz14(1, (N_V + 127) / 128, 4);
        k_gemm_mfma<<<gz14, 256, 0, stream>>>(hl1m, HI(819200), HI(819200) + 4096,
                                              biasF + 2420, nullptr, hl2m,
                                              N_V, 64, 64, 64, 1,
                                              1280000, 8192, 64, 1280000,
                                              nullptr, nullptr, nullptr, nullptr,
                                              nullptr, flag);
        // merged cls (y=4) + loc layer3 (y=0..3)
        dim3 gho((N_V + 255) / 256, 5);
        k_headout<<<gho, 256, 0, stream>>>(hc, hl2m, Wc2, bc2, Wl3, bl3, d_out, flag);
    } else {
        dim3 g(1, (N_V + 63) / 64);
        LAUNCH2(k_gemm, g, 256, s, Wc1, bc1, nullptr, hl1f, N_V, SD, 64, 1, flag);
        LAUNCH2(k_cls, (N_V + 255) / 256, 256, hl1f, Wc2, bc2, d_out, flag);
        for (int c = 0; c < 4; c++) {
            for (int f32v = 0; f32v < 2; f32v++) {
                size_t es = f32v ? 4 : 2;
                const void* Wl1c = Wl1 + (size_t)c * SD * 64 * es;
                const void* bl1c = bl1 + (size_t)c * 64 * es;
                const void* Wl2c = Wl2 + (size_t)c * 64 * 64 * es;
                const void* bl2c = bl2 + (size_t)c * 64 * es;
                const void* Wl3c = Wl3 + (size_t)c * 64 * 7 * es;
                const void* bl3c = bl3 + (size_t)c * 7 * es;
                if (f32v) {
                    k_gemm<true><<<g, 256, 0, stream>>>(s, Wl1c, bl1c, nullptr, hl1f, N_V, SD, 64, 1, flag);
                    k_gemm<true><<<g, 256, 0, stream>>>(hl1f, Wl2c, bl2c, nullptr, hl2f, N_V, 64, 64, 1, flag);
                    k_loc3<true><<<(N_V + 255) / 256, 256, 0, stream>>>(hl2f, Wl3c, bl3c, d_out, c, flag);
                } else {
                    k_gemm<false><<<g, 256, 0, stream>>>(s, Wl1c, bl1c, nullptr, hl1f, N_V, SD, 64, 1, flag);
                    k_gemm<false><<<g, 256, 0, stream>>>(hl1f, Wl2c, bl2c, nullptr, hl2f, N_V, 64, 64, 1, flag);
                    k_loc3<false><<<(N_V + 255) / 256, 256, 0, stream>>>(hl2f, Wl3c, bl3c, d_out, c, flag);
                }
            }
        }
    }
}

// Round 12
// 1057.097 us; speedup vs baseline: 1.1257x; 1.0682x over previous
//
#include <hip/hip_runtime.h>
#include <stdint.h>

#define N_V   20000
#define M_KP  160000
#define E_N   320000
#define SD    300
#define T_IT  3

typedef unsigned short bf16_t;
typedef __attribute__((ext_vector_type(8))) short short8_t;
typedef __attribute__((ext_vector_type(4))) float float4_t;

__device__ __forceinline__ float bf2f(bf16_t u) {
    return __uint_as_float(((unsigned)u) << 16);
}
__device__ __forceinline__ bf16_t f2bf(float f) {
    unsigned u = __float_as_uint(f);
    unsigned r = (u + 0x7FFFu + ((u >> 16) & 1u)) >> 16;
    return (bf16_t)r;
}

template<bool F32>
__device__ __forceinline__ float LD(const void* p, size_t i) {
    if (F32) return ((const float*)p)[i];
    return bf2f(((const bf16_t*)p)[i]);
}
template<bool F32>
__device__ __forceinline__ void ST(void* p, size_t i, float v) {
    if (F32) ((float*)p)[i] = v;
    else     ((bf16_t*)p)[i] = f2bf(v);
}
__device__ __forceinline__ float LDr(const void* p, long long i, bool f32) {
    return f32 ? ((const float*)p)[i] : bf2f(((const bf16_t*)p)[i]);
}
__device__ __forceinline__ void STr(void* p, size_t i, float v, bool f32) {
    if (f32) ((float*)p)[i] = v;
    else     ((bf16_t*)p)[i] = f2bf(v);
}

// ---------- merged: zero cnt + dtype detect (flag=1 if f32, 0 if bf16) ----------
__global__ __launch_bounds__(256) void k_detz(const unsigned* __restrict__ w,
                                              int* __restrict__ flag,
                                              int* __restrict__ cnt) {
    if (blockIdx.x < 79) {
        int i = blockIdx.x * 256 + threadIdx.x;
        if (i < N_V) cnt[i] = 0;
        return;
    }
    __shared__ int cnt_s;
    if (threadIdx.x == 0) cnt_s = 0;
    __syncthreads();
    if (threadIdx.x < 128) {
        unsigned u = w[threadIdx.x];      // 128 dwords = 512B, safe for either dtype
        unsigned lo = u & 0xFFFFu;
        int e = (lo >> 7) & 0xFF;
        int plaus = (lo == 0u) || (e >= 96 && e <= 126);
        atomicAdd(&cnt_s, plaus);
    }
    __syncthreads();
    if (threadIdx.x == 0) flag[0] = (cnt_s >= 64) ? 0 : 1;
}

__global__ void k_hist(const int* __restrict__ dst, int* __restrict__ cnt) {
    int e = blockIdx.x * blockDim.x + threadIdx.x;
    if (e < E_N) atomicAdd(&cnt[dst[e]], 1);
}

// ---------- fast single-block scan: 20 elems/thread, 3 phases ----------
__global__ __launch_bounds__(1024) void k_scan(const int* __restrict__ cnt,
                                               int* __restrict__ offs,
                                               int* __restrict__ cur) {
    __shared__ int sums[1024];
    int tid = threadIdx.x;
    int base = tid * 20;
    int vals[20];
    int s = 0;
#pragma unroll
    for (int j = 0; j < 20; j++) {
        int i = base + j;
        int v = (i < N_V) ? cnt[i] : 0;
        vals[j] = v;
        s += v;
    }
    sums[tid] = s;
    __syncthreads();
    for (int off = 1; off < 1024; off <<= 1) {
        int t = (tid >= off) ? sums[tid - off] : 0;
        __syncthreads();
        sums[tid] += t;
        __syncthreads();
    }
    int run = (tid == 0) ? 0 : sums[tid - 1];
    if (tid == 0) offs[0] = 0;
#pragma unroll
    for (int j = 0; j < 20; j++) {
        int i = base + j;
        if (i < N_V) {
            cur[i] = run;
            run += vals[j];
            offs[i + 1] = run;
        }
    }
}

// ---------- weight prep layout ----------
// Split matrices: m0 Wa 320x320 cum 0 | m1-3 WfS[t] | m4-6 Wg[t]
//   m7 Wc1 64x320 cum 716800 | m8-11 Wl1[c] | m12-15 Wl2[c] cum 819200
//   m16 Wi1 128x64 cum 835584 | m17 Wi2 304x128 cum 843776
// biasF: [0,300) ba | [300,1200) bf | [1200,2100) bg | [2100,2164) bc1
//      | [2164,2420) bl1 | [2420,2676) bl2 | [2676,2804) bi1 | [2804,3104) bi2
// wf3F: 3 x [3][300] rows 0..2 of Wf[t]
// whTF (at wf3F+2700): 3 x [3][320] Wh[t] transposed, zero-padded
// bhF  (at wf3F+5580): 3 x [3] bh[t]
#define PREP_SPLIT 882688
#define PREP_BIAS  3104
#define PREP_WF3   2700
#define PREP_WHT   2880
#define PREP_BH    9
#define PREP_TOT   (PREP_SPLIT + PREP_BIAS + PREP_WF3 + PREP_WHT + PREP_BH + 32)
#define SCAT_BLOCKS 1250
#define PREP_BLOCKS ((PREP_TOT + 255) / 256)

// ---------- merged: edge scatter + weight prep ----------
__global__ __launch_bounds__(256) void k_scprep(
    const int* __restrict__ src, const int* __restrict__ dst,
    int* __restrict__ cur, int* __restrict__ esrc,
    const void* __restrict__ Wa, const void* __restrict__ Wf,
    const void* __restrict__ Wg, const void* __restrict__ Wc1,
    const void* __restrict__ Wl1, const void* __restrict__ Wl2,
    const void* __restrict__ Wi1, const void* __restrict__ Wi2,
    const void* __restrict__ Whw, const void* __restrict__ bhw,
    const void* __restrict__ ba, const void* __restrict__ bfb,
    const void* __restrict__ bgb, const void* __restrict__ bc1,
    const void* __restrict__ bl1b, const void* __restrict__ bl2b,
    const void* __restrict__ bi1, const void* __restrict__ bi2,
    unsigned short* __restrict__ SP, float* __restrict__ biasF,
    float* __restrict__ wf3F, float* __restrict__ bzero,
    const int* __restrict__ flag)
{
    if (blockIdx.x < SCAT_BLOCKS) {
        int e = blockIdx.x * 256 + threadIdx.x;
        if (e < E_N) {
            int p = atomicAdd(&cur[dst[e]], 1);
            esrc[p] = src[e];
        }
        return;
    }
    int idx = (blockIdx.x - SCAT_BLOCKS) * 256 + threadIdx.x;
    if (idx >= PREP_TOT) return;
    bool f32 = flag[0] != 0;
    if (idx < PREP_SPLIT) {
        const void* srcp; long long eoff, cum; int srcN, Nn, Kk, Kpad, pe, local;
        if (idx < 716800) {
            int m = idx / 102400; local = idx - m * 102400;
            pe = 102400; cum = (long long)m * 102400;
            Kpad = 320; Nn = 300; Kk = 300; srcN = 300;
            srcp = (m == 0) ? Wa : (m <= 3 ? Wf : Wg);
            eoff = (m == 0) ? 0 : (m <= 3 ? (long long)((m - 1) * 303 + 3) * 300
                                          : (long long)(m - 4) * 90000);
        } else if (idx < 819200) {
            int j = (idx - 716800) / 20480; local = (idx - 716800) - j * 20480;
            pe = 20480; cum = 716800 + (long long)j * 20480;
            Kpad = 320; Nn = 64; Kk = 300; srcN = 64;
            srcp = (j == 0) ? Wc1 : Wl1;
            eoff = (j == 0) ? 0 : (long long)(j - 1) * 19200;
        } else if (idx < 835584) {
            int c = (idx - 819200) / 4096; local = (idx - 819200) - c * 4096;
            pe = 4096; cum = 819200 + (long long)c * 4096;
            Kpad = 64; Nn = 64; Kk = 64; srcN = 64;
            srcp = Wl2; eoff = (long long)c * 4096;
        } else if (idx < 843776) {
            local = idx - 835584;
            pe = 8192; cum = 835584;
            Kpad = 64; Nn = 128; Kk = 64; srcN = 128;
            srcp = Wi1; eoff = 0;
        } else {
            local = idx - 843776;
            pe = 38912; cum = 843776;
            Kpad = 128; Nn = 300; Kk = 128; srcN = 300;
            srcp = Wi2; eoff = 0;
        }
        int n = local / Kpad, k = local - n * Kpad;
        float v = 0.f;
        if (n < Nn && k < Kk) v = LDr(srcp, eoff + (long long)k * srcN + n, f32);
        bf16_t hi = f2bf(v);                 // RN split
        bf16_t lo = f2bf(v - bf2f(hi));      // bf16 input -> hi exact, lo = 0
        SP[2 * cum + local] = hi;
        SP[2 * cum + pe + local] = lo;
    } else if (idx < PREP_SPLIT + PREP_BIAS) {
        int b = idx - PREP_SPLIT;
        const void* srcp; int o;
        if (b < 300)       { srcp = ba;   o = b; }
        else if (b < 1200) { srcp = bfb;  o = b - 300; }
        else if (b < 2100) { srcp = bgb;  o = b - 1200; }
        else if (b < 2164) { srcp = bc1;  o = b - 2100; }
        else if (b < 2420) { srcp = bl1b; o = b - 2164; }
        else if (b < 2676) { srcp = bl2b; o = b - 2420; }
        else if (b < 2804) { srcp = bi1;  o = b - 2676; }
        else               { srcp = bi2;  o = b - 2804; }
        biasF[b] = LDr(srcp, o, f32);
    } else if (idx < PREP_SPLIT + PREP_BIAS + PREP_WF3) {
        int b2 = idx - (PREP_SPLIT + PREP_BIAS);
        int t = b2 / 900, rem = b2 - t * 900;
        wf3F[b2] = LDr(Wf, (long long)t * 303 * SD + rem, f32);
    } else if (idx < PREP_SPLIT + PREP_BIAS + PREP_WF3 + PREP_WHT) {
        int b3 = idx - (PREP_SPLIT + PREP_BIAS + PREP_WF3);
        int t = b3 / 960, rem = b3 - t * 960;
        int j = rem / 320, k = rem - j * 320;
        wf3F[2700 + b3] = (k < SD) ? LDr(Whw, (long long)t * SD * 3 + k * 3 + j, f32)
                                   : 0.f;
    } else if (idx < PREP_SPLIT + PREP_BIAS + PREP_WF3 + PREP_WHT + PREP_BH) {
        int b4 = idx - (PREP_SPLIT + PREP_BIAS + PREP_WF3 + PREP_WHT);
        wf3F[5580 + b4] = LDr(bhw, b4, f32);   // bh[t][j]
    } else {
        bzero[idx - (PREP_SPLIT + PREP_BIAS + PREP_WF3 + PREP_WHT + PREP_BH)] = 0.f;
    }
}

// ---------- fused init MLP (fallback VALU path) ----------
template<bool F32>
__global__ __launch_bounds__(256) void k_init_fused(
    const void* __restrict__ kp,
    const void* __restrict__ Wi0, const void* __restrict__ bi0,
    const void* __restrict__ Wi1, const void* __restrict__ bi1,
    const void* __restrict__ Wi2, const void* __restrict__ bi2,
    float* __restrict__ kpmax, const int* __restrict__ flag) {
    if ((flag[0] != 0) != F32) return;
    __shared__ float kps[256];
    __shared__ float h1s[64][64];
    __shared__ float h2s[64 * 128];
    int tid = threadIdx.x;
    int row0 = blockIdx.x * 64;
    kps[tid] = LD<F32>(kp, (size_t)row0 * 4 + tid);
    __syncthreads();
    {
        int c = tid & 63;
        float w0 = LD<F32>(Wi0, c), w1 = LD<F32>(Wi0, 64 + c);
        float w2 = LD<F32>(Wi0, 128 + c), w3 = LD<F32>(Wi0, 192 + c);
        float b0 = LD<F32>(bi0, c);
        int rbase = (tid >> 6) * 16;
#pragma unroll
        for (int rr = 0; rr < 16; rr++) {
            int r = rbase + rr;
            float a = b0 + kps[r * 4] * w0 + kps[r * 4 + 1] * w1
                         + kps[r * 4 + 2] * w2 + kps[r * 4 + 3] * w3;
            h1s[r][c] = fmaxf(a, 0.f);
        }
    }
    __syncthreads();
    {
        int c = tid & 127;
        int rbase = (tid >> 7) * 32;
        float b1 = LD<F32>(bi1, c);
        float acc[32];
#pragma unroll
        for (int rr = 0; rr < 32; rr++) acc[rr] = b1;
        for (int k = 0; k < 64; k++) {
            float wv = LD<F32>(Wi1, (size_t)k * 128 + c);
#pragma unroll
            for (int rr = 0; rr < 32; rr++) acc[rr] += h1s[rbase + rr][k] * wv;
        }
#pragma unroll
        for (int rr = 0; rr < 32; rr++)
            h2s[(size_t)(rbase + rr) * 128 + c] = fmaxf(acc[rr], 0.f);
    }
    __syncthreads();
    {
        int cx = tid & 63, rg = tid >> 6;
        float acc[16][5];
#pragma unroll
        for (int r = 0; r < 16; r++)
#pragma unroll
            for (int j = 0; j < 5; j++) acc[r][j] = 0.f;
        bool ok4 = (cx < SD - 256);
        for (int k = 0; k < 128; k++) {
            float w[5];
#pragma unroll
            for (int j = 0; j < 4; j++) w[j] = LD<F32>(Wi2, (size_t)k * SD + cx + 64 * j);
            w[4] = ok4 ? LD<F32>(Wi2, (size_t)k * SD + cx + 256) : 0.f;
#pragma unroll
            for (int r = 0; r < 16; r++) {
                float av = h2s[(rg * 16 + r) * 128 + k];
#pragma unroll
                for (int j = 0; j < 5; j++) acc[r][j] += av * w[j];
            }
        }
        int vbase = (row0 >> 3) + rg * 2;
#pragma unroll
        for (int half = 0; half < 2; half++) {
            int v = vbase + half;
#pragma unroll
            for (int j = 0; j < 5; j++) {
                int c = cx + 64 * j;
                if (c >= SD) continue;
                float m = acc[half * 8][j];
#pragma unroll
                for (int r = 1; r < 8; r++) m = fmaxf(m, acc[half * 8 + r][j]);
                kpmax[(size_t)v * SD + c] = fmaxf(m + LD<F32>(bi2, c), 0.f);
            }
        }
    }
}

// ---------- generic tiled f32 GEMM (fallback path only) ----------
template<bool F32>
__global__ __launch_bounds__(256) void k_gemm(
    const float* __restrict__ A, const void* __restrict__ W,
    const void* __restrict__ bias, const float* res,
    float* C, int Mr, int K, int Nc, int do_relu, const int* __restrict__ flag) {
    if ((flag[0] != 0) != F32) return;
    __shared__ float As[16][65];
    __shared__ float Ws[16][64];
    int tid = threadIdx.x;
    int tx = tid & 15, ty = tid >> 4;
    int row0 = blockIdx.y * 64, col0 = blockIdx.x * 64;
    float acc[4][4] = {{0.f}};
    int lk = tid & 15, lr = tid >> 4;
    int ln = tid & 63, lk4 = tid >> 6;
    for (int k0 = 0; k0 < K; k0 += 16) {
#pragma unroll
        for (int i = 0; i < 4; i++) {
            int r = lr + i * 16;
            int gr = row0 + r, gk = k0 + lk;
            As[lk][r] = (gr < Mr && gk < K) ? A[(size_t)gr * K + gk] : 0.f;
        }
#pragma unroll
        for (int p = 0; p < 4; p++) {
            int kk = lk4 + p * 4;
            int gk = k0 + kk, gn = col0 + ln;
            Ws[kk][ln] = (gk < K && gn < Nc) ? LD<F32>(W, (size_t)gk * Nc + gn) : 0.f;
        }
        __syncthreads();
#pragma unroll
        for (int kk = 0; kk < 16; kk++) {
            float a[4], w[4];
#pragma unroll
            for (int i = 0; i < 4; i++) a[i] = As[kk][ty * 4 + i];
#pragma unroll
            for (int j = 0; j < 4; j++) w[j] = Ws[kk][tx * 4 + j];
#pragma unroll
            for (int i = 0; i < 4; i++)
#pragma unroll
                for (int j = 0; j < 4; j++) acc[i][j] += a[i] * w[j];
        }
        __syncthreads();
    }
#pragma unroll
    for (int i = 0; i < 4; i++) {
        int gr = row0 + ty * 4 + i;
        if (gr >= Mr) continue;
#pragma unroll
        for (int j = 0; j < 4; j++) {
            int gn = col0 + tx * 4 + j;
            if (gn >= Nc) continue;
            float c = acc[i][j] + LD<F32>(bias, gn);
            if (res) c += res[(size_t)gr * Nc + gn];
            if (do_relu) c = fmaxf(c, 0.f);
            C[(size_t)gr * Nc + gn] = c;
        }
    }
}

// ---------- MFMA helpers ----------
__device__ __forceinline__ void mfma16(float4_t& c, short8_t a, short8_t b) {
    asm("v_mfma_f32_16x16x32_bf16 %0, %1, %2, %0" : "+v"(c) : "v"(a), "v"(b));
}
__device__ __forceinline__ void split2(float a, float b, unsigned& h, unsigned& l) {
    asm("v_cvt_pk_bf16_f32 %0, %1, %2" : "=v"(h) : "v"(a), "v"(b));
    float la = a - __uint_as_float(h << 16);
    float lb = b - __uint_as_float(h & 0xFFFF0000u);
    asm("v_cvt_pk_bf16_f32 %0, %1, %2" : "=v"(l) : "v"(la), "v"(lb));
}
__device__ __forceinline__ void split8(float4_t x0, float4_t x1,
                                       short8_t* hi, short8_t* lo) {
    union { unsigned u[4]; short8_t v; } H, L;
#pragma unroll
    for (int p = 0; p < 4; p++) {
        float a, b;
        if (p == 0)      { a = x0[0]; b = x0[1]; }
        else if (p == 1) { a = x0[2]; b = x0[3]; }
        else if (p == 2) { a = x1[0]; b = x1[1]; }
        else             { a = x1[2]; b = x1[3]; }
        unsigned ph, pl;
        split2(a, b, ph, pl);
        H.u[p] = ph; L.u[p] = pl;
    }
    *hi = H.v; *lo = L.v;
}

// ---------- MFMA init MLP v3 (+ wlo skip) ----------
__global__ __launch_bounds__(256) void k_init_mfma(
    const void* __restrict__ kp,
    const void* __restrict__ Wi0, const void* __restrict__ bi0,
    const unsigned short* __restrict__ W1T,   // [128][64], lo at +8192
    const unsigned short* __restrict__ W2T,   // [304][128], lo at +38912
    const float* __restrict__ b1F, const float* __restrict__ b2F,
    float* __restrict__ kpmax, const int* __restrict__ flag)
{
    bool f32 = flag[0] != 0;
    bool wlo = f32;
    __shared__ __attribute__((aligned(16))) unsigned short lds[2][8704]; // 34,816 B
    int tid = threadIdx.x;
    int w = tid >> 6, lane = tid & 63;
    int rg = w >> 1, ch = w & 1;
    int l15 = lane & 15, g = lane >> 4;
    unsigned short* h2h = lds[rg];
    unsigned short* h2l = lds[rg] + 4352;
    int rw0 = blockIdx.x * 64 + rg * 32;

    float kpr[2][4];
#pragma unroll
    for (int mt = 0; mt < 2; mt++) {
        long long r = rw0 + mt * 16 + l15;
#pragma unroll
        for (int j = 0; j < 4; j++) kpr[mt][j] = LDr(kp, r * 4 + j, f32);
    }
    short8_t a1h[2][2], a1l[2][2];
#pragma unroll
    for (int ks = 0; ks < 2; ks++) {
        float h[2][8];
#pragma unroll
        for (int e = 0; e < 8; e++) {
            int chn = ks * 32 + 8 * g + e;
            float w0 = LDr(Wi0, chn, f32),       w1 = LDr(Wi0, 64 + chn, f32);
            float w2 = LDr(Wi0, 128 + chn, f32), w3 = LDr(Wi0, 192 + chn, f32);
            float b0 = LDr(bi0, chn, f32);
#pragma unroll
            for (int mt = 0; mt < 2; mt++)
                h[mt][e] = fmaxf(b0 + kpr[mt][0] * w0 + kpr[mt][1] * w1
                                    + kpr[mt][2] * w2 + kpr[mt][3] * w3, 0.f);
        }
#pragma unroll
        for (int mt = 0; mt < 2; mt++) {
            union { unsigned u[4]; short8_t v; } H, L;
#pragma unroll
            for (int p = 0; p < 4; p++) {
                unsigned hh, ll;
                split2(h[mt][2 * p], h[mt][2 * p + 1], hh, ll);
                H.u[p] = hh; L.u[p] = ll;
            }
            a1h[mt][ks] = H.v; a1l[mt][ks] = L.v;
        }
    }

#pragma unroll
    for (int i = 0; i < 4; i++) {
        int n0 = ch * 4 + i;
        const unsigned short* bp = W1T + (n0 * 16 + l15) * 64 + 8 * g;
        short8_t bh0 = *(const short8_t*)bp;
        short8_t bh1 = *(const short8_t*)(bp + 32);
        float4_t c0 = {0.f, 0.f, 0.f, 0.f}, c1 = {0.f, 0.f, 0.f, 0.f};
        mfma16(c0, a1h[0][0], bh0); mfma16(c0, a1h[0][1], bh1);
        mfma16(c0, a1l[0][0], bh0); mfma16(c0, a1l[0][1], bh1);
        mfma16(c1, a1h[1][0], bh0); mfma16(c1, a1h[1][1], bh1);
        mfma16(c1, a1l[1][0], bh0); mfma16(c1, a1l[1][1], bh1);
        if (wlo) {
            short8_t bl0 = *(const short8_t*)(bp + 8192);
            short8_t bl1 = *(const short8_t*)(bp + 8224);
            mfma16(c0, a1h[0][0], bl0); mfma16(c0, a1h[0][1], bl1);
            mfma16(c1, a1h[1][0], bl0); mfma16(c1, a1h[1][1], bl1);
        }
        int col = n0 * 16 + l15;
        float bv = b1F[col];
#pragma unroll
        for (int i2 = 0; i2 < 4; i2++) {
            float v0 = fmaxf(c0[i2] + bv, 0.f);
            bf16_t h0 = f2bf(v0);
            h2h[(4 * g + i2) * 136 + col] = h0;
            h2l[(4 * g + i2) * 136 + col] = f2bf(v0 - bf2f(h0));
            float v1 = fmaxf(c1[i2] + bv, 0.f);
            bf16_t h1v = f2bf(v1);
            h2h[(16 + 4 * g + i2) * 136 + col] = h1v;
            h2l[(16 + 4 * g + i2) * 136 + col] = f2bf(v1 - bf2f(h1v));
        }
    }
    __syncthreads();

    short8_t a2h[2][4], a2l[2][4];
#pragma unroll
    for (int mt = 0; mt < 2; mt++)
#pragma unroll
        for (int ks = 0; ks < 4; ks++) {
            int off = (mt * 16 + l15) * 136 + ks * 32 + 8 * g;
            a2h[mt][ks] = *(const short8_t*)(h2h + off);
            a2l[mt][ks] = *(const short8_t*)(h2l + off);
        }
    int vb = blockIdx.x * 8 + rg * 4;
    int n0beg = ch ? 10 : 0, n0end = ch ? 19 : 10;
    for (int n0 = n0beg; n0 < n0end; n0++) {
        const unsigned short* bp = W2T + (n0 * 16 + l15) * 128 + 8 * g;
        short8_t bh[4];
#pragma unroll
        for (int ks = 0; ks < 4; ks++) bh[ks] = *(const short8_t*)(bp + ks * 32);
        float4_t c0 = {0.f, 0.f, 0.f, 0.f}, c1 = {0.f, 0.f, 0.f, 0.f};
#pragma unroll
        for (int ks = 0; ks < 4; ks++) {
            mfma16(c0, a2h[0][ks], bh[ks]); mfma16(c1, a2h[1][ks], bh[ks]);
        }
#pragma unroll
        for (int ks = 0; ks < 4; ks++) {
            mfma16(c0, a2l[0][ks], bh[ks]); mfma16(c1, a2l[1][ks], bh[ks]);
        }
        if (wlo) {
            short8_t bl[4];
#pragma unroll
            for (int ks = 0; ks < 4; ks++)
                bl[ks] = *(const short8_t*)(bp + 38912 + ks * 32);
#pragma unroll
            for (int ks = 0; ks < 4; ks++) {
                mfma16(c0, a2h[0][ks], bl[ks]); mfma16(c1, a2h[1][ks], bl[ks]);
            }
        }
        float m0 = fmaxf(fmaxf(c0[0], c0[1]), fmaxf(c0[2], c0[3]));
        m0 = fmaxf(m0, __shfl_xor(m0, 16));
        float m1 = fmaxf(fmaxf(c1[0], c1[1]), fmaxf(c1[2], c1[3]));
        m1 = fmaxf(m1, __shfl_xor(m1, 16));
        int col = n0 * 16 + l15;
        if (col < SD) {
            float bv = b2F[col];
            if (g == 0) {
                kpmax[(size_t)(vb + 0) * SD + col] = fmaxf(m0 + bv, 0.f);
                kpmax[(size_t)(vb + 2) * SD + col] = fmaxf(m1 + bv, 0.f);
            } else if (g == 2) {
                kpmax[(size_t)(vb + 1) * SD + col] = fmaxf(m0 + bv, 0.f);
                kpmax[(size_t)(vb + 3) * SD + col] = fmaxf(m1 + bv, 0.f);
            }
        }
    }
}

// ---------- split-bf16 MFMA GEMM v4: XCD-swizzle + fused dx + AB epilogue ----------
// If swz: grid is (NX, 8*ceil(NY/8)); bid-swizzle puts all NX col-tiles of a
//   row-panel on ONE XCD (A/res fetched once per XCD instead of NX times).
//   If xisz: the decoded x slot is the z-batch index (col-tiles = 1).
// (K+31)/32 must be EVEN. If posp != null: dx computed in-kernel; C = A@W +
//   bias + pos@Wf3; bbag = dx@Wf3 - pos@Wf3.
__global__ __launch_bounds__(256) void k_gemm_mfma(
    const float* __restrict__ A, const unsigned short* __restrict__ WhiT,
    const unsigned short* __restrict__ WloT, const float* __restrict__ bias,
    const float* __restrict__ res, float* __restrict__ C,
    int M, int K, int Kpad, int N, int relu, int swz, int xisz,
    long long zA, long long zW, int zB, long long zC,
    const void* posp, const float* whTF, const float* wf3F,
    const float* bhF, float* bbag, const int* __restrict__ flag)
{
    int xx, yy, z;
    if (swz) {
        int nx = gridDim.x;
        int bid = blockIdx.y * nx + blockIdx.x;
        int r = bid & 7, idx = bid >> 3;
        int q = idx / nx;
        yy = r + 8 * q;
        xx = idx - q * nx;
        z = xisz ? xx : blockIdx.z;
        if (xisz) xx = 0;
        if (yy * 128 >= M) return;
    } else {
        xx = blockIdx.x; yy = blockIdx.y; z = blockIdx.z;
    }
    bool wlo = flag[0] != 0;   // weight-lo nonzero only in f32 mode
    A    += (size_t)z * zA;
    WhiT += (size_t)z * zW;
    WloT += (size_t)z * zW;
    bias += (size_t)z * zB;
    C    += (size_t)z * zC;
    int tid = threadIdx.x;
    int w = tid >> 6, lane = tid & 63;
    int l15 = lane & 15, g = lane >> 4;
    int row0 = yy * 128 + w * 32;   // wave owns 32 rows
    int col0 = xx * 64;
    bool ab = posp != nullptr;

    __shared__ float dxs[4][2][16][3];

    float4_t acc[2][4];
#pragma unroll
    for (int i = 0; i < 2; i++)
#pragma unroll
        for (int j = 0; j < 4; j++) acc[i][j] = (float4_t){0.f, 0.f, 0.f, 0.f};
    float dxp[2][3] = {{0.f, 0.f, 0.f}, {0.f, 0.f, 0.f}};

    const unsigned short* bhp[4];
    const unsigned short* blp[4];
#pragma unroll
    for (int ns = 0; ns < 4; ns++) {
        size_t o = (size_t)(col0 + ns * 16 + l15) * Kpad + 8 * g;
        bhp[ns] = WhiT + o; blp[ns] = WloT + o;
    }
    const float* app[2];
    int amode[2]; bool adead[2];
#pragma unroll
    for (int ms = 0; ms < 2; ms++) {
        int base = row0 + ms * 16;
        int gr = base + l15;
        amode[ms] = (base + 16 <= M) ? 2 : (base < M ? 1 : 0);
        adead[ms] = gr >= M;
        int grc = gr < M ? gr : (M - 1);
        app[ms] = A + (size_t)grc * K + 8 * g;
    }
    const float4_t zf4 = {0.f, 0.f, 0.f, 0.f};
    const short8_t z8 = {0, 0, 0, 0, 0, 0, 0, 0};

    auto LOADB = [&](short8_t* bh, short8_t* bl) {
#pragma unroll
        for (int ns = 0; ns < 4; ns++) {
            bh[ns] = *(const short8_t*)bhp[ns];
            bl[ns] = wlo ? *(const short8_t*)blp[ns] : z8;
            bhp[ns] += 32; blp[ns] += 32;
        }
    };
    auto LOADA = [&](float4_t* x0, float4_t* x1) {
#pragma unroll
        for (int ms = 0; ms < 2; ms++) {
            if (amode[ms] == 0) { x0[ms] = zf4; x1[ms] = zf4; }
            else {
                x0[ms] = *(const float4_t*)app[ms];
                x1[ms] = *(const float4_t*)(app[ms] + 4);
                if (amode[ms] == 1 && adead[ms]) { x0[ms] = zf4; x1[ms] = zf4; }
            }
            app[ms] += 32;
        }
    };
    auto COMPUTE = [&](const short8_t* bh, const short8_t* bl,
                       const float4_t* x0, const float4_t* x1, int kbase) {
        if (ab) {
#pragma unroll
            for (int j = 0; j < 3; j++) {
                float4_t wa = *(const float4_t*)(whTF + j * 320 + kbase + 8 * g);
                float4_t wb = *(const float4_t*)(whTF + j * 320 + kbase + 8 * g + 4);
#pragma unroll
                for (int ms = 0; ms < 2; ms++) {
                    dxp[ms][j] += x0[ms][0] * wa[0] + x0[ms][1] * wa[1]
                                + x0[ms][2] * wa[2] + x0[ms][3] * wa[3]
                                + x1[ms][0] * wb[0] + x1[ms][1] * wb[1]
                                + x1[ms][2] * wb[2] + x1[ms][3] * wb[3];
                }
            }
        }
#pragma unroll
        for (int ms = 0; ms < 2; ms++) {
            short8_t ah, al;
            split8(x0[ms], x1[ms], &ah, &al);
#pragma unroll
            for (int ns = 0; ns < 4; ns++) {
                mfma16(acc[ms][ns], ah, bh[ns]);
                mfma16(acc[ms][ns], al, bh[ns]);
            }
            if (wlo) {
#pragma unroll
                for (int ns = 0; ns < 4; ns++) mfma16(acc[ms][ns], ah, bl[ns]);
            }
        }
    };

    short8_t bhA[4], blA[4], bhB[4], blB[4];
    float4_t x0A[2], x1A[2], x0B[2], x1B[2];
    int iters = (K + 31) / 32;                 // 10 or 2 (even)
    LOADB(bhA, blA); LOADA(x0A, x1A);
    for (int it = 0; it < iters; it += 2) {
        LOADB(bhB, blB); LOADA(x0B, x1B);      // prefetch it+1
        COMPUTE(bhA, blA, x0A, x1A, it * 32);
        if (it + 2 < iters) { LOADB(bhA, blA); LOADA(x0A, x1A); }  // prefetch it+2
        COMPUTE(bhB, blB, x0B, x1B, (it + 1) * 32);
    }

    if (ab) {
        // reduce dx partials over the 4 g-groups (lanes l15+16g share a row)
#pragma unroll
        for (int ms = 0; ms < 2; ms++)
#pragma unroll
            for (int j = 0; j < 3; j++) {
                float p = dxp[ms][j];
                p += __shfl_xor(p, 16);
                p += __shfl_xor(p, 32);
                dxp[ms][j] = p;
            }
        if (g == 0) {
#pragma unroll
            for (int ms = 0; ms < 2; ms++)
#pragma unroll
                for (int j = 0; j < 3; j++) dxs[w][ms][l15][j] = dxp[ms][j];
        }
        __syncthreads();
    }

    bool pf32 = ab && wlo;
    int gnv[4]; float bvv[4], w30v[4], w31v[4], w32v[4];
#pragma unroll
    for (int ns = 0; ns < 4; ns++) {
        int gn = col0 + ns * 16 + l15;
        gnv[ns] = gn;
        bvv[ns] = (gn < N) ? bias[gn] : 0.f;
        if (ab && gn < N) {
            w30v[ns] = wf3F[gn]; w31v[ns] = wf3F[300 + gn]; w32v[ns] = wf3F[600 + gn];
        } else { w30v[ns] = 0.f; w31v[ns] = 0.f; w32v[ns] = 0.f; }
    }
    float bh0 = 0.f, bh1 = 0.f, bh2 = 0.f;
    if (ab) { bh0 = bhF[0]; bh1 = bhF[1]; bh2 = bhF[2]; }
#pragma unroll
    for (int ms = 0; ms < 2; ms++) {
#pragma unroll
        for (int r = 0; r < 4; r++) {
            int gr = row0 + ms * 16 + 4 * g + r;
            if (gr >= M) continue;
            float p0 = 0.f, p1 = 0.f, p2 = 0.f, d0 = 0.f, d1 = 0.f, d2 = 0.f;
            if (ab) {
                p0 = LDr(posp, (long long)gr * 3 + 0, pf32);
                p1 = LDr(posp, (long long)gr * 3 + 1, pf32);
                p2 = LDr(posp, (long long)gr * 3 + 2, pf32);
                int rl = 4 * g + r;
                d0 = dxs[w][ms][rl][0] + bh0;
                d1 = dxs[w][ms][rl][1] + bh1;
                d2 = dxs[w][ms][rl][2] + bh2;
            }
#pragma unroll
            for (int ns = 0; ns < 4; ns++) {
                int gn = gnv[ns];
                if (gn >= N) continue;
                float c = acc[ms][ns][r] + bvv[ns];
                if (ab) {
                    float P = p0 * w30v[ns] + p1 * w31v[ns] + p2 * w32v[ns];
                    float D = d0 * w30v[ns] + d1 * w31v[ns] + d2 * w32v[ns];
                    c += P;
                    bbag[(size_t)gr * N + gn] = D - P;
                }
                if (res) c += res[(size_t)gr * N + gn];
                if (relu) c = fmaxf(c, 0.f);
                C[(size_t)gr * N + gn] = c;
            }
        }
    }
}

__global__ __launch_bounds__(256) void k_aggr(
    const float* __restrict__ a, float* bbag,
    const int* __restrict__ offs, const int* __restrict__ esrc) {
    int wv = threadIdx.x >> 6, lane = threadIdx.x & 63;
    int v = blockIdx.x * 4 + wv;
    if (v >= N_V) return;
    int e0 = offs[v], e1 = offs[v + 1];
    float r0 = -3.0e38f, r1 = r0, r2 = r0, r3 = r0, r4 = r0;
    bool c4 = lane < SD - 256;
    for (int e = e0; e < e1; e++) {
        const float* ar = a + (size_t)esrc[e] * SD + lane;
        r0 = fmaxf(r0, ar[0]);
        r1 = fmaxf(r1, ar[64]);
        r2 = fmaxf(r2, ar[128]);
        r3 = fmaxf(r3, ar[192]);
        if (c4) r4 = fmaxf(r4, ar[256]);
    }
    float* bv = bbag + (size_t)v * SD + lane;
    bv[0]   = fmaxf(0.f, r0 + bv[0]);
    bv[64]  = fmaxf(0.f, r1 + bv[64]);
    bv[128] = fmaxf(0.f, r2 + bv[128]);
    bv[192] = fmaxf(0.f, r3 + bv[192]);
    if (c4) bv[256] = fmaxf(0.f, r4 + bv[256]);
}

// merged heads output: y in [0,4) -> loc3 class y from hl2all; y==4 -> cls from hc
__global__ void k_headout(const float* __restrict__ hc,
                          const float* __restrict__ hl2all,
                          const void* __restrict__ Wc2, const void* __restrict__ bc2,
                          const void* __restrict__ Wl3, const void* __restrict__ bl3,
                          void* __restrict__ out, const int* __restrict__ flag) {
    bool f32 = flag[0] != 0;
    int y = blockIdx.y;
    int v = blockIdx.x * blockDim.x + threadIdx.x;
    if (v >= N_V) return;
    if (y == 4) {
        float acc[4];
#pragma unroll
        for (int j = 0; j < 4; j++) acc[j] = LDr(bc2, j, f32);
        for (int k = 0; k < 64; k++) {
            float h = hc[(size_t)v * 64 + k];
#pragma unroll
            for (int j = 0; j < 4; j++) acc[j] += h * LDr(Wc2, k * 4 + j, f32);
        }
#pragma unroll
        for (int j = 0; j < 4; j++) STr(out, v * 4 + j, fmaxf(acc[j], 0.f), f32);
    } else {
        const float* h2 = hl2all + (size_t)y * N_V * 64;
        long long wo = (long long)y * 64 * 7, bo = (long long)y * 7;
        float acc[7];
#pragma unroll
        for (int j = 0; j < 7; j++) acc[j] = LDr(bl3, bo + j, f32);
        for (int k = 0; k < 64; k++) {
            float h = h2[(size_t)v * 64 + k];
#pragma unroll
            for (int j = 0; j < 7; j++) acc[j] += h * LDr(Wl3, wo + k * 7 + j, f32);
        }
#pragma unroll
        for (int j = 0; j < 7; j++)
            STr(out, 80000 + (size_t)v * 28 + y * 7 + j, fmaxf(acc[j], 0.f), f32);
    }
}

// ---------- fallback-path small kernels ----------
template<bool F32>
__global__ void k_dx(const float* __restrict__ s, const void* __restrict__ Wh,
                     const void* __restrict__ bh, float* __restrict__ dx,
                     const int* __restrict__ flag) {
    if ((flag[0] != 0) != F32) return;
    int wv = threadIdx.x >> 6, lane = threadIdx.x & 63;
    int v = blockIdx.x * 4 + wv;
    if (v >= N_V) return;
    float p0 = 0.f, p1 = 0.f, p2 = 0.f;
    for (int d = lane; d < SD; d += 64) {
        float sv = s[(size_t)v * SD + d];
        p0 += sv * LD<F32>(Wh, d * 3 + 0);
        p1 += sv * LD<F32>(Wh, d * 3 + 1);
        p2 += sv * LD<F32>(Wh, d * 3 + 2);
    }
#pragma unroll
    for (int off = 32; off > 0; off >>= 1) {
        p0 += __shfl_down(p0, off);
        p1 += __shfl_down(p1, off);
        p2 += __shfl_down(p2, off);
    }
    if (lane == 0) {
        dx[v * 3 + 0] = p0 + LD<F32>(bh, 0);
        dx[v * 3 + 1] = p1 + LD<F32>(bh, 1);
        dx[v * 3 + 2] = p2 + LD<F32>(bh, 2);
    }
}

template<bool F32>
__global__ void k_ab(const float* __restrict__ dx, const void* __restrict__ pos,
                     const void* __restrict__ Wf3, float* __restrict__ ua,
                     float* __restrict__ bbag, const int* __restrict__ flag) {
    if ((flag[0] != 0) != F32) return;
    int idx = blockIdx.x * blockDim.x + threadIdx.x;
    if (idx >= N_V * SD) return;
    int v = idx / SD, c = idx - v * SD;
    float w0 = LD<F32>(Wf3, c), w1 = LD<F32>(Wf3, SD + c), w2 = LD<F32>(Wf3, 2 * SD + c);
    float P = LD<F32>(pos, v * 3 + 0) * w0 + LD<F32>(pos, v * 3 + 1) * w1
            + LD<F32>(pos, v * 3 + 2) * w2;
    float D = dx[v * 3 + 0] * w0 + dx[v * 3 + 1] * w1 + dx[v * 3 + 2] * w2;
    ua[idx] += P;
    bbag[idx] = D - P;
}

template<bool F32>
__global__ void k_cls(const float* __restrict__ hc, const void* __restrict__ W,
                      const void* __restrict__ b, void* __restrict__ out,
                      const int* __restrict__ flag) {
    if ((flag[0] != 0) != F32) return;
    int v = blockIdx.x * blockDim.x + threadIdx.x;
    if (v >= N_V) return;
    float acc[4];
#pragma unroll
    for (int j = 0; j < 4; j++) acc[j] = LD<F32>(b, j);
    for (int k = 0; k < 64; k++) {
        float h = hc[(size_t)v * 64 + k];
#pragma unroll
        for (int j = 0; j < 4; j++) acc[j] += h * LD<F32>(W, k * 4 + j);
    }
#pragma unroll
    for (int j = 0; j < 4; j++) ST<F32>(out, v * 4 + j, fmaxf(acc[j], 0.f));
}

template<bool F32>
__global__ void k_loc3(const float* __restrict__ h2, const void* __restrict__ W,
                       const void* __restrict__ b, void* __restrict__ out, int cls,
                       const int* __restrict__ flag) {
    if ((flag[0] != 0) != F32) return;
    int v = blockIdx.x * blockDim.x + threadIdx.x;
    if (v >= N_V) return;
    float acc[7];
#pragma unroll
    for (int j = 0; j < 7; j++) acc[j] = LD<F32>(b, j);
    for (int k = 0; k < 64; k++) {
        float h = h2[(size_t)v * 64 + k];
#pragma unroll
        for (int j = 0; j < 7; j++) acc[j] += h * LD<F32>(W, k * 7 + j);
    }
#pragma unroll
    for (int j = 0; j < 7; j++)
        ST<F32>(out, 80000 + (size_t)v * 28 + cls * 7 + j, fmaxf(acc[j], 0.f));
}

#define LAUNCH2(kname, grid, blk, ...) \
    do { kname<false><<<grid, blk, 0, stream>>>(__VA_ARGS__); \
         kname<true><<<grid, blk, 0, stream>>>(__VA_ARGS__); } while (0)

extern "C" void kernel_launch(void* const* d_in, const int* in_sizes, int n_in,
                              void* d_out, int out_size, void* d_ws, size_t ws_size,
                              hipStream_t stream) {
    const void* kp  = d_in[0];
    const void* pos = d_in[1];
    const int* eidx = (const int*)d_in[3];
    const int* e_src = eidx;
    const int* e_dst = eidx + E_N;
    const void* Wi0 = d_in[4];   const void* bi0 = d_in[5];
    const void* Wi1 = d_in[6];   const void* bi1 = d_in[7];
    const void* Wi2 = d_in[8];   const void* bi2 = d_in[9];
    const void* Wa  = d_in[10];  const void* ba  = d_in[11];
    const char* Wh  = (const char*)d_in[12];  const char* bh = (const char*)d_in[13];
    const char* Wf  = (const char*)d_in[14];  const char* bff = (const char*)d_in[15];
    const char* Wg  = (const char*)d_in[16];  const char* bg = (const char*)d_in[17];
    const void* Wc1 = d_in[18];  const void* bc1 = d_in[19];
    const void* Wc2 = d_in[20];  const void* bc2 = d_in[21];
    const char* Wl1 = (const char*)d_in[22];  const char* bl1 = (const char*)d_in[23];
    const char* Wl2 = (const char*)d_in[24];  const char* bl2 = (const char*)d_in[25];
    const char* Wl3 = (const char*)d_in[26];  const char* bl3 = (const char*)d_in[27];

    char* ws = (char*)d_ws;
    // region A (24MB): kpmax/ua -> hc(z0)+hl1m(z1..4, spills 1.6MB into dead bbag)
    float* regA  = (float*)(ws + 0);
    float* kpmax = regA;
    float* ua    = regA;
    float* hc    = regA;                      // head z=0
    float* hl1m  = regA + 1280000;            // head z=1..4
    float* hl1f  = (float*)(ws + 6000000);    // fallback
    float* hl2f  = (float*)(ws + 12000000);   // fallback
    // region B (24MB): bbag (GNN; dead at head time)
    float* bbag  = (float*)(ws + 24000000);
    // region C (24MB): s (GNN; dead after head GEMM1) -> hl2m
    float* s     = (float*)(ws + 48000000);
    float* hl2m  = (float*)(ws + 48000000);
    // small stuff
    int*   cnt   = (int*)(ws + 72000000);
    int*   offs  = (int*)(ws + 72100000);
    int*   cur   = (int*)(ws + 72200000);
    int*   esrc  = (int*)(ws + 72300000);
    float* dx    = (float*)(ws + 73600000);   // fallback-path only
    float* wf3F  = (float*)(ws + 73844000);   // wf3(2700) | whT(2880) | bh(9)
    int*   flag  = (int*)(ws + 73900000);
    // MFMA-path extras
    unsigned short* SPLIT = (unsigned short*)(ws + 73950000); // 3.53 MB
    float* biasF = (float*)(ws + 77481000);                   // 12.4 KB
    // total footprint < 77.5 MB

    bool mf = (ws_size == 0) || (ws_size >= (size_t)77500000);
    auto HI = [&](long long cum) { return SPLIT + 2 * cum; };
    float* whTF = wf3F + 2700;
    float* bhF  = wf3F + 5580;

    // ----- zero cnt + dtype detect (merged) -----
    k_detz<<<80, 256, 0, stream>>>((const unsigned*)Wi0, flag, cnt);

    // ----- CSR: hist, scan, then scatter (+ weight prep merged) -----
    k_hist<<<(E_N + 255) / 256, 256, 0, stream>>>(e_dst, cnt);
    k_scan<<<1, 1024, 0, stream>>>(cnt, offs, cur);
    {
        int grid = SCAT_BLOCKS + (mf ? PREP_BLOCKS : 0);
        k_scprep<<<grid, 256, 0, stream>>>(
            e_src, e_dst, cur, esrc,
            Wa, Wf, Wg, Wc1, Wl1, Wl2, Wi1, Wi2, Wh, bh,
            ba, bff, bg, bc1, bl1, bl2, bi1, bi2,
            SPLIT, biasF, wf3F, bbag, flag);
    }

    // ----- init MLP + segmax -----
    if (mf) {
        const unsigned short* W1T = SPLIT + 2LL * 835584;
        const unsigned short* W2T = SPLIT + 2LL * 843776;
        k_init_mfma<<<M_KP / 64, 256, 0, stream>>>(kp, Wi0, bi0, W1T, W2T,
                                                   biasF + 2676, biasF + 2804,
                                                   kpmax, flag);
    } else {
        LAUNCH2(k_init_fused, M_KP / 64, 256, kp, Wi0, bi0, Wi1, bi1, Wi2, bi2, kpmax, flag);
    }

    const dim3 GSD(5, 160);   // swizzled: 5 col-tiles x 8*ceil(157/8) row-slots
    if (mf) {
        k_gemm_mfma<<<GSD, 256, 0, stream>>>(kpmax, HI(0), HI(0) + 102400,
                                             biasF, nullptr, s, N_V, SD, 320, SD, 1,
                                             1, 0, 0, 0, 0, 0,
                                             nullptr, nullptr, nullptr, nullptr,
                                             nullptr, flag);
    } else {
        dim3 g((SD + 63) / 64, (N_V + 63) / 64);
        LAUNCH2(k_gemm, g, 256, kpmax, Wa, ba, nullptr, s, N_V, SD, SD, 1, flag);
    }

    // ----- GNN iterations -----
    for (int t = 0; t < T_IT; t++) {
        dim3 g5((SD + 63) / 64, (N_V + 63) / 64);
        if (mf) {
            long long cum = (long long)(1 + t) * 102400;
            // ua = s@WfS + bf + pos@Wf3 ; dx in-kernel ; bbag = dx@Wf3 - pos@Wf3
            k_gemm_mfma<<<GSD, 256, 0, stream>>>(s, HI(cum), HI(cum) + 102400,
                                                 biasF + 300 + t * 300, nullptr, ua,
                                                 N_V, SD, 320, SD, 0,
                                                 1, 0, 0, 0, 0, 0,
                                                 pos, whTF + t * 960, wf3F + t * 900,
                                                 bhF + t * 3, bbag, flag);
        } else {
            for (int f32v = 0; f32v < 2; f32v++) {
                size_t es = f32v ? 4 : 2;
                const void* Wf_t = Wf + (size_t)t * 303 * SD * es;
                const void* WfS  = Wf + ((size_t)t * 303 + 3) * SD * es;
                const void* bf_t = bff + (size_t)t * SD * es;
                const void* Wh_t = Wh + (size_t)t * SD * 3 * es;
                const void* bh_t = bh + (size_t)t * 3 * es;
                if (f32v) {
                    k_gemm<true><<<g5, 256, 0, stream>>>(s, WfS, bf_t, nullptr, ua, N_V, SD, SD, 0, flag);
                    k_dx<true><<<(N_V + 3) / 4, 256, 0, stream>>>(s, Wh_t, bh_t, dx, flag);
                    k_ab<true><<<(N_V * SD + 255) / 256, 256, 0, stream>>>(dx, pos, Wf_t, ua, bbag, flag);
                } else {
                    k_gemm<false><<<g5, 256, 0, stream>>>(s, WfS, bf_t, nullptr, ua, N_V, SD, SD, 0, flag);
                    k_dx<false><<<(N_V + 3) / 4, 256, 0, stream>>>(s, Wh_t, bh_t, dx, flag);
                    k_ab<false><<<(N_V * SD + 255) / 256, 256, 0, stream>>>(dx, pos, Wf_t, ua, bbag, flag);
                }
            }
        }
        k_aggr<<<(N_V + 3) / 4, 256, 0, stream>>>(ua, bbag, offs, esrc);
        if (mf) {
            long long cum = (long long)(4 + t) * 102400;
            k_gemm_mfma<<<GSD, 256, 0, stream>>>(bbag, HI(cum), HI(cum) + 102400,
                                                 biasF + 1200 + t * 300, s, s,
                                                 N_V, SD, 320, SD, 0,
                                                 1, 0, 0, 0, 0, 0,
                                                 nullptr, nullptr, nullptr, nullptr,
                                                 nullptr, flag);
        } else {
            for (int f32v = 0; f32v < 2; f32v++) {
                size_t es = f32v ? 4 : 2;
                const void* Wg_t = Wg + (size_t)t * SD * SD * es;
                const void* bg_t = bg + (size_t)t * SD * es;
                if (f32v)
                    k_gemm<true><<<g5, 256, 0, stream>>>(bbag, Wg_t, bg_t, s, s, N_V, SD, SD, 0, flag);
                else
                    k_gemm<false><<<g5, 256, 0, stream>>>(bbag, Wg_t, bg_t, s, s, N_V, SD, SD, 0, flag);
            }
        }
    }

    // ----- heads -----
    if (mf) {
        // z=0: Wc1 -> hc ; z=1..4: Wl1[c] -> hl1m (z folded into swizzle x-slot)
        dim3 gz15(5, 160, 1);
        k_gemm_mfma<<<gz15, 256, 0, stream>>>(s, HI(716800), HI(716800) + 20480,
                                              biasF + 2100, nullptr, regA,
                                              N_V, SD, 320, 64, 1,
                                              1, 1, 0, 40960, 64, 1280000,
                                              nullptr, nullptr, nullptr, nullptr,
                                              nullptr, flag);
        // loc layer2 batched: hl1m -> hl2m (per-z A, no swizzle)
        dim3 gz14(1, (N_V + 127) / 128, 4);
        k_gemm_mfma<<<gz14, 256, 0, stream>>>(hl1m, HI(819200), HI(819200) + 4096,
                                              biasF + 2420, nullptr, hl2m,
                                              N_V, 64, 64, 64, 1,
                                              0, 0, 1280000, 8192, 64, 1280000,
                                              nullptr, nullptr, nullptr, nullptr,
                                              nullptr, flag);
        // merged cls (y=4) + loc layer3 (y=0..3)
        dim3 gho((N_V + 255) / 256, 5);
        k_headout<<<gho, 256, 0, stream>>>(hc, hl2m, Wc2, bc2, Wl3, bl3, d_out, flag);
    } else {
        dim3 g(1, (N_V + 63) / 64);
        LAUNCH2(k_gemm, g, 256, s, Wc1, bc1, nullptr, hl1f, N_V, SD, 64, 1, flag);
        LAUNCH2(k_cls, (N_V + 255) / 256, 256, hl1f, Wc2, bc2, d_out, flag);
        for (int c = 0; c < 4; c++) {
            for (int f32v = 0; f32v < 2; f32v++) {
                size_t es = f32v ? 4 : 2;
                const void* Wl1c = Wl1 + (size_t)c * SD * 64 * es;
                const void* bl1c = bl1 + (size_t)c * 64 * es;
                const void* Wl2c = Wl2 + (size_t)c * 64 * 64 * es;
                const void* bl2c = bl2 + (size_t)c * 64 * es;
                const void* Wl3c = Wl3 + (size_t)c * 64 * 7 * es;
                const void* bl3c = bl3 + (size_t)c * 7 * es;
                if (f32v) {
                    k_gemm<true><<<g, 256, 0, stream>>>(s, Wl1c, bl1c, nullptr, hl1f, N_V, SD, 64, 1, flag);
                    k_gemm<true><<<g, 256, 0, stream>>>(hl1f, Wl2c, bl2c, nullptr, hl2f, N_V, 64, 64, 1, flag);
                    k_loc3<true><<<(N_V + 255) / 256, 256, 0, stream>>>(hl2f, Wl3c, bl3c, d_out, c, flag);
                } else {
                    k_gemm<false><<<g, 256, 0, stream>>>(s, Wl1c, bl1c, nullptr, hl1f, N_V, SD, 64, 1, flag);
                    k_gemm<false><<<g, 256, 0, stream>>>(hl1f, Wl2c, bl2c, nullptr, hl2f, N_V, 64, 64, 1, flag);
                    k_loc3<false><<<(N_V + 255) / 256, 256, 0, stream>>>(hl2f, Wl3c, bl3c, d_out, c, flag);
                }
            }
        }
    }
}

// Round 13
// 1043.164 us; speedup vs baseline: 1.1408x; 1.0134x over previous
//
#include <hip/hip_runtime.h>
#include <stdint.h>

#define N_V   20000
#define M_KP  160000
#define E_N   320000
#define SD    300
#define T_IT  3

typedef unsigned short bf16_t;
typedef __attribute__((ext_vector_type(8))) short short8_t;
typedef __attribute__((ext_vector_type(4))) float float4_t;

__device__ __forceinline__ float bf2f(bf16_t u) {
    return __uint_as_float(((unsigned)u) << 16);
}
__device__ __forceinline__ bf16_t f2bf(float f) {
    unsigned u = __float_as_uint(f);
    unsigned r = (u + 0x7FFFu + ((u >> 16) & 1u)) >> 16;
    return (bf16_t)r;
}

template<bool F32>
__device__ __forceinline__ float LD(const void* p, size_t i) {
    if (F32) return ((const float*)p)[i];
    return bf2f(((const bf16_t*)p)[i]);
}
template<bool F32>
__device__ __forceinline__ void ST(void* p, size_t i, float v) {
    if (F32) ((float*)p)[i] = v;
    else     ((bf16_t*)p)[i] = f2bf(v);
}
__device__ __forceinline__ float LDr(const void* p, long long i, bool f32) {
    return f32 ? ((const float*)p)[i] : bf2f(((const bf16_t*)p)[i]);
}
__device__ __forceinline__ void STr(void* p, size_t i, float v, bool f32) {
    if (f32) ((float*)p)[i] = v;
    else     ((bf16_t*)p)[i] = f2bf(v);
}

// ---------- merged: zero cnt + dtype detect (flag=1 if f32, 0 if bf16) ----------
__global__ __launch_bounds__(256) void k_detz(const unsigned* __restrict__ w,
                                              int* __restrict__ flag,
                                              int* __restrict__ cnt) {
    if (blockIdx.x < 79) {
        int i = blockIdx.x * 256 + threadIdx.x;
        if (i < N_V) cnt[i] = 0;
        return;
    }
    __shared__ int cnt_s;
    if (threadIdx.x == 0) cnt_s = 0;
    __syncthreads();
    if (threadIdx.x < 128) {
        unsigned u = w[threadIdx.x];      // 128 dwords = 512B, safe for either dtype
        unsigned lo = u & 0xFFFFu;
        int e = (lo >> 7) & 0xFF;
        int plaus = (lo == 0u) || (e >= 96 && e <= 126);
        atomicAdd(&cnt_s, plaus);
    }
    __syncthreads();
    if (threadIdx.x == 0) flag[0] = (cnt_s >= 64) ? 0 : 1;
}

__global__ void k_hist(const int* __restrict__ dst, int* __restrict__ cnt) {
    int e = blockIdx.x * blockDim.x + threadIdx.x;
    if (e < E_N) atomicAdd(&cnt[dst[e]], 1);
}

// ---------- fast single-block scan: 20 elems/thread, 3 phases ----------
__global__ __launch_bounds__(1024) void k_scan(const int* __restrict__ cnt,
                                               int* __restrict__ offs,
                                               int* __restrict__ cur) {
    __shared__ int sums[1024];
    int tid = threadIdx.x;
    int base = tid * 20;
    int vals[20];
    int s = 0;
#pragma unroll
    for (int j = 0; j < 20; j++) {
        int i = base + j;
        int v = (i < N_V) ? cnt[i] : 0;
        vals[j] = v;
        s += v;
    }
    sums[tid] = s;
    __syncthreads();
    for (int off = 1; off < 1024; off <<= 1) {
        int t = (tid >= off) ? sums[tid - off] : 0;
        __syncthreads();
        sums[tid] += t;
        __syncthreads();
    }
    int run = (tid == 0) ? 0 : sums[tid - 1];
    if (tid == 0) offs[0] = 0;
#pragma unroll
    for (int j = 0; j < 20; j++) {
        int i = base + j;
        if (i < N_V) {
            cur[i] = run;
            run += vals[j];
            offs[i + 1] = run;
        }
    }
}

// ---------- weight prep layout ----------
// Split matrices: m0 Wa 320x320 cum 0 | m1-3 WfS[t] | m4-6 Wg[t]
//   m7 Wc1 64x320 cum 716800 | m8-11 Wl1[c] | m12-15 Wl2[c] cum 819200
//   m16 Wi1 128x64 cum 835584 | m17 Wi2 304x128 cum 843776
// biasF: [0,300) ba | [300,1200) bf | [1200,2100) bg | [2100,2164) bc1
//      | [2164,2420) bl1 | [2420,2676) bl2 | [2676,2804) bi1 | [2804,3104) bi2
// wf3F: 3 x [3][300] rows 0..2 of Wf[t]
// whTF (at wf3F+2700): 3 x [3][320] Wh[t] transposed, zero-padded
// bhF  (at wf3F+5580): 3 x [3] bh[t]
#define PREP_SPLIT 882688
#define PREP_BIAS  3104
#define PREP_WF3   2700
#define PREP_WHT   2880
#define PREP_BH    9
#define PREP_TOT   (PREP_SPLIT + PREP_BIAS + PREP_WF3 + PREP_WHT + PREP_BH + 32)
#define SCAT_BLOCKS 1250
#define PREP_BLOCKS ((PREP_TOT + 255) / 256)

// ---------- merged: edge scatter + weight prep ----------
__global__ __launch_bounds__(256) void k_scprep(
    const int* __restrict__ src, const int* __restrict__ dst,
    int* __restrict__ cur, int* __restrict__ esrc,
    const void* __restrict__ Wa, const void* __restrict__ Wf,
    const void* __restrict__ Wg, const void* __restrict__ Wc1,
    const void* __restrict__ Wl1, const void* __restrict__ Wl2,
    const void* __restrict__ Wi1, const void* __restrict__ Wi2,
    const void* __restrict__ Whw, const void* __restrict__ bhw,
    const void* __restrict__ ba, const void* __restrict__ bfb,
    const void* __restrict__ bgb, const void* __restrict__ bc1,
    const void* __restrict__ bl1b, const void* __restrict__ bl2b,
    const void* __restrict__ bi1, const void* __restrict__ bi2,
    unsigned short* __restrict__ SP, float* __restrict__ biasF,
    float* __restrict__ wf3F, float* __restrict__ bzero,
    const int* __restrict__ flag)
{
    if (blockIdx.x < SCAT_BLOCKS) {
        int e = blockIdx.x * 256 + threadIdx.x;
        if (e < E_N) {
            int p = atomicAdd(&cur[dst[e]], 1);
            esrc[p] = src[e];
        }
        return;
    }
    int idx = (blockIdx.x - SCAT_BLOCKS) * 256 + threadIdx.x;
    if (idx >= PREP_TOT) return;
    bool f32 = flag[0] != 0;
    if (idx < PREP_SPLIT) {
        const void* srcp; long long eoff, cum; int srcN, Nn, Kk, Kpad, pe, local;
        if (idx < 716800) {
            int m = idx / 102400; local = idx - m * 102400;
            pe = 102400; cum = (long long)m * 102400;
            Kpad = 320; Nn = 300; Kk = 300; srcN = 300;
            srcp = (m == 0) ? Wa : (m <= 3 ? Wf : Wg);
            eoff = (m == 0) ? 0 : (m <= 3 ? (long long)((m - 1) * 303 + 3) * 300
                                          : (long long)(m - 4) * 90000);
        } else if (idx < 819200) {
            int j = (idx - 716800) / 20480; local = (idx - 716800) - j * 20480;
            pe = 20480; cum = 716800 + (long long)j * 20480;
            Kpad = 320; Nn = 64; Kk = 300; srcN = 64;
            srcp = (j == 0) ? Wc1 : Wl1;
            eoff = (j == 0) ? 0 : (long long)(j - 1) * 19200;
        } else if (idx < 835584) {
            int c = (idx - 819200) / 4096; local = (idx - 819200) - c * 4096;
            pe = 4096; cum = 819200 + (long long)c * 4096;
            Kpad = 64; Nn = 64; Kk = 64; srcN = 64;
            srcp = Wl2; eoff = (long long)c * 4096;
        } else if (idx < 843776) {
            local = idx - 835584;
            pe = 8192; cum = 835584;
            Kpad = 64; Nn = 128; Kk = 64; srcN = 128;
            srcp = Wi1; eoff = 0;
        } else {
            local = idx - 843776;
            pe = 38912; cum = 843776;
            Kpad = 128; Nn = 300; Kk = 128; srcN = 300;
            srcp = Wi2; eoff = 0;
        }
        int n = local / Kpad, k = local - n * Kpad;
        float v = 0.f;
        if (n < Nn && k < Kk) v = LDr(srcp, eoff + (long long)k * srcN + n, f32);
        bf16_t hi = f2bf(v);                 // RN split
        bf16_t lo = f2bf(v - bf2f(hi));      // bf16 input -> hi exact, lo = 0
        SP[2 * cum + local] = hi;
        SP[2 * cum + pe + local] = lo;
    } else if (idx < PREP_SPLIT + PREP_BIAS) {
        int b = idx - PREP_SPLIT;
        const void* srcp; int o;
        if (b < 300)       { srcp = ba;   o = b; }
        else if (b < 1200) { srcp = bfb;  o = b - 300; }
        else if (b < 2100) { srcp = bgb;  o = b - 1200; }
        else if (b < 2164) { srcp = bc1;  o = b - 2100; }
        else if (b < 2420) { srcp = bl1b; o = b - 2164; }
        else if (b < 2676) { srcp = bl2b; o = b - 2420; }
        else if (b < 2804) { srcp = bi1;  o = b - 2676; }
        else               { srcp = bi2;  o = b - 2804; }
        biasF[b] = LDr(srcp, o, f32);
    } else if (idx < PREP_SPLIT + PREP_BIAS + PREP_WF3) {
        int b2 = idx - (PREP_SPLIT + PREP_BIAS);
        int t = b2 / 900, rem = b2 - t * 900;
        wf3F[b2] = LDr(Wf, (long long)t * 303 * SD + rem, f32);
    } else if (idx < PREP_SPLIT + PREP_BIAS + PREP_WF3 + PREP_WHT) {
        int b3 = idx - (PREP_SPLIT + PREP_BIAS + PREP_WF3);
        int t = b3 / 960, rem = b3 - t * 960;
        int j = rem / 320, k = rem - j * 320;
        wf3F[2700 + b3] = (k < SD) ? LDr(Whw, (long long)t * SD * 3 + k * 3 + j, f32)
                                   : 0.f;
    } else if (idx < PREP_SPLIT + PREP_BIAS + PREP_WF3 + PREP_WHT + PREP_BH) {
        int b4 = idx - (PREP_SPLIT + PREP_BIAS + PREP_WF3 + PREP_WHT);
        wf3F[5580 + b4] = LDr(bhw, b4, f32);   // bh[t][j]
    } else {
        bzero[idx - (PREP_SPLIT + PREP_BIAS + PREP_WF3 + PREP_WHT + PREP_BH)] = 0.f;
    }
}

// ---------- fused init MLP (fallback VALU path) ----------
template<bool F32>
__global__ __launch_bounds__(256) void k_init_fused(
    const void* __restrict__ kp,
    const void* __restrict__ Wi0, const void* __restrict__ bi0,
    const void* __restrict__ Wi1, const void* __restrict__ bi1,
    const void* __restrict__ Wi2, const void* __restrict__ bi2,
    float* __restrict__ kpmax, const int* __restrict__ flag) {
    if ((flag[0] != 0) != F32) return;
    __shared__ float kps[256];
    __shared__ float h1s[64][64];
    __shared__ float h2s[64 * 128];
    int tid = threadIdx.x;
    int row0 = blockIdx.x * 64;
    kps[tid] = LD<F32>(kp, (size_t)row0 * 4 + tid);
    __syncthreads();
    {
        int c = tid & 63;
        float w0 = LD<F32>(Wi0, c), w1 = LD<F32>(Wi0, 64 + c);
        float w2 = LD<F32>(Wi0, 128 + c), w3 = LD<F32>(Wi0, 192 + c);
        float b0 = LD<F32>(bi0, c);
        int rbase = (tid >> 6) * 16;
#pragma unroll
        for (int rr = 0; rr < 16; rr++) {
            int r = rbase + rr;
            float a = b0 + kps[r * 4] * w0 + kps[r * 4 + 1] * w1
                         + kps[r * 4 + 2] * w2 + kps[r * 4 + 3] * w3;
            h1s[r][c] = fmaxf(a, 0.f);
        }
    }
    __syncthreads();
    {
        int c = tid & 127;
        int rbase = (tid >> 7) * 32;
        float b1 = LD<F32>(bi1, c);
        float acc[32];
#pragma unroll
        for (int rr = 0; rr < 32; rr++) acc[rr] = b1;
        for (int k = 0; k < 64; k++) {
            float wv = LD<F32>(Wi1, (size_t)k * 128 + c);
#pragma unroll
            for (int rr = 0; rr < 32; rr++) acc[rr] += h1s[rbase + rr][k] * wv;
        }
#pragma unroll
        for (int rr = 0; rr < 32; rr++)
            h2s[(size_t)(rbase + rr) * 128 + c] = fmaxf(acc[rr], 0.f);
    }
    __syncthreads();
    {
        int cx = tid & 63, rg = tid >> 6;
        float acc[16][5];
#pragma unroll
        for (int r = 0; r < 16; r++)
#pragma unroll
            for (int j = 0; j < 5; j++) acc[r][j] = 0.f;
        bool ok4 = (cx < SD - 256);
        for (int k = 0; k < 128; k++) {
            float w[5];
#pragma unroll
            for (int j = 0; j < 4; j++) w[j] = LD<F32>(Wi2, (size_t)k * SD + cx + 64 * j);
            w[4] = ok4 ? LD<F32>(Wi2, (size_t)k * SD + cx + 256) : 0.f;
#pragma unroll
            for (int r = 0; r < 16; r++) {
                float av = h2s[(rg * 16 + r) * 128 + k];
#pragma unroll
                for (int j = 0; j < 5; j++) acc[r][j] += av * w[j];
            }
        }
        int vbase = (row0 >> 3) + rg * 2;
#pragma unroll
        for (int half = 0; half < 2; half++) {
            int v = vbase + half;
#pragma unroll
            for (int j = 0; j < 5; j++) {
                int c = cx + 64 * j;
                if (c >= SD) continue;
                float m = acc[half * 8][j];
#pragma unroll
                for (int r = 1; r < 8; r++) m = fmaxf(m, acc[half * 8 + r][j]);
                kpmax[(size_t)v * SD + c] = fmaxf(m + LD<F32>(bi2, c), 0.f);
            }
        }
    }
}

// ---------- generic tiled f32 GEMM (fallback path only) ----------
template<bool F32>
__global__ __launch_bounds__(256) void k_gemm(
    const float* __restrict__ A, const void* __restrict__ W,
    const void* __restrict__ bias, const float* res,
    float* C, int Mr, int K, int Nc, int do_relu, const int* __restrict__ flag) {
    if ((flag[0] != 0) != F32) return;
    __shared__ float As[16][65];
    __shared__ float Ws[16][64];
    int tid = threadIdx.x;
    int tx = tid & 15, ty = tid >> 4;
    int row0 = blockIdx.y * 64, col0 = blockIdx.x * 64;
    float acc[4][4] = {{0.f}};
    int lk = tid & 15, lr = tid >> 4;
    int ln = tid & 63, lk4 = tid >> 6;
    for (int k0 = 0; k0 < K; k0 += 16) {
#pragma unroll
        for (int i = 0; i < 4; i++) {
            int r = lr + i * 16;
            int gr = row0 + r, gk = k0 + lk;
            As[lk][r] = (gr < Mr && gk < K) ? A[(size_t)gr * K + gk] : 0.f;
        }
#pragma unroll
        for (int p = 0; p < 4; p++) {
            int kk = lk4 + p * 4;
            int gk = k0 + kk, gn = col0 + ln;
            Ws[kk][ln] = (gk < K && gn < Nc) ? LD<F32>(W, (size_t)gk * Nc + gn) : 0.f;
        }
        __syncthreads();
#pragma unroll
        for (int kk = 0; kk < 16; kk++) {
            float a[4], w[4];
#pragma unroll
            for (int i = 0; i < 4; i++) a[i] = As[kk][ty * 4 + i];
#pragma unroll
            for (int j = 0; j < 4; j++) w[j] = Ws[kk][tx * 4 + j];
#pragma unroll
            for (int i = 0; i < 4; i++)
#pragma unroll
                for (int j = 0; j < 4; j++) acc[i][j] += a[i] * w[j];
        }
        __syncthreads();
    }
#pragma unroll
    for (int i = 0; i < 4; i++) {
        int gr = row0 + ty * 4 + i;
        if (gr >= Mr) continue;
#pragma unroll
        for (int j = 0; j < 4; j++) {
            int gn = col0 + tx * 4 + j;
            if (gn >= Nc) continue;
            float c = acc[i][j] + LD<F32>(bias, gn);
            if (res) c += res[(size_t)gr * Nc + gn];
            if (do_relu) c = fmaxf(c, 0.f);
            C[(size_t)gr * Nc + gn] = c;
        }
    }
}

// ---------- MFMA helpers ----------
__device__ __forceinline__ void mfma16(float4_t& c, short8_t a, short8_t b) {
    asm("v_mfma_f32_16x16x32_bf16 %0, %1, %2, %0" : "+v"(c) : "v"(a), "v"(b));
}
__device__ __forceinline__ void split2(float a, float b, unsigned& h, unsigned& l) {
    asm("v_cvt_pk_bf16_f32 %0, %1, %2" : "=v"(h) : "v"(a), "v"(b));
    float la = a - __uint_as_float(h << 16);
    float lb = b - __uint_as_float(h & 0xFFFF0000u);
    asm("v_cvt_pk_bf16_f32 %0, %1, %2" : "=v"(l) : "v"(la), "v"(lb));
}
__device__ __forceinline__ void split8(float4_t x0, float4_t x1,
                                       short8_t* hi, short8_t* lo) {
    union { unsigned u[4]; short8_t v; } H, L;
#pragma unroll
    for (int p = 0; p < 4; p++) {
        float a, b;
        if (p == 0)      { a = x0[0]; b = x0[1]; }
        else if (p == 1) { a = x0[2]; b = x0[3]; }
        else if (p == 2) { a = x1[0]; b = x1[1]; }
        else             { a = x1[2]; b = x1[3]; }
        unsigned ph, pl;
        split2(a, b, ph, pl);
        H.u[p] = ph; L.u[p] = pl;
    }
    *hi = H.v; *lo = L.v;
}

// ---------- MFMA init MLP v3 (+ wlo skip) ----------
__global__ __launch_bounds__(256) void k_init_mfma(
    const void* __restrict__ kp,
    const void* __restrict__ Wi0, const void* __restrict__ bi0,
    const unsigned short* __restrict__ W1T,   // [128][64], lo at +8192
    const unsigned short* __restrict__ W2T,   // [304][128], lo at +38912
    const float* __restrict__ b1F, const float* __restrict__ b2F,
    float* __restrict__ kpmax, const int* __restrict__ flag)
{
    bool f32 = flag[0] != 0;
    bool wlo = f32;
    __shared__ __attribute__((aligned(16))) unsigned short lds[2][8704]; // 34,816 B
    int tid = threadIdx.x;
    int w = tid >> 6, lane = tid & 63;
    int rg = w >> 1, ch = w & 1;
    int l15 = lane & 15, g = lane >> 4;
    unsigned short* h2h = lds[rg];
    unsigned short* h2l = lds[rg] + 4352;
    int rw0 = blockIdx.x * 64 + rg * 32;

    float kpr[2][4];
#pragma unroll
    for (int mt = 0; mt < 2; mt++) {
        long long r = rw0 + mt * 16 + l15;
#pragma unroll
        for (int j = 0; j < 4; j++) kpr[mt][j] = LDr(kp, r * 4 + j, f32);
    }
    short8_t a1h[2][2], a1l[2][2];
#pragma unroll
    for (int ks = 0; ks < 2; ks++) {
        float h[2][8];
#pragma unroll
        for (int e = 0; e < 8; e++) {
            int chn = ks * 32 + 8 * g + e;
            float w0 = LDr(Wi0, chn, f32),       w1 = LDr(Wi0, 64 + chn, f32);
            float w2 = LDr(Wi0, 128 + chn, f32), w3 = LDr(Wi0, 192 + chn, f32);
            float b0 = LDr(bi0, chn, f32);
#pragma unroll
            for (int mt = 0; mt < 2; mt++)
                h[mt][e] = fmaxf(b0 + kpr[mt][0] * w0 + kpr[mt][1] * w1
                                    + kpr[mt][2] * w2 + kpr[mt][3] * w3, 0.f);
        }
#pragma unroll
        for (int mt = 0; mt < 2; mt++) {
            union { unsigned u[4]; short8_t v; } H, L;
#pragma unroll
            for (int p = 0; p < 4; p++) {
                unsigned hh, ll;
                split2(h[mt][2 * p], h[mt][2 * p + 1], hh, ll);
                H.u[p] = hh; L.u[p] = ll;
            }
            a1h[mt][ks] = H.v; a1l[mt][ks] = L.v;
        }
    }

#pragma unroll
    for (int i = 0; i < 4; i++) {
        int n0 = ch * 4 + i;
        const unsigned short* bp = W1T + (n0 * 16 + l15) * 64 + 8 * g;
        short8_t bh0 = *(const short8_t*)bp;
        short8_t bh1 = *(const short8_t*)(bp + 32);
        float4_t c0 = {0.f, 0.f, 0.f, 0.f}, c1 = {0.f, 0.f, 0.f, 0.f};
        mfma16(c0, a1h[0][0], bh0); mfma16(c0, a1h[0][1], bh1);
        mfma16(c0, a1l[0][0], bh0); mfma16(c0, a1l[0][1], bh1);
        mfma16(c1, a1h[1][0], bh0); mfma16(c1, a1h[1][1], bh1);
        mfma16(c1, a1l[1][0], bh0); mfma16(c1, a1l[1][1], bh1);
        if (wlo) {
            short8_t bl0 = *(const short8_t*)(bp + 8192);
            short8_t bl1 = *(const short8_t*)(bp + 8224);
            mfma16(c0, a1h[0][0], bl0); mfma16(c0, a1h[0][1], bl1);
            mfma16(c1, a1h[1][0], bl0); mfma16(c1, a1h[1][1], bl1);
        }
        int col = n0 * 16 + l15;
        float bv = b1F[col];
#pragma unroll
        for (int i2 = 0; i2 < 4; i2++) {
            float v0 = fmaxf(c0[i2] + bv, 0.f);
            bf16_t h0 = f2bf(v0);
            h2h[(4 * g + i2) * 136 + col] = h0;
            h2l[(4 * g + i2) * 136 + col] = f2bf(v0 - bf2f(h0));
            float v1 = fmaxf(c1[i2] + bv, 0.f);
            bf16_t h1v = f2bf(v1);
            h2h[(16 + 4 * g + i2) * 136 + col] = h1v;
            h2l[(16 + 4 * g + i2) * 136 + col] = f2bf(v1 - bf2f(h1v));
        }
    }
    __syncthreads();

    short8_t a2h[2][4], a2l[2][4];
#pragma unroll
    for (int mt = 0; mt < 2; mt++)
#pragma unroll
        for (int ks = 0; ks < 4; ks++) {
            int off = (mt * 16 + l15) * 136 + ks * 32 + 8 * g;
            a2h[mt][ks] = *(const short8_t*)(h2h + off);
            a2l[mt][ks] = *(const short8_t*)(h2l + off);
        }
    int vb = blockIdx.x * 8 + rg * 4;
    int n0beg = ch ? 10 : 0, n0end = ch ? 19 : 10;
    for (int n0 = n0beg; n0 < n0end; n0++) {
        const unsigned short* bp = W2T + (n0 * 16 + l15) * 128 + 8 * g;
        short8_t bh[4];
#pragma unroll
        for (int ks = 0; ks < 4; ks++) bh[ks] = *(const short8_t*)(bp + ks * 32);
        float4_t c0 = {0.f, 0.f, 0.f, 0.f}, c1 = {0.f, 0.f, 0.f, 0.f};
#pragma unroll
        for (int ks = 0; ks < 4; ks++) {
            mfma16(c0, a2h[0][ks], bh[ks]); mfma16(c1, a2h[1][ks], bh[ks]);
        }
#pragma unroll
        for (int ks = 0; ks < 4; ks++) {
            mfma16(c0, a2l[0][ks], bh[ks]); mfma16(c1, a2l[1][ks], bh[ks]);
        }
        if (wlo) {
            short8_t bl[4];
#pragma unroll
            for (int ks = 0; ks < 4; ks++)
                bl[ks] = *(const short8_t*)(bp + 38912 + ks * 32);
#pragma unroll
            for (int ks = 0; ks < 4; ks++) {
                mfma16(c0, a2h[0][ks], bl[ks]); mfma16(c1, a2h[1][ks], bl[ks]);
            }
        }
        float m0 = fmaxf(fmaxf(c0[0], c0[1]), fmaxf(c0[2], c0[3]));
        m0 = fmaxf(m0, __shfl_xor(m0, 16));
        float m1 = fmaxf(fmaxf(c1[0], c1[1]), fmaxf(c1[2], c1[3]));
        m1 = fmaxf(m1, __shfl_xor(m1, 16));
        int col = n0 * 16 + l15;
        if (col < SD) {
            float bv = b2F[col];
            if (g == 0) {
                kpmax[(size_t)(vb + 0) * SD + col] = fmaxf(m0 + bv, 0.f);
                kpmax[(size_t)(vb + 2) * SD + col] = fmaxf(m1 + bv, 0.f);
            } else if (g == 2) {
                kpmax[(size_t)(vb + 1) * SD + col] = fmaxf(m0 + bv, 0.f);
                kpmax[(size_t)(vb + 3) * SD + col] = fmaxf(m1 + bv, 0.f);
            }
        }
    }
}

// ---------- split-bf16 MFMA GEMM v4: XCD-swizzle + fused dx + AB epilogue ----------
// If swz: grid is (NX, 8*ceil(NY/8)); bid-swizzle puts all NX col-tiles of a
//   row-panel on ONE XCD (A/res fetched once per XCD instead of NX times).
//   If xisz: the decoded x slot is the z-batch index (col-tiles = 1).
// (K+31)/32 must be EVEN. If posp != null: dx computed in-kernel; C = A@W +
//   bias + pos@Wf3; bbag = dx@Wf3 - pos@Wf3.
__global__ __launch_bounds__(256) void k_gemm_mfma(
    const float* __restrict__ A, const unsigned short* __restrict__ WhiT,
    const unsigned short* __restrict__ WloT, const float* __restrict__ bias,
    const float* __restrict__ res, float* __restrict__ C,
    int M, int K, int Kpad, int N, int relu, int swz, int xisz,
    long long zA, long long zW, int zB, long long zC,
    const void* posp, const float* whTF, const float* wf3F,
    const float* bhF, float* bbag, const int* __restrict__ flag)
{
    int xx, yy, z;
    if (swz) {
        int nx = gridDim.x;
        int bid = blockIdx.y * nx + blockIdx.x;
        int r = bid & 7, idx = bid >> 3;
        int q = idx / nx;
        yy = r + 8 * q;
        xx = idx - q * nx;
        z = xisz ? xx : blockIdx.z;
        if (xisz) xx = 0;
        if (yy * 128 >= M) return;
    } else {
        xx = blockIdx.x; yy = blockIdx.y; z = blockIdx.z;
    }
    bool wlo = flag[0] != 0;   // weight-lo nonzero only in f32 mode
    A    += (size_t)z * zA;
    WhiT += (size_t)z * zW;
    WloT += (size_t)z * zW;
    bias += (size_t)z * zB;
    C    += (size_t)z * zC;
    int tid = threadIdx.x;
    int w = tid >> 6, lane = tid & 63;
    int l15 = lane & 15, g = lane >> 4;
    int row0 = yy * 128 + w * 32;   // wave owns 32 rows
    int col0 = xx * 64;
    bool ab = posp != nullptr;

    __shared__ float dxs[4][2][16][3];

    float4_t acc[2][4];
#pragma unroll
    for (int i = 0; i < 2; i++)
#pragma unroll
        for (int j = 0; j < 4; j++) acc[i][j] = (float4_t){0.f, 0.f, 0.f, 0.f};
    float dxp[2][3] = {{0.f, 0.f, 0.f}, {0.f, 0.f, 0.f}};

    const unsigned short* bhp[4];
    const unsigned short* blp[4];
#pragma unroll
    for (int ns = 0; ns < 4; ns++) {
        size_t o = (size_t)(col0 + ns * 16 + l15) * Kpad + 8 * g;
        bhp[ns] = WhiT + o; blp[ns] = WloT + o;
    }
    const float* app[2];
    int amode[2]; bool adead[2];
#pragma unroll
    for (int ms = 0; ms < 2; ms++) {
        int base = row0 + ms * 16;
        int gr = base + l15;
        amode[ms] = (base + 16 <= M) ? 2 : (base < M ? 1 : 0);
        adead[ms] = gr >= M;
        int grc = gr < M ? gr : (M - 1);
        app[ms] = A + (size_t)grc * K + 8 * g;
    }
    const float4_t zf4 = {0.f, 0.f, 0.f, 0.f};
    const short8_t z8 = {0, 0, 0, 0, 0, 0, 0, 0};

    auto LOADB = [&](short8_t* bh, short8_t* bl) {
#pragma unroll
        for (int ns = 0; ns < 4; ns++) {
            bh[ns] = *(const short8_t*)bhp[ns];
            bl[ns] = wlo ? *(const short8_t*)blp[ns] : z8;
            bhp[ns] += 32; blp[ns] += 32;
        }
    };
    auto LOADA = [&](float4_t* x0, float4_t* x1) {
#pragma unroll
        for (int ms = 0; ms < 2; ms++) {
            if (amode[ms] == 0) { x0[ms] = zf4; x1[ms] = zf4; }
            else {
                x0[ms] = *(const float4_t*)app[ms];
                x1[ms] = *(const float4_t*)(app[ms] + 4);
                if (amode[ms] == 1 && adead[ms]) { x0[ms] = zf4; x1[ms] = zf4; }
            }
            app[ms] += 32;
        }
    };
    auto COMPUTE = [&](const short8_t* bh, const short8_t* bl,
                       const float4_t* x0, const float4_t* x1, int kbase) {
        if (ab) {
#pragma unroll
            for (int j = 0; j < 3; j++) {
                float4_t wa = *(const float4_t*)(whTF + j * 320 + kbase + 8 * g);
                float4_t wb = *(const float4_t*)(whTF + j * 320 + kbase + 8 * g + 4);
#pragma unroll
                for (int ms = 0; ms < 2; ms++) {
                    dxp[ms][j] += x0[ms][0] * wa[0] + x0[ms][1] * wa[1]
                                + x0[ms][2] * wa[2] + x0[ms][3] * wa[3]
                                + x1[ms][0] * wb[0] + x1[ms][1] * wb[1]
                                + x1[ms][2] * wb[2] + x1[ms][3] * wb[3];
                }
            }
        }
#pragma unroll
        for (int ms = 0; ms < 2; ms++) {
            short8_t ah, al;
            split8(x0[ms], x1[ms], &ah, &al);
#pragma unroll
            for (int ns = 0; ns < 4; ns++) {
                mfma16(acc[ms][ns], ah, bh[ns]);
                mfma16(acc[ms][ns], al, bh[ns]);
            }
            if (wlo) {
#pragma unroll
                for (int ns = 0; ns < 4; ns++) mfma16(acc[ms][ns], ah, bl[ns]);
            }
        }
    };

    short8_t bhA[4], blA[4], bhB[4], blB[4];
    float4_t x0A[2], x1A[2], x0B[2], x1B[2];
    int iters = (K + 31) / 32;                 // 10 or 2 (even)
    LOADB(bhA, blA); LOADA(x0A, x1A);
    for (int it = 0; it < iters; it += 2) {
        LOADB(bhB, blB); LOADA(x0B, x1B);      // prefetch it+1
        COMPUTE(bhA, blA, x0A, x1A, it * 32);
        if (it + 2 < iters) { LOADB(bhA, blA); LOADA(x0A, x1A); }  // prefetch it+2
        COMPUTE(bhB, blB, x0B, x1B, (it + 1) * 32);
    }

    if (ab) {
        // reduce dx partials over the 4 g-groups (lanes l15+16g share a row)
#pragma unroll
        for (int ms = 0; ms < 2; ms++)
#pragma unroll
            for (int j = 0; j < 3; j++) {
                float p = dxp[ms][j];
                p += __shfl_xor(p, 16);
                p += __shfl_xor(p, 32);
                dxp[ms][j] = p;
            }
        if (g == 0) {
#pragma unroll
            for (int ms = 0; ms < 2; ms++)
#pragma unroll
                for (int j = 0; j < 3; j++) dxs[w][ms][l15][j] = dxp[ms][j];
        }
        __syncthreads();
    }

    bool pf32 = ab && wlo;
    int gnv[4]; float bvv[4], w30v[4], w31v[4], w32v[4];
#pragma unroll
    for (int ns = 0; ns < 4; ns++) {
        int gn = col0 + ns * 16 + l15;
        gnv[ns] = gn;
        bvv[ns] = (gn < N) ? bias[gn] : 0.f;
        if (ab && gn < N) {
            w30v[ns] = wf3F[gn]; w31v[ns] = wf3F[300 + gn]; w32v[ns] = wf3F[600 + gn];
        } else { w30v[ns] = 0.f; w31v[ns] = 0.f; w32v[ns] = 0.f; }
    }
    float bh0 = 0.f, bh1 = 0.f, bh2 = 0.f;
    if (ab) { bh0 = bhF[0]; bh1 = bhF[1]; bh2 = bhF[2]; }
#pragma unroll
    for (int ms = 0; ms < 2; ms++) {
#pragma unroll
        for (int r = 0; r < 4; r++) {
            int gr = row0 + ms * 16 + 4 * g + r;
            if (gr >= M) continue;
            float p0 = 0.f, p1 = 0.f, p2 = 0.f, d0 = 0.f, d1 = 0.f, d2 = 0.f;
            if (ab) {
                p0 = LDr(posp, (long long)gr * 3 + 0, pf32);
                p1 = LDr(posp, (long long)gr * 3 + 1, pf32);
                p2 = LDr(posp, (long long)gr * 3 + 2, pf32);
                int rl = 4 * g + r;
                d0 = dxs[w][ms][rl][0] + bh0;
                d1 = dxs[w][ms][rl][1] + bh1;
                d2 = dxs[w][ms][rl][2] + bh2;
            }
#pragma unroll
            for (int ns = 0; ns < 4; ns++) {
                int gn = gnv[ns];
                if (gn >= N) continue;
                float c = acc[ms][ns][r] + bvv[ns];
                if (ab) {
                    float P = p0 * w30v[ns] + p1 * w31v[ns] + p2 * w32v[ns];
                    float D = d0 * w30v[ns] + d1 * w31v[ns] + d2 * w32v[ns];
                    c += P;
                    bbag[(size_t)gr * N + gn] = D - P;
                }
                if (res) c += res[(size_t)gr * N + gn];
                if (relu) c = fmaxf(c, 0.f);
                C[(size_t)gr * N + gn] = c;
            }
        }
    }
}

// ---------- aggr: 4x-unrolled gather for memory-level parallelism ----------
__global__ __launch_bounds__(256) void k_aggr(
    const float* __restrict__ a, float* bbag,
    const int* __restrict__ offs, const int* __restrict__ esrc) {
    int wv = threadIdx.x >> 6, lane = threadIdx.x & 63;
    int v = blockIdx.x * 4 + wv;
    if (v >= N_V) return;
    int e0 = offs[v], e1 = offs[v + 1];
    float r0 = -3.0e38f, r1 = r0, r2 = r0, r3 = r0, r4 = r0;
    float s0 = r0, s1 = r0, s2 = r0, s3 = r0, s4 = r0;
    bool c4 = lane < SD - 256;
    int e = e0;
    for (; e + 3 < e1; e += 4) {
        const float* A0 = a + (size_t)esrc[e]     * SD + lane;
        const float* A1 = a + (size_t)esrc[e + 1] * SD + lane;
        const float* A2 = a + (size_t)esrc[e + 2] * SD + lane;
        const float* A3 = a + (size_t)esrc[e + 3] * SD + lane;
        float x00 = A0[0],   x10 = A1[0],   x20 = A2[0],   x30 = A3[0];
        float x01 = A0[64],  x11 = A1[64],  x21 = A2[64],  x31 = A3[64];
        float x02 = A0[128], x12 = A1[128], x22 = A2[128], x32 = A3[128];
        float x03 = A0[192], x13 = A1[192], x23 = A2[192], x33 = A3[192];
        float x04 = 0.f, x14 = 0.f, x24 = 0.f, x34 = 0.f;
        if (c4) { x04 = A0[256]; x14 = A1[256]; x24 = A2[256]; x34 = A3[256]; }
        r0 = fmaxf(r0, fmaxf(x00, x10)); s0 = fmaxf(s0, fmaxf(x20, x30));
        r1 = fmaxf(r1, fmaxf(x01, x11)); s1 = fmaxf(s1, fmaxf(x21, x31));
        r2 = fmaxf(r2, fmaxf(x02, x12)); s2 = fmaxf(s2, fmaxf(x22, x32));
        r3 = fmaxf(r3, fmaxf(x03, x13)); s3 = fmaxf(s3, fmaxf(x23, x33));
        if (c4) { r4 = fmaxf(r4, fmaxf(x04, x14)); s4 = fmaxf(s4, fmaxf(x24, x34)); }
    }
    r0 = fmaxf(r0, s0); r1 = fmaxf(r1, s1); r2 = fmaxf(r2, s2);
    r3 = fmaxf(r3, s3); r4 = fmaxf(r4, s4);
    for (; e < e1; e++) {
        const float* ar = a + (size_t)esrc[e] * SD + lane;
        r0 = fmaxf(r0, ar[0]);
        r1 = fmaxf(r1, ar[64]);
        r2 = fmaxf(r2, ar[128]);
        r3 = fmaxf(r3, ar[192]);
        if (c4) r4 = fmaxf(r4, ar[256]);
    }
    float* bv = bbag + (size_t)v * SD + lane;
    bv[0]   = fmaxf(0.f, r0 + bv[0]);
    bv[64]  = fmaxf(0.f, r1 + bv[64]);
    bv[128] = fmaxf(0.f, r2 + bv[128]);
    bv[192] = fmaxf(0.f, r3 + bv[192]);
    if (c4) bv[256] = fmaxf(0.f, r4 + bv[256]);
}

// merged heads output: y in [0,4) -> loc3 class y from hl2all; y==4 -> cls from hc
__global__ void k_headout(const float* __restrict__ hc,
                          const float* __restrict__ hl2all,
                          const void* __restrict__ Wc2, const void* __restrict__ bc2,
                          const void* __restrict__ Wl3, const void* __restrict__ bl3,
                          void* __restrict__ out, const int* __restrict__ flag) {
    bool f32 = flag[0] != 0;
    int y = blockIdx.y;
    int v = blockIdx.x * blockDim.x + threadIdx.x;
    if (v >= N_V) return;
    if (y == 4) {
        float acc[4];
#pragma unroll
        for (int j = 0; j < 4; j++) acc[j] = LDr(bc2, j, f32);
        for (int k = 0; k < 64; k++) {
            float h = hc[(size_t)v * 64 + k];
#pragma unroll
            for (int j = 0; j < 4; j++) acc[j] += h * LDr(Wc2, k * 4 + j, f32);
        }
#pragma unroll
        for (int j = 0; j < 4; j++) STr(out, v * 4 + j, fmaxf(acc[j], 0.f), f32);
    } else {
        const float* h2 = hl2all + (size_t)y * N_V * 64;
        long long wo = (long long)y * 64 * 7, bo = (long long)y * 7;
        float acc[7];
#pragma unroll
        for (int j = 0; j < 7; j++) acc[j] = LDr(bl3, bo + j, f32);
        for (int k = 0; k < 64; k++) {
            float h = h2[(size_t)v * 64 + k];
#pragma unroll
            for (int j = 0; j < 7; j++) acc[j] += h * LDr(Wl3, wo + k * 7 + j, f32);
        }
#pragma unroll
        for (int j = 0; j < 7; j++)
            STr(out, 80000 + (size_t)v * 28 + y * 7 + j, fmaxf(acc[j], 0.f), f32);
    }
}

// ---------- fallback-path small kernels ----------
template<bool F32>
__global__ void k_dx(const float* __restrict__ s, const void* __restrict__ Wh,
                     const void* __restrict__ bh, float* __restrict__ dx,
                     const int* __restrict__ flag) {
    if ((flag[0] != 0) != F32) return;
    int wv = threadIdx.x >> 6, lane = threadIdx.x & 63;
    int v = blockIdx.x * 4 + wv;
    if (v >= N_V) return;
    float p0 = 0.f, p1 = 0.f, p2 = 0.f;
    for (int d = lane; d < SD; d += 64) {
        float sv = s[(size_t)v * SD + d];
        p0 += sv * LD<F32>(Wh, d * 3 + 0);
        p1 += sv * LD<F32>(Wh, d * 3 + 1);
        p2 += sv * LD<F32>(Wh, d * 3 + 2);
    }
#pragma unroll
    for (int off = 32; off > 0; off >>= 1) {
        p0 += __shfl_down(p0, off);
        p1 += __shfl_down(p1, off);
        p2 += __shfl_down(p2, off);
    }
    if (lane == 0) {
        dx[v * 3 + 0] = p0 + LD<F32>(bh, 0);
        dx[v * 3 + 1] = p1 + LD<F32>(bh, 1);
        dx[v * 3 + 2] = p2 + LD<F32>(bh, 2);
    }
}

template<bool F32>
__global__ void k_ab(const float* __restrict__ dx, const void* __restrict__ pos,
                     const void* __restrict__ Wf3, float* __restrict__ ua,
                     float* __restrict__ bbag, const int* __restrict__ flag) {
    if ((flag[0] != 0) != F32) return;
    int idx = blockIdx.x * blockDim.x + threadIdx.x;
    if (idx >= N_V * SD) return;
    int v = idx / SD, c = idx - v * SD;
    float w0 = LD<F32>(Wf3, c), w1 = LD<F32>(Wf3, SD + c), w2 = LD<F32>(Wf3, 2 * SD + c);
    float P = LD<F32>(pos, v * 3 + 0) * w0 + LD<F32>(pos, v * 3 + 1) * w1
            + LD<F32>(pos, v * 3 + 2) * w2;
    float D = dx[v * 3 + 0] * w0 + dx[v * 3 + 1] * w1 + dx[v * 3 + 2] * w2;
    ua[idx] += P;
    bbag[idx] = D - P;
}

template<bool F32>
__global__ void k_cls(const float* __restrict__ hc, const void* __restrict__ W,
                      const void* __restrict__ b, void* __restrict__ out,
                      const int* __restrict__ flag) {
    if ((flag[0] != 0) != F32) return;
    int v = blockIdx.x * blockDim.x + threadIdx.x;
    if (v >= N_V) return;
    float acc[4];
#pragma unroll
    for (int j = 0; j < 4; j++) acc[j] = LD<F32>(b, j);
    for (int k = 0; k < 64; k++) {
        float h = hc[(size_t)v * 64 + k];
#pragma unroll
        for (int j = 0; j < 4; j++) acc[j] += h * LD<F32>(W, k * 4 + j);
    }
#pragma unroll
    for (int j = 0; j < 4; j++) ST<F32>(out, v * 4 + j, fmaxf(acc[j], 0.f));
}

template<bool F32>
__global__ void k_loc3(const float* __restrict__ h2, const void* __restrict__ W,
                       const void* __restrict__ b, void* __restrict__ out, int cls,
                       const int* __restrict__ flag) {
    if ((flag[0] != 0) != F32) return;
    int v = blockIdx.x * blockDim.x + threadIdx.x;
    if (v >= N_V) return;
    float acc[7];
#pragma unroll
    for (int j = 0; j < 7; j++) acc[j] = LD<F32>(b, j);
    for (int k = 0; k < 64; k++) {
        float h = h2[(size_t)v * 64 + k];
#pragma unroll
        for (int j = 0; j < 7; j++) acc[j] += h * LD<F32>(W, k * 7 + j);
    }
#pragma unroll
    for (int j = 0; j < 7; j++)
        ST<F32>(out, 80000 + (size_t)v * 28 + cls * 7 + j, fmaxf(acc[j], 0.f));
}

#define LAUNCH2(kname, grid, blk, ...) \
    do { kname<false><<<grid, blk, 0, stream>>>(__VA_ARGS__); \
         kname<true><<<grid, blk, 0, stream>>>(__VA_ARGS__); } while (0)

extern "C" void kernel_launch(void* const* d_in, const int* in_sizes, int n_in,
                              void* d_out, int out_size, void* d_ws, size_t ws_size,
                              hipStream_t stream) {
    const void* kp  = d_in[0];
    const void* pos = d_in[1];
    const int* eidx = (const int*)d_in[3];
    const int* e_src = eidx;
    const int* e_dst = eidx + E_N;
    const void* Wi0 = d_in[4];   const void* bi0 = d_in[5];
    const void* Wi1 = d_in[6];   const void* bi1 = d_in[7];
    const void* Wi2 = d_in[8];   const void* bi2 = d_in[9];
    const void* Wa  = d_in[10];  const void* ba  = d_in[11];
    const char* Wh  = (const char*)d_in[12];  const char* bh = (const char*)d_in[13];
    const char* Wf  = (const char*)d_in[14];  const char* bff = (const char*)d_in[15];
    const char* Wg  = (const char*)d_in[16];  const char* bg = (const char*)d_in[17];
    const void* Wc1 = d_in[18];  const void* bc1 = d_in[19];
    const void* Wc2 = d_in[20];  const void* bc2 = d_in[21];
    const char* Wl1 = (const char*)d_in[22];  const char* bl1 = (const char*)d_in[23];
    const char* Wl2 = (const char*)d_in[24];  const char* bl2 = (const char*)d_in[25];
    const char* Wl3 = (const char*)d_in[26];  const char* bl3 = (const char*)d_in[27];

    char* ws = (char*)d_ws;
    // region A (24MB): kpmax/ua -> hc(z0)+hl1m(z1..4, spills 1.6MB into dead bbag)
    float* regA  = (float*)(ws + 0);
    float* kpmax = regA;
    float* ua    = regA;
    float* hc    = regA;                      // head z=0
    float* hl1m  = regA + 1280000;            // head z=1..4
    float* hl1f  = (float*)(ws + 6000000);    // fallback
    float* hl2f  = (float*)(ws + 12000000);   // fallback
    // region B (24MB): bbag (GNN; dead at head time)
    float* bbag  = (float*)(ws + 24000000);
    // region C (24MB): s (GNN; dead after head GEMM1) -> hl2m
    float* s     = (float*)(ws + 48000000);
    float* hl2m  = (float*)(ws + 48000000);
    // small stuff
    int*   cnt   = (int*)(ws + 72000000);
    int*   offs  = (int*)(ws + 72100000);
    int*   cur   = (int*)(ws + 72200000);
    int*   esrc  = (int*)(ws + 72300000);
    float* dx    = (float*)(ws + 73600000);   // fallback-path only
    float* wf3F  = (float*)(ws + 73844000);   // wf3(2700) | whT(2880) | bh(9)
    int*   flag  = (int*)(ws + 73900000);
    // MFMA-path extras
    unsigned short* SPLIT = (unsigned short*)(ws + 73950000); // 3.53 MB
    float* biasF = (float*)(ws + 77481000);                   // 12.4 KB
    // total footprint < 77.5 MB

    bool mf = (ws_size == 0) || (ws_size >= (size_t)77500000);
    auto HI = [&](long long cum) { return SPLIT + 2 * cum; };
    float* whTF = wf3F + 2700;
    float* bhF  = wf3F + 5580;

    // ----- zero cnt + dtype detect (merged) -----
    k_detz<<<80, 256, 0, stream>>>((const unsigned*)Wi0, flag, cnt);

    // ----- CSR: hist, scan, then scatter (+ weight prep merged) -----
    k_hist<<<(E_N + 255) / 256, 256, 0, stream>>>(e_dst, cnt);
    k_scan<<<1, 1024, 0, stream>>>(cnt, offs, cur);
    {
        int grid = SCAT_BLOCKS + (mf ? PREP_BLOCKS : 0);
        k_scprep<<<grid, 256, 0, stream>>>(
            e_src, e_dst, cur, esrc,
            Wa, Wf, Wg, Wc1, Wl1, Wl2, Wi1, Wi2, Wh, bh,
            ba, bff, bg, bc1, bl1, bl2, bi1, bi2,
            SPLIT, biasF, wf3F, bbag, flag);
    }

    // ----- init MLP + segmax -----
    if (mf) {
        const unsigned short* W1T = SPLIT + 2LL * 835584;
        const unsigned short* W2T = SPLIT + 2LL * 843776;
        k_init_mfma<<<M_KP / 64, 256, 0, stream>>>(kp, Wi0, bi0, W1T, W2T,
                                                   biasF + 2676, biasF + 2804,
                                                   kpmax, flag);
    } else {
        LAUNCH2(k_init_fused, M_KP / 64, 256, kp, Wi0, bi0, Wi1, bi1, Wi2, bi2, kpmax, flag);
    }

    const dim3 GSD(5, 160);   // swizzled: 5 col-tiles x 8*ceil(157/8) row-slots
    if (mf) {
        k_gemm_mfma<<<GSD, 256, 0, stream>>>(kpmax, HI(0), HI(0) + 102400,
                                             biasF, nullptr, s, N_V, SD, 320, SD, 1,
                                             1, 0, 0, 0, 0, 0,
                                             nullptr, nullptr, nullptr, nullptr,
                                             nullptr, flag);
    } else {
        dim3 g((SD + 63) / 64, (N_V + 63) / 64);
        LAUNCH2(k_gemm, g, 256, kpmax, Wa, ba, nullptr, s, N_V, SD, SD, 1, flag);
    }

    // ----- GNN iterations -----
    for (int t = 0; t < T_IT; t++) {
        dim3 g5((SD + 63) / 64, (N_V + 63) / 64);
        if (mf) {
            long long cum = (long long)(1 + t) * 102400;
            // ua = s@WfS + bf + pos@Wf3 ; dx in-kernel ; bbag = dx@Wf3 - pos@Wf3
            k_gemm_mfma<<<GSD, 256, 0, stream>>>(s, HI(cum), HI(cum) + 102400,
                                                 biasF + 300 + t * 300, nullptr, ua,
                                                 N_V, SD, 320, SD, 0,
                                                 1, 0, 0, 0, 0, 0,
                                                 pos, whTF + t * 960, wf3F + t * 900,
                                                 bhF + t * 3, bbag, flag);
        } else {
            for (int f32v = 0; f32v < 2; f32v++) {
                size_t es = f32v ? 4 : 2;
                const void* Wf_t = Wf + (size_t)t * 303 * SD * es;
                const void* WfS  = Wf + ((size_t)t * 303 + 3) * SD * es;
                const void* bf_t = bff + (size_t)t * SD * es;
                const void* Wh_t = Wh + (size_t)t * SD * 3 * es;
                const void* bh_t = bh + (size_t)t * 3 * es;
                if (f32v) {
                    k_gemm<true><<<g5, 256, 0, stream>>>(s, WfS, bf_t, nullptr, ua, N_V, SD, SD, 0, flag);
                    k_dx<true><<<(N_V + 3) / 4, 256, 0, stream>>>(s, Wh_t, bh_t, dx, flag);
                    k_ab<true><<<(N_V * SD + 255) / 256, 256, 0, stream>>>(dx, pos, Wf_t, ua, bbag, flag);
                } else {
                    k_gemm<false><<<g5, 256, 0, stream>>>(s, WfS, bf_t, nullptr, ua, N_V, SD, SD, 0, flag);
                    k_dx<false><<<(N_V + 3) / 4, 256, 0, stream>>>(s, Wh_t, bh_t, dx, flag);
                    k_ab<false><<<(N_V * SD + 255) / 256, 256, 0, stream>>>(dx, pos, Wf_t, ua, bbag, flag);
                }
            }
        }
        k_aggr<<<(N_V + 3) / 4, 256, 0, stream>>>(ua, bbag, offs, esrc);
        if (mf) {
            long long cum = (long long)(4 + t) * 102400;
            k_gemm_mfma<<<GSD, 256, 0, stream>>>(bbag, HI(cum), HI(cum) + 102400,
                                                 biasF + 1200 + t * 300, s, s,
                                                 N_V, SD, 320, SD, 0,
                                                 1, 0, 0, 0, 0, 0,
                                                 nullptr, nullptr, nullptr, nullptr,
                                                 nullptr, flag);
        } else {
            for (int f32v = 0; f32v < 2; f32v++) {
                size_t es = f32v ? 4 : 2;
                const void* Wg_t = Wg + (size_t)t * SD * SD * es;
                const void* bg_t = bg + (size_t)t * SD * es;
                if (f32v)
                    k_gemm<true><<<g5, 256, 0, stream>>>(bbag, Wg_t, bg_t, s, s, N_V, SD, SD, 0, flag);
                else
                    k_gemm<false><<<g5, 256, 0, stream>>>(bbag, Wg_t, bg_t, s, s, N_V, SD, SD, 0, flag);
            }
        }
    }

    // ----- heads -----
    if (mf) {
        // z=0: Wc1 -> hc ; z=1..4: Wl1[c] -> hl1m (z folded into swizzle x-slot)
        dim3 gz15(5, 160, 1);
        k_gemm_mfma<<<gz15, 256, 0, stream>>>(s, HI(716800), HI(716800) + 20480,
                                              biasF + 2100, nullptr, regA,
                                              N_V, SD, 320, 64, 1,
                                              1, 1, 0, 40960, 64, 1280000,
                                              nullptr, nullptr, nullptr, nullptr,
                                              nullptr, flag);
        // loc layer2 batched: hl1m -> hl2m (per-z A, no swizzle)
        dim3 gz14(1, (N_V + 127) / 128, 4);
        k_gemm_mfma<<<gz14, 256, 0, stream>>>(hl1m, HI(819200), HI(819200) + 4096,
                                              biasF + 2420, nullptr, hl2m,
                                              N_V, 64, 64, 64, 1,
                                              0, 0, 1280000, 8192, 64, 1280000,
                                              nullptr, nullptr, nullptr, nullptr,
                                              nullptr, flag);
        // merged cls (y=4) + loc layer3 (y=0..3)
        dim3 gho((N_V + 255) / 256, 5);
        k_headout<<<gho, 256, 0, stream>>>(hc, hl2m, Wc2, bc2, Wl3, bl3, d_out, flag);
    } else {
        dim3 g(1, (N_V + 63) / 64);
        LAUNCH2(k_gemm, g, 256, s, Wc1, bc1, nullptr, hl1f, N_V, SD, 64, 1, flag);
        LAUNCH2(k_cls, (N_V + 255) / 256, 256, hl1f, Wc2, bc2, d_out, flag);
        for (int c = 0; c < 4; c++) {
            for (int f32v = 0; f32v < 2; f32v++) {
                size_t es = f32v ? 4 : 2;
                const void* Wl1c = Wl1 + (size_t)c * SD * 64 * es;
                const void* bl1c = bl1 + (size_t)c * 64 * es;
                const void* Wl2c = Wl2 + (size_t)c * 64 * 64 * es;
                const void* bl2c = bl2 + (size_t)c * 64 * es;
                const void* Wl3c = Wl3 + (size_t)c * 64 * 7 * es;
                const void* bl3c = bl3 + (size_t)c * 7 * es;
                if (f32v) {
                    k_gemm<true><<<g, 256, 0, stream>>>(s, Wl1c, bl1c, nullptr, hl1f, N_V, SD, 64, 1, flag);
                    k_gemm<true><<<g, 256, 0, stream>>>(hl1f, Wl2c, bl2c, nullptr, hl2f, N_V, 64, 64, 1, flag);
                    k_loc3<true><<<(N_V + 255) / 256, 256, 0, stream>>>(hl2f, Wl3c, bl3c, d_out, c, flag);
                } else {
                    k_gemm<false><<<g, 256, 0, stream>>>(s, Wl1c, bl1c, nullptr, hl1f, N_V, SD, 64, 1, flag);
                    k_gemm<false><<<g, 256, 0, stream>>>(hl1f, Wl2c, bl2c, nullptr, hl2f, N_V, 64, 64, 1, flag);
                    k_loc3<false><<<(N_V + 255) / 256, 256, 0, stream>>>(hl2f, Wl3c, bl3c, d_out, c, flag);
                }
            }
        }
    }
}